// Round 1
// 381.685 us; speedup vs baseline: 1.0196x; 1.0196x over previous
//
#include <hip/hip_runtime.h>
#include <stdint.h>

// ---------------------------------------------------------------------------
// TransformerBlock: B=32, L=512, D=256, H=4.
// Inputs fp32 (dict order); OUTPUT fp32.
// bf16 MFMA GEMMs + fused flash attention:
//   - balanced XCD-affinity swizzle (all q-tiles of a bh on one XCD, qt
//     fast-varying in dispatch order for load balance)
//   - causal staging+MFMA skip in phase 1
//   - phase-2 V double-buffer (1 barrier/iter, staging overlaps MFMA)
//   - r10: deferred softmax normalization + early bf16 P-packing releases
//     S[32] (128 VGPRs) before O[16] goes live; __launch_bounds__(256,3)
//     caps regs at ~168 -> 3 waves/SIMD (was 1, occupancy 10.7%).
// ws = 59 + 5*CB MiB (CB=32 -> single chunk at ws=256MiB).
// ---------------------------------------------------------------------------
#define SEQ   512
#define DM    256
#define NB    32
#define NH    4
#define HD    (NH * DM)           // 1024
#define PE_MASK (SEQ * DM - 1)    // 131071
#define NEGV  (-4294967295.0f)

typedef __attribute__((ext_vector_type(8))) short short8;   // 8 x bf16
typedef __attribute__((ext_vector_type(4))) float f32x4;    // MFMA accumulator

#if defined(__has_builtin)
#if __has_builtin(__builtin_amdgcn_global_load_lds)
#define HAS_ASYNC 1
#endif
#endif
#ifndef HAS_ASYNC
#define HAS_ASYNC 0
#endif

__device__ __forceinline__ float b2f(unsigned short u) {
    return __uint_as_float(((uint32_t)u) << 16);
}
__device__ __forceinline__ unsigned short f2b(float f) {
    uint32_t u = __float_as_uint(f);
    u += 0x7fffu + ((u >> 16) & 1u);   // RNE
    return (unsigned short)(u >> 16);
}

// ---------------------------------------------------------------------------
// Canonicalize mask to int32 (auto-detect uint8 / int32 / int64) — r7-green.
// ---------------------------------------------------------------------------
__global__ __launch_bounds__(256) void mask_canon(
    const unsigned char* __restrict__ raw, int* __restrict__ canon)
{
    __shared__ int enc_byte, enc_odd;
    int tid = threadIdx.x;
    if (tid == 0) { enc_byte = 0; enc_odd = 0; }
    __syncthreads();
    if (tid < 255 && raw[tid * 4 + 1]) atomicOr(&enc_byte, 1);
    if (tid < 128 && ((const int*)raw)[tid * 2 + 1]) atomicOr(&enc_odd, 1);
    __syncthreads();
    int i = blockIdx.x * 256 + tid;
    int v;
    if (enc_byte)      v = (raw[i] != 0);
    else if (enc_odd)  v = (((const int*)raw)[i] != 0);
    else               v = ((((const int*)raw)[i * 2] | ((const int*)raw)[i * 2 + 1]) != 0);
    canon[i] = v;
}

// ---------------------------------------------------------------------------
// addpe3: Q/K/V + pe -> bf16, one dispatch (seg = blk>>12).
// ---------------------------------------------------------------------------
__global__ __launch_bounds__(256) void addpe3(
    const float* __restrict__ Q, const float* __restrict__ K,
    const float* __restrict__ V, const float* __restrict__ pe,
    unsigned short* __restrict__ Qp, unsigned short* __restrict__ Kp,
    unsigned short* __restrict__ Vp)
{
    int blk = blockIdx.x;                  // 0..12287
    int seg = blk >> 12;
    const float* X = (seg == 0) ? Q : (seg == 1) ? K : V;
    unsigned short* O = (seg == 0) ? Qp : (seg == 1) ? Kp : Vp;
    long i = (long)((blk & 4095) * 256 + threadIdx.x) * 4;
    float4 x = *reinterpret_cast<const float4*>(X + i);
    float4 p = *reinterpret_cast<const float4*>(pe + (i & PE_MASK));
    ushort4 o;
    o.x = f2b(x.x + p.x); o.y = f2b(x.y + p.y);
    o.z = f2b(x.z + p.z); o.w = f2b(x.w + p.w);
    *reinterpret_cast<ushort4*>(O + i) = o;
}

// ---------------------------------------------------------------------------
// conv2: w1,w2 fp32 -> bf16, one dispatch (128 blocks, seg = blk>>6).
// ---------------------------------------------------------------------------
__global__ __launch_bounds__(256) void conv2(
    const float* __restrict__ w1, const float* __restrict__ w2,
    unsigned short* __restrict__ o1, unsigned short* __restrict__ o2)
{
    int blk = blockIdx.x;
    const float* in = (blk < 64) ? w1 : w2;
    unsigned short* out = (blk < 64) ? o1 : o2;
    long i = (long)((blk & 63) * 256 + threadIdx.x) * 4;
    float4 x = *reinterpret_cast<const float4*>(in + i);
    ushort4 o;
    o.x = f2b(x.x); o.y = f2b(x.y); o.z = f2b(x.z); o.w = f2b(x.w);
    *reinterpret_cast<ushort4*>(out + i) = o;
}

// ---------------------------------------------------------------------------
// Transpose fp32 -> bf16: out[c][r] = bf16(in[r][c]); 32x32 tiles.
// z selects among 3 same-shape inputs (Wq/Wk/Wv), out spaced by outStride.
// ---------------------------------------------------------------------------
__global__ __launch_bounds__(256) void transpose_f2b3(
    const float* __restrict__ in0, const float* __restrict__ in1,
    const float* __restrict__ in2, unsigned short* __restrict__ out,
    int ldin, int ldout, long outStride)
{
    int z = blockIdx.z;
    const float* in = (z == 0) ? in0 : (z == 1) ? in1 : in2;
    unsigned short* op = out + z * outStride;
    __shared__ unsigned short tile[32][33];
    int r0 = blockIdx.y * 32, c0 = blockIdx.x * 32;
    int i = threadIdx.x >> 3;
    int j = (threadIdx.x & 7) * 4;
    float4 v = *reinterpret_cast<const float4*>(in + (long)(r0 + i) * ldin + c0 + j);
    tile[i][j + 0] = f2b(v.x); tile[i][j + 1] = f2b(v.y);
    tile[i][j + 2] = f2b(v.z); tile[i][j + 3] = f2b(v.w);
    __syncthreads();
    ushort4 w;
    w.x = tile[j + 0][i]; w.y = tile[j + 1][i]; w.z = tile[j + 2][i]; w.w = tile[j + 3][i];
    *reinterpret_cast<ushort4*>(op + (long)(c0 + i) * ldout + r0 + j) = w;
}

__global__ __launch_bounds__(256) void transpose_f2b(
    const float* __restrict__ in, unsigned short* __restrict__ out,
    int ldin, int ldout)
{
    __shared__ unsigned short tile[32][33];
    int r0 = blockIdx.y * 32, c0 = blockIdx.x * 32;
    int i = threadIdx.x >> 3;
    int j = (threadIdx.x & 7) * 4;
    float4 v = *reinterpret_cast<const float4*>(in + (long)(r0 + i) * ldin + c0 + j);
    tile[i][j + 0] = f2b(v.x); tile[i][j + 1] = f2b(v.y);
    tile[i][j + 2] = f2b(v.z); tile[i][j + 3] = f2b(v.w);
    __syncthreads();
    ushort4 w;
    w.x = tile[j + 0][i]; w.y = tile[j + 1][i]; w.z = tile[j + 2][i]; w.w = tile[j + 3][i];
    *reinterpret_cast<ushort4*>(out + (long)(c0 + i) * ldout + r0 + j) = w;
}

// ---------------------------------------------------------------------------
// Batched bf16 transpose (per-head V): out[c][r] = in[r][c]
// ---------------------------------------------------------------------------
__global__ __launch_bounds__(256) void transpose_bf16(
    const unsigned short* __restrict__ in, unsigned short* __restrict__ out,
    int ldin, int ldout, long sInB, long sInH, long sOutB, long sOutH, int Hdiv)
{
    int z = blockIdx.z; int b = z / Hdiv; int h = z % Hdiv;
    const unsigned short* ip = in + b * sInB + h * sInH;
    unsigned short* op = out + b * sOutB + h * sOutH;
    __shared__ unsigned short tile[32][33];
    int r0 = blockIdx.y * 32, c0 = blockIdx.x * 32;
    int i = threadIdx.x >> 3;
    int j = (threadIdx.x & 7) * 4;
    ushort4 v = *reinterpret_cast<const ushort4*>(ip + (long)(r0 + i) * ldin + c0 + j);
    tile[i][j + 0] = v.x; tile[i][j + 1] = v.y; tile[i][j + 2] = v.z; tile[i][j + 3] = v.w;
    __syncthreads();
    ushort4 w;
    w.x = tile[j + 0][i]; w.y = tile[j + 1][i]; w.z = tile[j + 2][i]; w.w = tile[j + 3][i];
    *reinterpret_cast<ushort4*>(op + (long)(c0 + i) * ldout + r0 + j) = w;
}

// ---------------------------------------------------------------------------
// Pure-bf16 MFMA GEMM (r9-green): C = scale*A.Bt (+bias, relu), 128x128 tile,
// global_load_lds width-16 staging. Batched via blockIdx.z.
// ---------------------------------------------------------------------------
template<bool BIAS, bool RELU, bool OUTBF16>
__global__ __launch_bounds__(256) void gemm_bt(
    const unsigned short* __restrict__ A, int lda,
    const unsigned short* __restrict__ B, int ldb,
    void* __restrict__ Cv, int ldc,
    const float* __restrict__ bias, float scale, int K, int Hdiv,
    long sAb, long sAh, long sAz,
    long sBb, long sBh, long sBz,
    long sCb, long sCh, long sCz)
{
    const int m0 = blockIdx.y * 128;
    const int n0 = blockIdx.x * 128;
    int z  = blockIdx.z;
    int bb = z / Hdiv, hh = z % Hdiv;
    const unsigned short* Ab = A + bb * sAb + hh * sAh + (long)z * sAz;
    const unsigned short* Bb = B + bb * sBb + hh * sBh + (long)z * sBz;
    long coff = bb * sCb + hh * sCh + (long)z * sCz;

    __shared__ unsigned short As[128 * 32];
    __shared__ unsigned short Bs[128 * 32];

    const int tid  = threadIdx.x;
    const int lane = tid & 63;
    const int wave = tid >> 6;
    const int wm   = (wave >> 1) * 64;
    const int wn   = (wave & 1) * 64;
    const int lm   = lane & 15;
    const int kq   = (lane >> 4) * 8;

    f32x4 acc[4][4] = {};

    for (int k0 = 0; k0 < K; k0 += 32) {
#pragma unroll
        for (int it = 0; it < 2; ++it) {
            int id = tid + it * 256;
            int r  = id >> 2;
            int c8 = (id & 3) * 8;
            const unsigned short* gA = Ab + (long)(m0 + r) * lda + k0 + c8;
            const unsigned short* gB = Bb + (long)(n0 + r) * ldb + k0 + c8;
#if HAS_ASYNC
            unsigned short* lA = &As[(size_t)(it * 256 + wave * 64) * 8];
            unsigned short* lB = &Bs[(size_t)(it * 256 + wave * 64) * 8];
            __builtin_amdgcn_global_load_lds(
                (const __attribute__((address_space(1))) void*)gA,
                (__attribute__((address_space(3))) void*)lA, 16, 0, 0);
            __builtin_amdgcn_global_load_lds(
                (const __attribute__((address_space(1))) void*)gB,
                (__attribute__((address_space(3))) void*)lB, 16, 0, 0);
#else
            *reinterpret_cast<uint4*>(&As[(size_t)id * 8]) =
                *reinterpret_cast<const uint4*>(gA);
            *reinterpret_cast<uint4*>(&Bs[(size_t)id * 8]) =
                *reinterpret_cast<const uint4*>(gB);
#endif
        }
        __syncthreads();

        short8 af[4], bfr[4];
#pragma unroll
        for (int i = 0; i < 4; ++i)
            af[i] = *reinterpret_cast<const short8*>(&As[(wm + i * 16 + lm) * 32 + kq]);
#pragma unroll
        for (int j = 0; j < 4; ++j)
            bfr[j] = *reinterpret_cast<const short8*>(&Bs[(wn + j * 16 + lm) * 32 + kq]);
#pragma unroll
        for (int i = 0; i < 4; ++i)
#pragma unroll
            for (int j = 0; j < 4; ++j)
                acc[i][j] = __builtin_amdgcn_mfma_f32_16x16x32_bf16(af[i], bfr[j], acc[i][j], 0, 0, 0);
        __syncthreads();
    }

#pragma unroll
    for (int j = 0; j < 4; ++j) {
        int col  = n0 + wn + j * 16 + lm;
        float bv = 0.f;
        if (BIAS) bv = bias[col];
#pragma unroll
        for (int i = 0; i < 4; ++i) {
#pragma unroll
            for (int r = 0; r < 4; ++r) {
                int row = m0 + wm + i * 16 + (lane >> 4) * 4 + r;
                float v = acc[i][j][r] * scale + bv;
                if (RELU) v = fmaxf(v, 0.f);
                long idx = coff + (long)row * ldc + col;
                if (OUTBF16) reinterpret_cast<unsigned short*>(Cv)[idx] = f2b(v);
                else         reinterpret_cast<float*>(Cv)[idx] = v;
            }
        }
    }
}

// ---------------------------------------------------------------------------
// Fused flash attention. Grid 8*nbh blocks; balanced XCD-affinity swizzle:
//   x=L&7, m=L>>3, qt=m&7, z=x+8*(m>>3)  (nbh%8==0)
//   -> all q-tiles of a bh share L%8 (XCD) AND qt varies fastest (balance).
// Phase 1: causal staging ([0,(qt+1)*64) K rows) + per-wave MFMA bound NT.
// Softmax: deferred normalization (O scaled by 1/sum in epilogue); scores
//   packed to bf16 regs (pk[32][2]) right after exp so S[32] (128 VGPRs)
//   dies before O[16] goes live. Peak regs ~150 -> 3 waves/SIMD.
// Phase 2: full 512 keys, V double-buffered (16 KiB halves of Ks), one
//   barrier per iteration; staging overlaps MFMA; Pw is wave-private.
// ---------------------------------------------------------------------------
__global__ __launch_bounds__(256, 3) void flash_attn(
    const unsigned short* __restrict__ Qh,
    const unsigned short* __restrict__ Kh,
    const unsigned short* __restrict__ VhT,
    unsigned short* __restrict__ Vatt,
    const int* __restrict__ maskc, int bh0, float scale, int nbh)
{
    const int tid  = threadIdx.x;
    const int lane = tid & 63;
    const int wave = tid >> 6;
    const int lm   = lane & 15;
    const int qg   = lane >> 4;
    const int kq   = qg * 8;

    const int L = blockIdx.x;
    int z, qt;
    if ((nbh & 7) == 0) {
        int x = L & 7, m = L >> 3;
        qt = m & 7;
        z  = x + 8 * (m >> 3);
    } else {
        z = L % nbh; qt = L / nbh;
    }
    const int b_l = z >> 2, h = z & 3;
    const int m0  = qt * 64;
    const int wq0 = m0 + wave * 16;
    const long qkbase = (long)b_l * SEQ * HD + (long)h * DM;
    const unsigned short* Aq = Qh + qkbase;
    const unsigned short* Ak = Kh + qkbase;
    const unsigned short* Av = VhT + (long)b_l * SEQ * HD + (long)h * SEQ * DM;
    unsigned short* Ov = Vatt + qkbase;
    const int bglob = (bh0 + z) >> 2;

    __shared__ unsigned short Ks[SEQ * 32];                 // 32 KiB
    __shared__ __align__(16) unsigned short Pw[4][16][40];  // 5 KiB

    f32x4 S[32] = {};
    const int NT = (m0 >> 4) + wave + 1;     // causal tile bound (wave-uniform)

    // ---- Phase 1: S = Q.K^T over 8 d-chunks of 32; K rows [0,(qt+1)*64) ----
    for (int kc = 0; kc < 8; ++kc) {
        for (int it = 0; it <= qt; ++it) {
            int id = tid + it * 256;
            const unsigned short* g = Ak + (long)(id >> 2) * HD + kc * 32 + (id & 3) * 8;
#if HAS_ASYNC
            unsigned short* l = &Ks[(size_t)(it * 256 + wave * 64) * 8];
            __builtin_amdgcn_global_load_lds(
                (const __attribute__((address_space(1))) void*)g,
                (__attribute__((address_space(3))) void*)l, 16, 0, 0);
#else
            *reinterpret_cast<uint4*>(&Ks[(size_t)id * 8]) =
                *reinterpret_cast<const uint4*>(g);
#endif
        }
        short8 qf = *reinterpret_cast<const short8*>(
            Aq + (long)(wq0 + lm) * HD + kc * 32 + kq);
        __syncthreads();
#pragma unroll
        for (int nt = 0; nt < 32; ++nt) {
            if (nt < NT) {
                short8 bf = *reinterpret_cast<const short8*>(&Ks[(nt * 16 + lm) * 32 + kq]);
                S[nt] = __builtin_amdgcn_mfma_f32_16x16x32_bf16(qf, bf, S[nt], 0, 0, 0);
            }
        }
        __syncthreads();
    }

    // ---- Prefetch V chunk 0 into Vs buffer 0 (overlaps softmax below) ----
    unsigned short* Vb0 = Ks;            // 16 KiB
    unsigned short* Vb1 = Ks + 8192;     // 16 KiB
#pragma unroll
    for (int it = 0; it < 4; ++it) {
        int id = tid + it * 256;
        const unsigned short* g = Av + (long)(id >> 2) * SEQ + (id & 3) * 8;
#if HAS_ASYNC
        unsigned short* l = &Vb0[(size_t)(it * 256 + wave * 64) * 8];
        __builtin_amdgcn_global_load_lds(
            (const __attribute__((address_space(1))) void*)g,
            (__attribute__((address_space(3))) void*)l, 16, 0, 0);
#else
        *reinterpret_cast<uint4*>(&Vb0[(size_t)id * 8]) =
            *reinterpret_cast<const uint4*>(g);
#endif
    }

    // ---- Softmax in registers (overlaps the V prefetch) ----
    // Deferred normalization: P kept unnormalized (e = exp(s - m) <= 1),
    // O is scaled by 1/sum in the epilogue. P packed to bf16 immediately,
    // releasing S[32] before O[16] allocates.
    int   qrow[4];
    bool  rowm[4];
    float mx[4], sm[4];
#pragma unroll
    for (int r = 0; r < 4; ++r) {
        int q = wq0 + qg * 4 + r;
        qrow[r] = q;
        rowm[r] = maskc[bglob * SEQ + q] != 0;
        mx[r] = -3.4e38f;
    }
#pragma unroll
    for (int nt = 0; nt < 32; ++nt) {
        int k = nt * 16 + lm;
#pragma unroll
        for (int r = 0; r < 4; ++r) {
            float v = S[nt][r] * scale;
            if (k > qrow[r] || rowm[r]) v = NEGV;
            S[nt][r] = v;
            mx[r] = fmaxf(mx[r], v);
        }
    }
#pragma unroll
    for (int r = 0; r < 4; ++r) {
#pragma unroll
        for (int off = 8; off >= 1; off >>= 1)
            mx[r] = fmaxf(mx[r], __shfl_xor(mx[r], off));
        sm[r] = 0.f;
    }
    uint32_t pk[32][2];   // bf16x2-packed unnormalized P (64 VGPRs)
#pragma unroll
    for (int nt = 0; nt < 32; ++nt) {
        float e0 = __expf(S[nt][0] - mx[0]);
        float e1 = __expf(S[nt][1] - mx[1]);
        float e2 = __expf(S[nt][2] - mx[2]);
        float e3 = __expf(S[nt][3] - mx[3]);
        sm[0] += e0; sm[1] += e1; sm[2] += e2; sm[3] += e3;
        pk[nt][0] = (uint32_t)f2b(e0) | ((uint32_t)f2b(e1) << 16);
        pk[nt][1] = (uint32_t)f2b(e2) | ((uint32_t)f2b(e3) << 16);
    }
#pragma unroll
    for (int r = 0; r < 4; ++r) {
#pragma unroll
        for (int off = 8; off >= 1; off >>= 1)
            sm[r] += __shfl_xor(sm[r], off);
        sm[r] = 1.0f / sm[r];    // applied to O in the epilogue
    }

    // ---- Phase 2: O = P.V, 16 key-chunks of 32, double-buffered V ----
    f32x4 O[16] = {};
#pragma unroll
    for (int kc2 = 0; kc2 < 16; ++kc2) {
        unsigned short* Vcur = (kc2 & 1) ? Vb1 : Vb0;
        __syncthreads();     // drains staging of chunk kc2 (+ prior reads)
        if (kc2 < 15) {      // prefetch chunk kc2+1 into the other buffer
            unsigned short* Vnext = (kc2 & 1) ? Vb0 : Vb1;
#pragma unroll
            for (int it = 0; it < 4; ++it) {
                int id = tid + it * 256;
                const unsigned short* g =
                    Av + (long)(id >> 2) * SEQ + (kc2 + 1) * 32 + (id & 3) * 8;
#if HAS_ASYNC
                unsigned short* l = &Vnext[(size_t)(it * 256 + wave * 64) * 8];
                __builtin_amdgcn_global_load_lds(
                    (const __attribute__((address_space(1))) void*)g,
                    (__attribute__((address_space(3))) void*)l, 16, 0, 0);
#else
                *reinterpret_cast<uint4*>(&Vnext[(size_t)id * 8]) =
                    *reinterpret_cast<const uint4*>(g);
#endif
            }
        }
        // P chunk (32 keys): packed regs -> wave-private LDS (A-layout src)
#pragma unroll
        for (int t = 0; t < 2; ++t) {
            int nt = kc2 * 2 + t;
#pragma unroll
            for (int r = 0; r < 4; ++r)
                Pw[wave][qg * 4 + r][t * 16 + lm] =
                    (unsigned short)(pk[nt][r >> 1] >> ((r & 1) * 16));
        }
        short8 pf = *reinterpret_cast<const short8*>(&Pw[wave][lm][kq]);
#pragma unroll
        for (int nt2 = 0; nt2 < 16; ++nt2) {
            short8 vf = *reinterpret_cast<const short8*>(&Vcur[(nt2 * 16 + lm) * 32 + kq]);
            O[nt2] = __builtin_amdgcn_mfma_f32_16x16x32_bf16(pf, vf, O[nt2], 0, 0, 0);
        }
    }

    // ---- epilogue (apply deferred 1/sum) ----
#pragma unroll
    for (int nt2 = 0; nt2 < 16; ++nt2) {
#pragma unroll
        for (int r = 0; r < 4; ++r) {
            int l = wq0 + qg * 4 + r;
            Ov[(long)l * HD + nt2 * 16 + lm] = f2b(O[nt2][r] * sm[r]);
        }
    }
}

// ---------------------------------------------------------------------------
// LN1: x = bf16 AttO + fp32 Q + fp32 pe  ->  fp32 Xf AND bf16 Xb
// ---------------------------------------------------------------------------
__global__ __launch_bounds__(256) void ln1_kernel(
    const unsigned short* __restrict__ AttO, const float* __restrict__ Q,
    const float* __restrict__ pe,
    const float* __restrict__ gamma, const float* __restrict__ beta,
    float* __restrict__ outf, unsigned short* __restrict__ outb)
{
    int row  = blockIdx.x * 4 + (threadIdx.x >> 6);
    int lane = threadIdx.x & 63;
    long base = (long)row * DM + lane * 4;
    ushort4 a = *reinterpret_cast<const ushort4*>(AttO + base);
    float4 qv = *reinterpret_cast<const float4*>(Q + base);
    float4 pv = *reinterpret_cast<const float4*>(pe + (base & PE_MASK));
    float x[4] = {b2f(a.x) + qv.x + pv.x, b2f(a.y) + qv.y + pv.y,
                  b2f(a.z) + qv.z + pv.z, b2f(a.w) + qv.w + pv.w};
    float s = x[0] + x[1] + x[2] + x[3];
#pragma unroll
    for (int off = 32; off > 0; off >>= 1) s += __shfl_xor(s, off);
    float mu = s * (1.0f / DM);
    float vs = 0.f;
#pragma unroll
    for (int t = 0; t < 4; ++t) { float d = x[t] - mu; vs += d * d; }
#pragma unroll
    for (int off = 32; off > 0; off >>= 1) vs += __shfl_xor(vs, off);
    float inv = rsqrtf(vs * (1.0f / DM) + 1e-5f);
    int d0 = lane * 4;
    float4 g = *reinterpret_cast<const float4*>(gamma + d0);
    float4 bt = *reinterpret_cast<const float4*>(beta + d0);
    float4 o;
    o.x = (x[0] - mu) * inv * g.x + bt.x;
    o.y = (x[1] - mu) * inv * g.y + bt.y;
    o.z = (x[2] - mu) * inv * g.z + bt.z;
    o.w = (x[3] - mu) * inv * g.w + bt.w;
    *reinterpret_cast<float4*>(outf + base) = o;
    ushort4 ob;
    ob.x = f2b(o.x); ob.y = f2b(o.y); ob.z = f2b(o.z); ob.w = f2b(o.w);
    *reinterpret_cast<ushort4*>(outb + base) = ob;
}

// ---------------------------------------------------------------------------
// LN2: x = fp32 F + fp32 X  ->  FP32 out
// ---------------------------------------------------------------------------
__global__ __launch_bounds__(256) void ln2_kernel(
    const float* __restrict__ F, const float* __restrict__ X,
    const float* __restrict__ gamma, const float* __restrict__ beta,
    float* __restrict__ out)
{
    int row  = blockIdx.x * 4 + (threadIdx.x >> 6);
    int lane = threadIdx.x & 63;
    long base = (long)row * DM + lane * 4;
    float4 a = *reinterpret_cast<const float4*>(F + base);
    float4 c = *reinterpret_cast<const float4*>(X + base);
    float x[4] = {a.x + c.x, a.y + c.y, a.z + c.z, a.w + c.w};
    float s = x[0] + x[1] + x[2] + x[3];
#pragma unroll
    for (int off = 32; off > 0; off >>= 1) s += __shfl_xor(s, off);
    float mu = s * (1.0f / DM);
    float vs = 0.f;
#pragma unroll
    for (int t = 0; t < 4; ++t) { float d = x[t] - mu; vs += d * d; }
#pragma unroll
    for (int off = 32; off > 0; off >>= 1) vs += __shfl_xor(vs, off);
    float inv = rsqrtf(vs * (1.0f / DM) + 1e-5f);
    int d0 = lane * 4;
    float4 g = *reinterpret_cast<const float4*>(gamma + d0);
    float4 bt = *reinterpret_cast<const float4*>(beta + d0);
    float4 o;
    o.x = (x[0] - mu) * inv * g.x + bt.x;
    o.y = (x[1] - mu) * inv * g.y + bt.y;
    o.z = (x[2] - mu) * inv * g.z + bt.z;
    o.w = (x[3] - mu) * inv * g.w + bt.w;
    *reinterpret_cast<float4*>(out + base) = o;
}

// ---------------------------------------------------------------------------
extern "C" void kernel_launch(void* const* d_in, const int* in_sizes, int n_in,
                              void* d_out, int out_size, void* d_ws, size_t ws_size,
                              hipStream_t stream)
{
    const float* Q  = (const float*)d_in[0];
    const float* Ki = (const float*)d_in[1];
    const float* Vi = (const float*)d_in[2];
    const unsigned char* mask_raw = (const unsigned char*)d_in[3];
    const float* pe = (const float*)d_in[4];
    const float* Wq = (const float*)d_in[5];
    const float* Wk = (const float*)d_in[6];
    const float* Wv = (const float*)d_in[7];
    const float* Wo = (const float*)d_in[8];
    const float* w1 = (const float*)d_in[9];
    const float* b1 = (const float*)d_in[10];
    const float* w2 = (const float*)d_in[11];
    const float* b2 = (const float*)d_in[12];
    const float* gamma = (const float*)d_in[13];
    const float* beta  = (const float*)d_in[14];
    float* out = (float*)d_out;

    const size_t MiB = 1048576;
    char* ws = (char*)d_ws;

    // ---- adaptive chunk size: footprint = 59 + max(5*CB, 24) MiB ----
    int CB = 1;
    for (int cb = 32; cb >= 1; cb >>= 1) {
        size_t scr_sz = (size_t)(5 * cb) * MiB;
        if (scr_sz < 24 * MiB) scr_sz = 24 * MiB;
        if ((59 * MiB + scr_sz) <= ws_size) { CB = cb; break; }
    }
    const int NCH = NB / CB;

    // ---- fixed low regions ----
    unsigned short* WqT  = (unsigned short*)(ws);                 // 512 KiB each
    unsigned short* WkT  = WqT + 262144;
    unsigned short* WvT  = WkT + 262144;
    unsigned short* WoT  = WvT + 262144;
    unsigned short* w1b  = (unsigned short*)(ws + 2 * MiB);       // 128 KiB
    unsigned short* w2b  = w1b + 65536;                           // 128 KiB
    int*            maskc = (int*)(ws + 2 * MiB + 262144);        // 64 KiB
    unsigned short* Qp   = (unsigned short*)(ws + 3 * MiB);       // 8 MiB bf16
    unsigned short* Kp   = (unsigned short*)(ws + 11 * MiB);      // 8 MiB
    unsigned short* Vp   = (unsigned short*)(ws + 19 * MiB);      // 8 MiB
    unsigned short* AttO = (unsigned short*)(ws + 27 * MiB);      // 8 MiB
    unsigned short* Xb   = (unsigned short*)(ws + 35 * MiB);      // 8 MiB
    float*          Xf   = (float*)(ws + 43 * MiB);               // 16 MiB
    char*           scr  = ws + 59 * MiB;
    // chunk scratch (CB MiB each)
    unsigned short* Qh   = (unsigned short*)(scr);
    unsigned short* Kh   = (unsigned short*)(scr + (size_t)CB * MiB);
    unsigned short* Vh   = (unsigned short*)(scr + (size_t)2 * CB * MiB);
    unsigned short* VhT  = (unsigned short*)(scr + (size_t)3 * CB * MiB);
    unsigned short* Vatt = (unsigned short*)(scr + (size_t)4 * CB * MiB);
    // tail aliases over scratch (chunk buffers dead by then)
    unsigned short* H1   = (unsigned short*)(scr);                // 8 MiB bf16
    float*          Ff   = (float*)(scr + 8 * MiB);               // 16 MiB fp32

    const float scale = (float)(1.0 / (16.0 + 1e-6));
    const long CROWS = (long)CB * SEQ;
    const long CBELT = (long)CB * MiB / 2;     // chunk-buffer stride, elements

    // 0. prep (merged): mask, weight transposes/conversions, fused PE-add
    mask_canon<<<64, 256, 0, stream>>>(mask_raw, maskc);
    transpose_f2b3<<<dim3(32, 8, 3), 256, 0, stream>>>(Wq, Wk, Wv, WqT, HD, DM, 262144);
    transpose_f2b<<<dim3(8, 32, 1), 256, 0, stream>>>(Wo, WoT, DM, HD);
    conv2<<<128, 256, 0, stream>>>(w1, w2, w1b, w2b);
    addpe3<<<12288, 256, 0, stream>>>(Q, Ki, Vi, pe, Qp, Kp, Vp);

    // 1. attention in NCH chunks of CB batches
    for (int c = 0; c < NCH; ++c) {
        const long r0   = (long)c * CROWS;
        const int  bh0  = c * CB * NH;
        const int  gy   = (int)(CROWS / 128);
        const int  nbh  = CB * NH;

        // all 3 projections in ONE dispatch (z=0:Q, 1:K, 2:V)
        gemm_bt<false, false, true><<<dim3(8, gy, 3), 256, 0, stream>>>(
            Qp + r0 * DM, DM, WqT, DM, Qh, HD, nullptr, 1.f, DM,
            1, 4194304, 0, 0, 262144, 0, 0, CBELT, 0, 0);

        // per-head V transpose: VhT[bl][h][d][l] = Vh[bl][l][h*256+d]
        transpose_bf16<<<dim3(8, 16, CB * NH), 256, 0, stream>>>(
            Vh, VhT, HD, SEQ, (long)SEQ * HD, DM, (long)SEQ * HD, (long)SEQ * DM, NH);

        // fused attention (balanced XCD swizzle + causal skip + V dbuf)
        flash_attn<<<dim3(8 * nbh, 1, 1), 256, 0, stream>>>(
            Qh, Kh, VhT, Vatt, maskc, bh0, scale, nbh);

        // output projection for this chunk -> AttO rows [r0, r0+CROWS)
        gemm_bt<false, false, true><<<dim3(2, gy, 1), 256, 0, stream>>>(
            Vatt, HD, WoT, HD, AttO + r0 * DM, DM, nullptr, 1.f, HD,
            1, 0,0,0, 0,0,0, 0,0,0);
    }

    // 2. LN1: X = LN(Q + pe + AttO) -> fp32 Xf + bf16 Xb
    ln1_kernel<<<4096, 256, 0, stream>>>(AttO, Q, pe, gamma, beta, Xf, Xb);

    // 3. FFN1: H1 = relu(Xb @ w1^T + b1) -> bf16
    gemm_bt<true, true, true><<<dim3(2, 128, 1), 256, 0, stream>>>(
        Xb, DM, w1b, DM, H1, DM, b1, 1.f, DM, 1, 0,0,0, 0,0,0, 0,0,0);
    // 4. FFN2: F = H1 @ w2^T + b2 -> fp32
    gemm_bt<true, false, false><<<dim3(2, 128, 1), 256, 0, stream>>>(
        H1, DM, w2b, DM, Ff, DM, b2, 1.f, DM, 1, 0,0,0, 0,0,0, 0,0,0);

    // 5. LN2: out = LN(F + X) -> FP32
    ln2_kernel<<<4096, 256, 0, stream>>>(Ff, Xf, gamma, beta, out);
}

// Round 3
// 351.481 us; speedup vs baseline: 1.1073x; 1.0859x over previous
//
#include <hip/hip_runtime.h>
#include <stdint.h>

// ---------------------------------------------------------------------------
// TransformerBlock: B=32, L=512, D=256, H=4.
// Inputs fp32 (dict order); OUTPUT fp32.
// bf16 MFMA GEMMs + fused flash attention:
//   - balanced XCD-affinity swizzle (all q-tiles of a bh on one XCD, qt
//     fast-varying in dispatch order for load balance)
//   - causal staging+MFMA skip in phase 1 AND phase 2
//   - masked (padding) rows: output == column-mean of Vh (uniform softmax
//     over ALL keys in the reference). Computed by vmean_part/vmean_reduce/
//     fix_mask and written into Vatt; flash_attn skips those rows' stores.
//     (r12 fix: r11's phase-2 causal skip truncated masked rows' uniform
//     attention to the causal prefix -> absmax 1.2.)
//   - phase-2 V double-buffer (1 barrier/iter, staging overlaps MFMA)
//   - deferred softmax normalization + early bf16 P-packing releases
//     S[32] (128 VGPRs) before O[16] goes live
//   - __launch_bounds__(256,2): 256-reg cap fits ~200-reg peak, no spill,
//     2 blocks/CU (25% occ). (256,3) spilled ~100MB.
// ws = 59 + 5*CB MiB + CB*34KB (CB=32 -> single chunk at ws=256MiB).
// ---------------------------------------------------------------------------
#define SEQ   512
#define DM    256
#define NB    32
#define NH    4
#define HD    (NH * DM)           // 1024
#define PE_MASK (SEQ * DM - 1)    // 131071
#define NEGV  (-4294967295.0f)

typedef __attribute__((ext_vector_type(8))) short short8;   // 8 x bf16
typedef __attribute__((ext_vector_type(4))) float f32x4;    // MFMA accumulator

#if defined(__has_builtin)
#if __has_builtin(__builtin_amdgcn_global_load_lds)
#define HAS_ASYNC 1
#endif
#endif
#ifndef HAS_ASYNC
#define HAS_ASYNC 0
#endif

__device__ __forceinline__ float b2f(unsigned short u) {
    return __uint_as_float(((uint32_t)u) << 16);
}
__device__ __forceinline__ unsigned short f2b(float f) {
    uint32_t u = __float_as_uint(f);
    u += 0x7fffu + ((u >> 16) & 1u);   // RNE
    return (unsigned short)(u >> 16);
}

// ---------------------------------------------------------------------------
// Canonicalize mask to int32 (auto-detect uint8 / int32 / int64) — r7-green.
// ---------------------------------------------------------------------------
__global__ __launch_bounds__(256) void mask_canon(
    const unsigned char* __restrict__ raw, int* __restrict__ canon)
{
    __shared__ int enc_byte, enc_odd;
    int tid = threadIdx.x;
    if (tid == 0) { enc_byte = 0; enc_odd = 0; }
    __syncthreads();
    if (tid < 255 && raw[tid * 4 + 1]) atomicOr(&enc_byte, 1);
    if (tid < 128 && ((const int*)raw)[tid * 2 + 1]) atomicOr(&enc_odd, 1);
    __syncthreads();
    int i = blockIdx.x * 256 + tid;
    int v;
    if (enc_byte)      v = (raw[i] != 0);
    else if (enc_odd)  v = (((const int*)raw)[i] != 0);
    else               v = ((((const int*)raw)[i * 2] | ((const int*)raw)[i * 2 + 1]) != 0);
    canon[i] = v;
}

// ---------------------------------------------------------------------------
// addpe3: Q/K/V + pe -> bf16, one dispatch (seg = blk>>12).
// ---------------------------------------------------------------------------
__global__ __launch_bounds__(256) void addpe3(
    const float* __restrict__ Q, const float* __restrict__ K,
    const float* __restrict__ V, const float* __restrict__ pe,
    unsigned short* __restrict__ Qp, unsigned short* __restrict__ Kp,
    unsigned short* __restrict__ Vp)
{
    int blk = blockIdx.x;                  // 0..12287
    int seg = blk >> 12;
    const float* X = (seg == 0) ? Q : (seg == 1) ? K : V;
    unsigned short* O = (seg == 0) ? Qp : (seg == 1) ? Kp : Vp;
    long i = (long)((blk & 4095) * 256 + threadIdx.x) * 4;
    float4 x = *reinterpret_cast<const float4*>(X + i);
    float4 p = *reinterpret_cast<const float4*>(pe + (i & PE_MASK));
    ushort4 o;
    o.x = f2b(x.x + p.x); o.y = f2b(x.y + p.y);
    o.z = f2b(x.z + p.z); o.w = f2b(x.w + p.w);
    *reinterpret_cast<ushort4*>(O + i) = o;
}

// ---------------------------------------------------------------------------
// conv2: w1,w2 fp32 -> bf16, one dispatch (128 blocks, seg = blk>>6).
// ---------------------------------------------------------------------------
__global__ __launch_bounds__(256) void conv2(
    const float* __restrict__ w1, const float* __restrict__ w2,
    unsigned short* __restrict__ o1, unsigned short* __restrict__ o2)
{
    int blk = blockIdx.x;
    const float* in = (blk < 64) ? w1 : w2;
    unsigned short* out = (blk < 64) ? o1 : o2;
    long i = (long)((blk & 63) * 256 + threadIdx.x) * 4;
    float4 x = *reinterpret_cast<const float4*>(in + i);
    ushort4 o;
    o.x = f2b(x.x); o.y = f2b(x.y); o.z = f2b(x.z); o.w = f2b(x.w);
    *reinterpret_cast<ushort4*>(out + i) = o;
}

// ---------------------------------------------------------------------------
// Transpose fp32 -> bf16: out[c][r] = bf16(in[r][c]); 32x32 tiles.
// z selects among 3 same-shape inputs (Wq/Wk/Wv), out spaced by outStride.
// ---------------------------------------------------------------------------
__global__ __launch_bounds__(256) void transpose_f2b3(
    const float* __restrict__ in0, const float* __restrict__ in1,
    const float* __restrict__ in2, unsigned short* __restrict__ out,
    int ldin, int ldout, long outStride)
{
    int z = blockIdx.z;
    const float* in = (z == 0) ? in0 : (z == 1) ? in1 : in2;
    unsigned short* op = out + z * outStride;
    __shared__ unsigned short tile[32][33];
    int r0 = blockIdx.y * 32, c0 = blockIdx.x * 32;
    int i = threadIdx.x >> 3;
    int j = (threadIdx.x & 7) * 4;
    float4 v = *reinterpret_cast<const float4*>(in + (long)(r0 + i) * ldin + c0 + j);
    tile[i][j + 0] = f2b(v.x); tile[i][j + 1] = f2b(v.y);
    tile[i][j + 2] = f2b(v.z); tile[i][j + 3] = f2b(v.w);
    __syncthreads();
    ushort4 w;
    w.x = tile[j + 0][i]; w.y = tile[j + 1][i]; w.z = tile[j + 2][i]; w.w = tile[j + 3][i];
    *reinterpret_cast<ushort4*>(op + (long)(c0 + i) * ldout + r0 + j) = w;
}

__global__ __launch_bounds__(256) void transpose_f2b(
    const float* __restrict__ in, unsigned short* __restrict__ out,
    int ldin, int ldout)
{
    __shared__ unsigned short tile[32][33];
    int r0 = blockIdx.y * 32, c0 = blockIdx.x * 32;
    int i = threadIdx.x >> 3;
    int j = (threadIdx.x & 7) * 4;
    float4 v = *reinterpret_cast<const float4*>(in + (long)(r0 + i) * ldin + c0 + j);
    tile[i][j + 0] = f2b(v.x); tile[i][j + 1] = f2b(v.y);
    tile[i][j + 2] = f2b(v.z); tile[i][j + 3] = f2b(v.w);
    __syncthreads();
    ushort4 w;
    w.x = tile[j + 0][i]; w.y = tile[j + 1][i]; w.z = tile[j + 2][i]; w.w = tile[j + 3][i];
    *reinterpret_cast<ushort4*>(out + (long)(c0 + i) * ldout + r0 + j) = w;
}

// ---------------------------------------------------------------------------
// Batched bf16 transpose (per-head V): out[c][r] = in[r][c]
// ---------------------------------------------------------------------------
__global__ __launch_bounds__(256) void transpose_bf16(
    const unsigned short* __restrict__ in, unsigned short* __restrict__ out,
    int ldin, int ldout, long sInB, long sInH, long sOutB, long sOutH, int Hdiv)
{
    int z = blockIdx.z; int b = z / Hdiv; int h = z % Hdiv;
    const unsigned short* ip = in + b * sInB + h * sInH;
    unsigned short* op = out + b * sOutB + h * sOutH;
    __shared__ unsigned short tile[32][33];
    int r0 = blockIdx.y * 32, c0 = blockIdx.x * 32;
    int i = threadIdx.x >> 3;
    int j = (threadIdx.x & 7) * 4;
    ushort4 v = *reinterpret_cast<const ushort4*>(ip + (long)(r0 + i) * ldin + c0 + j);
    tile[i][j + 0] = v.x; tile[i][j + 1] = v.y; tile[i][j + 2] = v.z; tile[i][j + 3] = v.w;
    __syncthreads();
    ushort4 w;
    w.x = tile[j + 0][i]; w.y = tile[j + 1][i]; w.z = tile[j + 2][i]; w.w = tile[j + 3][i];
    *reinterpret_cast<ushort4*>(op + (long)(c0 + i) * ldout + r0 + j) = w;
}

// ---------------------------------------------------------------------------
// vmean_part: partial column sums of Vh over l. part[(bl*8+seg)][c] =
//   sum_{l in [seg*64, seg*64+64)} Vh[bl][l][c]   (fp32)
// ---------------------------------------------------------------------------
__global__ __launch_bounds__(256) void vmean_part(
    const unsigned short* __restrict__ Vh, float* __restrict__ part)
{
    int bl = blockIdx.x, seg = blockIdx.y;
    const unsigned short* p = Vh + (long)bl * SEQ * HD + (long)seg * 64 * HD;
    int c = threadIdx.x * 4;
    float s0 = 0.f, s1 = 0.f, s2 = 0.f, s3 = 0.f;
    for (int l = 0; l < 64; ++l) {
        ushort4 v = *reinterpret_cast<const ushort4*>(p + (long)l * HD + c);
        s0 += b2f(v.x); s1 += b2f(v.y); s2 += b2f(v.z); s3 += b2f(v.w);
    }
    float4 o = {s0, s1, s2, s3};
    *reinterpret_cast<float4*>(part + (long)(bl * 8 + seg) * HD + c) = o;
}

// ---------------------------------------------------------------------------
// vmean_reduce: Vm[bl][c] = bf16( (1/SEQ) * sum_seg part[bl*8+seg][c] )
// ---------------------------------------------------------------------------
__global__ __launch_bounds__(256) void vmean_reduce(
    const float* __restrict__ part, unsigned short* __restrict__ Vm)
{
    int bl = blockIdx.x;
    int c = threadIdx.x * 4;
    const float* p = part + (long)bl * 8 * HD + c;
    float s0 = 0.f, s1 = 0.f, s2 = 0.f, s3 = 0.f;
#pragma unroll
    for (int seg = 0; seg < 8; ++seg) {
        float4 v = *reinterpret_cast<const float4*>(p + (long)seg * HD);
        s0 += v.x; s1 += v.y; s2 += v.z; s3 += v.w;
    }
    const float inv = 1.0f / SEQ;
    ushort4 o;
    o.x = f2b(s0 * inv); o.y = f2b(s1 * inv);
    o.z = f2b(s2 * inv); o.w = f2b(s3 * inv);
    *reinterpret_cast<ushort4*>(Vm + (long)bl * HD + c) = o;
}

// ---------------------------------------------------------------------------
// fix_mask: for padding-masked query rows, Vatt row := Vm row (uniform
// attention over ALL keys, per reference semantics).
// ---------------------------------------------------------------------------
__global__ __launch_bounds__(256) void fix_mask(
    const unsigned short* __restrict__ Vm, unsigned short* __restrict__ Vatt,
    const int* __restrict__ maskc, int b0)
{
    int row = blockIdx.x;              // bl*SEQ + l
    int bl = row >> 9, l = row & (SEQ - 1);
    if (maskc[(long)(b0 + bl) * SEQ + l] == 0) return;
    int c = threadIdx.x * 4;
    ushort4 v = *reinterpret_cast<const ushort4*>(Vm + (long)bl * HD + c);
    *reinterpret_cast<ushort4*>(Vatt + (long)row * HD + c) = v;
}

// ---------------------------------------------------------------------------
// Pure-bf16 MFMA GEMM (r9-green): C = scale*A.Bt (+bias, relu), 128x128 tile,
// global_load_lds width-16 staging. Batched via blockIdx.z.
// ---------------------------------------------------------------------------
template<bool BIAS, bool RELU, bool OUTBF16>
__global__ __launch_bounds__(256) void gemm_bt(
    const unsigned short* __restrict__ A, int lda,
    const unsigned short* __restrict__ B, int ldb,
    void* __restrict__ Cv, int ldc,
    const float* __restrict__ bias, float scale, int K, int Hdiv,
    long sAb, long sAh, long sAz,
    long sBb, long sBh, long sBz,
    long sCb, long sCh, long sCz)
{
    const int m0 = blockIdx.y * 128;
    const int n0 = blockIdx.x * 128;
    int z  = blockIdx.z;
    int bb = z / Hdiv, hh = z % Hdiv;
    const unsigned short* Ab = A + bb * sAb + hh * sAh + (long)z * sAz;
    const unsigned short* Bb = B + bb * sBb + hh * sBh + (long)z * sBz;
    long coff = bb * sCb + hh * sCh + (long)z * sCz;

    __shared__ unsigned short As[128 * 32];
    __shared__ unsigned short Bs[128 * 32];

    const int tid  = threadIdx.x;
    const int lane = tid & 63;
    const int wave = tid >> 6;
    const int wm   = (wave >> 1) * 64;
    const int wn   = (wave & 1) * 64;
    const int lm   = lane & 15;
    const int kq   = (lane >> 4) * 8;

    f32x4 acc[4][4] = {};

    for (int k0 = 0; k0 < K; k0 += 32) {
#pragma unroll
        for (int it = 0; it < 2; ++it) {
            int id = tid + it * 256;
            int r  = id >> 2;
            int c8 = (id & 3) * 8;
            const unsigned short* gA = Ab + (long)(m0 + r) * lda + k0 + c8;
            const unsigned short* gB = Bb + (long)(n0 + r) * ldb + k0 + c8;
#if HAS_ASYNC
            unsigned short* lA = &As[(size_t)(it * 256 + wave * 64) * 8];
            unsigned short* lB = &Bs[(size_t)(it * 256 + wave * 64) * 8];
            __builtin_amdgcn_global_load_lds(
                (const __attribute__((address_space(1))) void*)gA,
                (__attribute__((address_space(3))) void*)lA, 16, 0, 0);
            __builtin_amdgcn_global_load_lds(
                (const __attribute__((address_space(1))) void*)gB,
                (__attribute__((address_space(3))) void*)lB, 16, 0, 0);
#else
            *reinterpret_cast<uint4*>(&As[(size_t)id * 8]) =
                *reinterpret_cast<const uint4*>(gA);
            *reinterpret_cast<uint4*>(&Bs[(size_t)id * 8]) =
                *reinterpret_cast<const uint4*>(gB);
#endif
        }
        __syncthreads();

        short8 af[4], bfr[4];
#pragma unroll
        for (int i = 0; i < 4; ++i)
            af[i] = *reinterpret_cast<const short8*>(&As[(wm + i * 16 + lm) * 32 + kq]);
#pragma unroll
        for (int j = 0; j < 4; ++j)
            bfr[j] = *reinterpret_cast<const short8*>(&Bs[(wn + j * 16 + lm) * 32 + kq]);
#pragma unroll
        for (int i = 0; i < 4; ++i)
#pragma unroll
            for (int j = 0; j < 4; ++j)
                acc[i][j] = __builtin_amdgcn_mfma_f32_16x16x32_bf16(af[i], bfr[j], acc[i][j], 0, 0, 0);
        __syncthreads();
    }

#pragma unroll
    for (int j = 0; j < 4; ++j) {
        int col  = n0 + wn + j * 16 + lm;
        float bv = 0.f;
        if (BIAS) bv = bias[col];
#pragma unroll
        for (int i = 0; i < 4; ++i) {
#pragma unroll
            for (int r = 0; r < 4; ++r) {
                int row = m0 + wm + i * 16 + (lane >> 4) * 4 + r;
                float v = acc[i][j][r] * scale + bv;
                if (RELU) v = fmaxf(v, 0.f);
                long idx = coff + (long)row * ldc + col;
                if (OUTBF16) reinterpret_cast<unsigned short*>(Cv)[idx] = f2b(v);
                else         reinterpret_cast<float*>(Cv)[idx] = v;
            }
        }
    }
}

// ---------------------------------------------------------------------------
// Fused flash attention. Grid 8*nbh blocks; balanced XCD-affinity swizzle:
//   x=L&7, m=L>>3, qt=m&7, z=x+8*(m>>3)  (nbh%8==0)
// Phase 1: causal staging ([0,(qt+1)*64) K rows) + per-wave MFMA bound NT.
// Softmax: causal-only masking (padding-masked rows handled by fix_mask;
//   their compute here is discarded). Deferred normalization; P packed to
//   bf16 regs right after exp so S[32] dies before O[16] goes live.
// Phase 2: CAUSAL bound KC = 2*(qt+1) key-chunks of 32 (suffix e == 0.0f
//   exactly: exp underflow), V double-buffered, one barrier/iter; full
//   unroll + block-uniform guard keeps pk[] statically indexed.
// Epilogue: store only unmasked rows (masked rows owned by fix_mask).
// ---------------------------------------------------------------------------
__global__ __launch_bounds__(256, 2) void flash_attn(
    const unsigned short* __restrict__ Qh,
    const unsigned short* __restrict__ Kh,
    const unsigned short* __restrict__ VhT,
    unsigned short* __restrict__ Vatt,
    const int* __restrict__ maskc, int bh0, float scale, int nbh)
{
    const int tid  = threadIdx.x;
    const int lane = tid & 63;
    const int wave = tid >> 6;
    const int lm   = lane & 15;
    const int qg   = lane >> 4;
    const int kq   = qg * 8;

    const int L = blockIdx.x;
    int z, qt;
    if ((nbh & 7) == 0) {
        int x = L & 7, m = L >> 3;
        qt = m & 7;
        z  = x + 8 * (m >> 3);
    } else {
        z = L % nbh; qt = L / nbh;
    }
    const int b_l = z >> 2, h = z & 3;
    const int m0  = qt * 64;
    const int wq0 = m0 + wave * 16;
    const long qkbase = (long)b_l * SEQ * HD + (long)h * DM;
    const unsigned short* Aq = Qh + qkbase;
    const unsigned short* Ak = Kh + qkbase;
    const unsigned short* Av = VhT + (long)b_l * SEQ * HD + (long)h * SEQ * DM;
    unsigned short* Ov = Vatt + qkbase;
    const int bglob = (bh0 + z) >> 2;

    __shared__ unsigned short Ks[SEQ * 32];                 // 32 KiB
    __shared__ __align__(16) unsigned short Pw[4][16][40];  // 5 KiB

    f32x4 S[32] = {};
    const int NT = (m0 >> 4) + wave + 1;     // causal tile bound (wave-uniform)

    // ---- Phase 1: S = Q.K^T over 8 d-chunks of 32; K rows [0,(qt+1)*64) ----
    for (int kc = 0; kc < 8; ++kc) {
        for (int it = 0; it <= qt; ++it) {
            int id = tid + it * 256;
            const unsigned short* g = Ak + (long)(id >> 2) * HD + kc * 32 + (id & 3) * 8;
#if HAS_ASYNC
            unsigned short* l = &Ks[(size_t)(it * 256 + wave * 64) * 8];
            __builtin_amdgcn_global_load_lds(
                (const __attribute__((address_space(1))) void*)g,
                (__attribute__((address_space(3))) void*)l, 16, 0, 0);
#else
            *reinterpret_cast<uint4*>(&Ks[(size_t)id * 8]) =
                *reinterpret_cast<const uint4*>(g);
#endif
        }
        short8 qf = *reinterpret_cast<const short8*>(
            Aq + (long)(wq0 + lm) * HD + kc * 32 + kq);
        __syncthreads();
#pragma unroll
        for (int nt = 0; nt < 32; ++nt) {
            if (nt < NT) {
                short8 bf = *reinterpret_cast<const short8*>(&Ks[(nt * 16 + lm) * 32 + kq]);
                S[nt] = __builtin_amdgcn_mfma_f32_16x16x32_bf16(qf, bf, S[nt], 0, 0, 0);
            }
        }
        __syncthreads();
    }

    // ---- Prefetch V chunk 0 into Vs buffer 0 (overlaps softmax below) ----
    unsigned short* Vb0 = Ks;            // 16 KiB
    unsigned short* Vb1 = Ks + 8192;     // 16 KiB
#pragma unroll
    for (int it = 0; it < 4; ++it) {
        int id = tid + it * 256;
        const unsigned short* g = Av + (long)(id >> 2) * SEQ + (id & 3) * 8;
#if HAS_ASYNC
        unsigned short* l = &Vb0[(size_t)(it * 256 + wave * 64) * 8];
        __builtin_amdgcn_global_load_lds(
            (const __attribute__((address_space(1))) void*)g,
            (__attribute__((address_space(3))) void*)l, 16, 0, 0);
#else
        *reinterpret_cast<uint4*>(&Vb0[(size_t)id * 8]) =
            *reinterpret_cast<const uint4*>(g);
#endif
    }

    // ---- Softmax in registers (overlaps the V prefetch) ----
    // Causal masking only: padding-masked rows compute a normal (discarded)
    // causal softmax. Deferred normalization: e = exp(s - m) unnormalized;
    // O scaled by 1/sum in the epilogue.
    int   qrow[4];
    bool  rowm[4];
    float mx[4], sm[4];
#pragma unroll
    for (int r = 0; r < 4; ++r) {
        int q = wq0 + qg * 4 + r;
        qrow[r] = q;
        rowm[r] = maskc[bglob * SEQ + q] != 0;
        mx[r] = -3.4e38f;
    }
#pragma unroll
    for (int nt = 0; nt < 32; ++nt) {
        int k = nt * 16 + lm;
#pragma unroll
        for (int r = 0; r < 4; ++r) {
            float v = S[nt][r] * scale;
            if (k > qrow[r]) v = NEGV;
            S[nt][r] = v;
            mx[r] = fmaxf(mx[r], v);
        }
    }
#pragma unroll
    for (int r = 0; r < 4; ++r) {
#pragma unroll
        for (int off = 8; off >= 1; off >>= 1)
            mx[r] = fmaxf(mx[r], __shfl_xor(mx[r], off));
        sm[r] = 0.f;
    }
    uint32_t pk[32][2];   // bf16x2-packed unnormalized P (64 VGPRs)
#pragma unroll
    for (int nt = 0; nt < 32; ++nt) {
        float e0 = __expf(S[nt][0] - mx[0]);
        float e1 = __expf(S[nt][1] - mx[1]);
        float e2 = __expf(S[nt][2] - mx[2]);
        float e3 = __expf(S[nt][3] - mx[3]);
        sm[0] += e0; sm[1] += e1; sm[2] += e2; sm[3] += e3;
        pk[nt][0] = (uint32_t)f2b(e0) | ((uint32_t)f2b(e1) << 16);
        pk[nt][1] = (uint32_t)f2b(e2) | ((uint32_t)f2b(e3) << 16);
    }
#pragma unroll
    for (int r = 0; r < 4; ++r) {
#pragma unroll
        for (int off = 8; off >= 1; off >>= 1)
            sm[r] += __shfl_xor(sm[r], off);
        sm[r] = 1.0f / sm[r];    // applied to O in the epilogue
    }

    // ---- Phase 2: O = P.V, causal KC chunks of 32 keys, double-buffered V --
    // Keys >= (qt+1)*64 have e == 0.0f exactly (exp underflow) -> skip.
    // KC is block-uniform (qt uniform), so guarded __syncthreads is safe.
    const int KC = 2 * (qt + 1);
    f32x4 O[16] = {};
#pragma unroll
    for (int kc2 = 0; kc2 < 16; ++kc2) {
        if (kc2 < KC) {
            unsigned short* Vcur = (kc2 & 1) ? Vb1 : Vb0;
            __syncthreads();     // drains staging of chunk kc2 (+ prior reads)
            if (kc2 + 1 < KC) {  // prefetch chunk kc2+1 into the other buffer
                unsigned short* Vnext = (kc2 & 1) ? Vb0 : Vb1;
#pragma unroll
                for (int it = 0; it < 4; ++it) {
                    int id = tid + it * 256;
                    const unsigned short* g =
                        Av + (long)(id >> 2) * SEQ + (kc2 + 1) * 32 + (id & 3) * 8;
#if HAS_ASYNC
                    unsigned short* l = &Vnext[(size_t)(it * 256 + wave * 64) * 8];
                    __builtin_amdgcn_global_load_lds(
                        (const __attribute__((address_space(1))) void*)g,
                        (__attribute__((address_space(3))) void*)l, 16, 0, 0);
#else
                    *reinterpret_cast<uint4*>(&Vnext[(size_t)id * 8]) =
                        *reinterpret_cast<const uint4*>(g);
#endif
                }
            }
            // P chunk (32 keys): packed regs -> wave-private LDS (A-layout src)
#pragma unroll
            for (int t = 0; t < 2; ++t) {
                int nt = kc2 * 2 + t;
#pragma unroll
                for (int r = 0; r < 4; ++r)
                    Pw[wave][qg * 4 + r][t * 16 + lm] =
                        (unsigned short)(pk[nt][r >> 1] >> ((r & 1) * 16));
            }
            short8 pf = *reinterpret_cast<const short8*>(&Pw[wave][lm][kq]);
#pragma unroll
            for (int nt2 = 0; nt2 < 16; ++nt2) {
                short8 vf = *reinterpret_cast<const short8*>(&Vcur[(nt2 * 16 + lm) * 32 + kq]);
                O[nt2] = __builtin_amdgcn_mfma_f32_16x16x32_bf16(pf, vf, O[nt2], 0, 0, 0);
            }
        }
    }

    // ---- epilogue (apply deferred 1/sum; skip masked rows: fix_mask owns) --
#pragma unroll
    for (int nt2 = 0; nt2 < 16; ++nt2) {
#pragma unroll
        for (int r = 0; r < 4; ++r) {
            if (!rowm[r]) {
                int l = wq0 + qg * 4 + r;
                Ov[(long)l * HD + nt2 * 16 + lm] = f2b(O[nt2][r] * sm[r]);
            }
        }
    }
}

// ---------------------------------------------------------------------------
// LN1: x = bf16 AttO + fp32 Q + fp32 pe  ->  fp32 Xf AND bf16 Xb
// ---------------------------------------------------------------------------
__global__ __launch_bounds__(256) void ln1_kernel(
    const unsigned short* __restrict__ AttO, const float* __restrict__ Q,
    const float* __restrict__ pe,
    const float* __restrict__ gamma, const float* __restrict__ beta,
    float* __restrict__ outf, unsigned short* __restrict__ outb)
{
    int row  = blockIdx.x * 4 + (threadIdx.x >> 6);
    int lane = threadIdx.x & 63;
    long base = (long)row * DM + lane * 4;
    ushort4 a = *reinterpret_cast<const ushort4*>(AttO + base);
    float4 qv = *reinterpret_cast<const float4*>(Q + base);
    float4 pv = *reinterpret_cast<const float4*>(pe + (base & PE_MASK));
    float x[4] = {b2f(a.x) + qv.x + pv.x, b2f(a.y) + qv.y + pv.y,
                  b2f(a.z) + qv.z + pv.z, b2f(a.w) + qv.w + pv.w};
    float s = x[0] + x[1] + x[2] + x[3];
#pragma unroll
    for (int off = 32; off > 0; off >>= 1) s += __shfl_xor(s, off);
    float mu = s * (1.0f / DM);
    float vs = 0.f;
#pragma unroll
    for (int t = 0; t < 4; ++t) { float d = x[t] - mu; vs += d * d; }
#pragma unroll
    for (int off = 32; off > 0; off >>= 1) vs += __shfl_xor(vs, off);
    float inv = rsqrtf(vs * (1.0f / DM) + 1e-5f);
    int d0 = lane * 4;
    float4 g = *reinterpret_cast<const float4*>(gamma + d0);
    float4 bt = *reinterpret_cast<const float4*>(beta + d0);
    float4 o;
    o.x = (x[0] - mu) * inv * g.x + bt.x;
    o.y = (x[1] - mu) * inv * g.y + bt.y;
    o.z = (x[2] - mu) * inv * g.z + bt.z;
    o.w = (x[3] - mu) * inv * g.w + bt.w;
    *reinterpret_cast<float4*>(outf + base) = o;
    ushort4 ob;
    ob.x = f2b(o.x); ob.y = f2b(o.y); ob.z = f2b(o.z); ob.w = f2b(o.w);
    *reinterpret_cast<ushort4*>(outb + base) = ob;
}

// ---------------------------------------------------------------------------
// LN2: x = fp32 F + fp32 X  ->  FP32 out
// ---------------------------------------------------------------------------
__global__ __launch_bounds__(256) void ln2_kernel(
    const float* __restrict__ F, const float* __restrict__ X,
    const float* __restrict__ gamma, const float* __restrict__ beta,
    float* __restrict__ out)
{
    int row  = blockIdx.x * 4 + (threadIdx.x >> 6);
    int lane = threadIdx.x & 63;
    long base = (long)row * DM + lane * 4;
    float4 a = *reinterpret_cast<const float4*>(F + base);
    float4 c = *reinterpret_cast<const float4*>(X + base);
    float x[4] = {a.x + c.x, a.y + c.y, a.z + c.z, a.w + c.w};
    float s = x[0] + x[1] + x[2] + x[3];
#pragma unroll
    for (int off = 32; off > 0; off >>= 1) s += __shfl_xor(s, off);
    float mu = s * (1.0f / DM);
    float vs = 0.f;
#pragma unroll
    for (int t = 0; t < 4; ++t) { float d = x[t] - mu; vs += d * d; }
#pragma unroll
    for (int off = 32; off > 0; off >>= 1) vs += __shfl_xor(vs, off);
    float inv = rsqrtf(vs * (1.0f / DM) + 1e-5f);
    int d0 = lane * 4;
    float4 g = *reinterpret_cast<const float4*>(gamma + d0);
    float4 bt = *reinterpret_cast<const float4*>(beta + d0);
    float4 o;
    o.x = (x[0] - mu) * inv * g.x + bt.x;
    o.y = (x[1] - mu) * inv * g.y + bt.y;
    o.z = (x[2] - mu) * inv * g.z + bt.z;
    o.w = (x[3] - mu) * inv * g.w + bt.w;
    *reinterpret_cast<float4*>(out + base) = o;
}

// ---------------------------------------------------------------------------
extern "C" void kernel_launch(void* const* d_in, const int* in_sizes, int n_in,
                              void* d_out, int out_size, void* d_ws, size_t ws_size,
                              hipStream_t stream)
{
    const float* Q  = (const float*)d_in[0];
    const float* Ki = (const float*)d_in[1];
    const float* Vi = (const float*)d_in[2];
    const unsigned char* mask_raw = (const unsigned char*)d_in[3];
    const float* pe = (const float*)d_in[4];
    const float* Wq = (const float*)d_in[5];
    const float* Wk = (const float*)d_in[6];
    const float* Wv = (const float*)d_in[7];
    const float* Wo = (const float*)d_in[8];
    const float* w1 = (const float*)d_in[9];
    const float* b1 = (const float*)d_in[10];
    const float* w2 = (const float*)d_in[11];
    const float* b2 = (const float*)d_in[12];
    const float* gamma = (const float*)d_in[13];
    const float* beta  = (const float*)d_in[14];
    float* out = (float*)d_out;

    const size_t MiB = 1048576;
    char* ws = (char*)d_ws;

    // ---- adaptive chunk size: footprint = 59 + max(5*CB + 34KB*CB, 24) MiB --
    int CB = 1;
    for (int cb = 32; cb >= 1; cb >>= 1) {
        size_t scr_sz = (size_t)(5 * cb) * MiB + (size_t)cb * 34816;
        if (scr_sz < 24 * MiB) scr_sz = 24 * MiB;
        if ((59 * MiB + scr_sz) <= ws_size) { CB = cb; break; }
    }
    const int NCH = NB / CB;

    // ---- fixed low regions ----
    unsigned short* WqT  = (unsigned short*)(ws);                 // 512 KiB each
    unsigned short* WkT  = WqT + 262144;
    unsigned short* WvT  = WkT + 262144;
    unsigned short* WoT  = WvT + 262144;
    unsigned short* w1b  = (unsigned short*)(ws + 2 * MiB);       // 128 KiB
    unsigned short* w2b  = w1b + 65536;                           // 128 KiB
    int*            maskc = (int*)(ws + 2 * MiB + 262144);        // 64 KiB
    unsigned short* Qp   = (unsigned short*)(ws + 3 * MiB);       // 8 MiB bf16
    unsigned short* Kp   = (unsigned short*)(ws + 11 * MiB);      // 8 MiB
    unsigned short* Vp   = (unsigned short*)(ws + 19 * MiB);      // 8 MiB
    unsigned short* AttO = (unsigned short*)(ws + 27 * MiB);      // 8 MiB
    unsigned short* Xb   = (unsigned short*)(ws + 35 * MiB);      // 8 MiB
    float*          Xf   = (float*)(ws + 43 * MiB);               // 16 MiB
    char*           scr  = ws + 59 * MiB;
    // chunk scratch (CB MiB each)
    unsigned short* Qh   = (unsigned short*)(scr);
    unsigned short* Kh   = (unsigned short*)(scr + (size_t)CB * MiB);
    unsigned short* Vh   = (unsigned short*)(scr + (size_t)2 * CB * MiB);
    unsigned short* VhT  = (unsigned short*)(scr + (size_t)3 * CB * MiB);
    unsigned short* Vatt = (unsigned short*)(scr + (size_t)4 * CB * MiB);
    // vmean scratch (per chunk; dead at tail-alias time)
    float*          part = (float*)(scr + (size_t)5 * CB * MiB);            // CB*32 KiB
    unsigned short* Vm   = (unsigned short*)(scr + (size_t)5 * CB * MiB
                                             + (size_t)CB * 8 * HD * 4);    // CB*2 KiB
    // tail aliases over scratch (chunk buffers dead by then)
    unsigned short* H1   = (unsigned short*)(scr);                // 8 MiB bf16
    float*          Ff   = (float*)(scr + 8 * MiB);               // 16 MiB fp32

    const float scale = (float)(1.0 / (16.0 + 1e-6));
    const long CROWS = (long)CB * SEQ;
    const long CBELT = (long)CB * MiB / 2;     // chunk-buffer stride, elements

    // 0. prep (merged): mask, weight transposes/conversions, fused PE-add
    mask_canon<<<64, 256, 0, stream>>>(mask_raw, maskc);
    transpose_f2b3<<<dim3(32, 8, 3), 256, 0, stream>>>(Wq, Wk, Wv, WqT, HD, DM, 262144);
    transpose_f2b<<<dim3(8, 32, 1), 256, 0, stream>>>(Wo, WoT, DM, HD);
    conv2<<<128, 256, 0, stream>>>(w1, w2, w1b, w2b);
    addpe3<<<12288, 256, 0, stream>>>(Q, Ki, Vi, pe, Qp, Kp, Vp);

    // 1. attention in NCH chunks of CB batches
    for (int c = 0; c < NCH; ++c) {
        const long r0   = (long)c * CROWS;
        const int  bh0  = c * CB * NH;
        const int  gy   = (int)(CROWS / 128);
        const int  nbh  = CB * NH;

        // all 3 projections in ONE dispatch (z=0:Q, 1:K, 2:V)
        gemm_bt<false, false, true><<<dim3(8, gy, 3), 256, 0, stream>>>(
            Qp + r0 * DM, DM, WqT, DM, Qh, HD, nullptr, 1.f, DM,
            1, 4194304, 0, 0, 262144, 0, 0, CBELT, 0, 0);

        // per-head V transpose: VhT[bl][h][d][l] = Vh[bl][l][h*256+d]
        transpose_bf16<<<dim3(8, 16, CB * NH), 256, 0, stream>>>(
            Vh, VhT, HD, SEQ, (long)SEQ * HD, DM, (long)SEQ * HD, (long)SEQ * DM, NH);

        // per-batch V column means (for padding-masked rows)
        vmean_part<<<dim3(CB, 8), 256, 0, stream>>>(Vh, part);
        vmean_reduce<<<CB, 256, 0, stream>>>(part, Vm);

        // fused attention (balanced XCD swizzle + causal skip both phases)
        flash_attn<<<dim3(8 * nbh, 1, 1), 256, 0, stream>>>(
            Qh, Kh, VhT, Vatt, maskc, bh0, scale, nbh);

        // masked rows: Vatt row := Vm row (uniform attention over all keys)
        fix_mask<<<(int)CROWS, 256, 0, stream>>>(Vm, Vatt, maskc, c * CB);

        // output projection for this chunk -> AttO rows [r0, r0+CROWS)
        gemm_bt<false, false, true><<<dim3(2, gy, 1), 256, 0, stream>>>(
            Vatt, HD, WoT, HD, AttO + r0 * DM, DM, nullptr, 1.f, HD,
            1, 0,0,0, 0,0,0, 0,0,0);
    }

    // 2. LN1: X = LN(Q + pe + AttO) -> fp32 Xf + bf16 Xb
    ln1_kernel<<<4096, 256, 0, stream>>>(AttO, Q, pe, gamma, beta, Xf, Xb);

    // 3. FFN1: H1 = relu(Xb @ w1^T + b1) -> bf16
    gemm_bt<true, true, true><<<dim3(2, 128, 1), 256, 0, stream>>>(
        Xb, DM, w1b, DM, H1, DM, b1, 1.f, DM, 1, 0,0,0, 0,0,0, 0,0,0);
    // 4. FFN2: F = H1 @ w2^T + b2 -> fp32
    gemm_bt<true, false, false><<<dim3(2, 128, 1), 256, 0, stream>>>(
        H1, DM, w2b, DM, Ff, DM, b2, 1.f, DM, 1, 0,0,0, 0,0,0, 0,0,0);

    // 5. LN2: out = LN(F + X) -> FP32
    ln2_kernel<<<4096, 256, 0, stream>>>(Ff, Xf, gamma, beta, out);
}

// Round 4
// 348.113 us; speedup vs baseline: 1.1180x; 1.0097x over previous
//
#include <hip/hip_runtime.h>
#include <stdint.h>

// ---------------------------------------------------------------------------
// TransformerBlock: B=32, L=512, D=256, H=4.
// Inputs fp32 (dict order); OUTPUT fp32.
// bf16 MFMA GEMMs + fused flash attention:
//   - balanced XCD-affinity swizzle (all q-tiles of a bh on one XCD, qt
//     fast-varying in dispatch order for load balance)
//   - r13: LDS XOR-swizzle (byte ^= ((byte>>7)&7)<<4) on Ks and V tiles —
//     kills the 8-way ds_read_b128 bank conflict (64B row stride). Linear
//     global_load_lds dest + pre-swizzled GLOBAL source + swizzled read
//     (rule 21: both-sides-or-neither).
//   - r13: phase-1 double-buffered stage-ahead (stage kc+1 -> compute kc ->
//     one barrier). Staging fixed at 8 iters (full 512 rows) so the
//     compiler can statically count vmcnt for the qf load; extra K reads
//     are L2-absorbed (panel shared per XCD).
//   - causal MFMA skip in phase 1, causal chunk bound in phase 2
//   - masked (padding) rows: output == column-mean of Vh via vmean_part/
//     vmean_reduce/fix_mask; flash_attn skips those rows' stores.
//   - deferred softmax normalization + early bf16 P-packing releases
//     S[32] (128 AGPRs) before O[16] goes live
//   - __launch_bounds__(256,2): fits ~240-reg peak, no spill, 2 blocks/CU.
// ws = 59 + 5*CB MiB + CB*34KB (CB=32 -> single chunk at ws=256MiB).
// ---------------------------------------------------------------------------
#define SEQ   512
#define DM    256
#define NB    32
#define NH    4
#define HD    (NH * DM)           // 1024
#define PE_MASK (SEQ * DM - 1)    // 131071
#define NEGV  (-4294967295.0f)

typedef __attribute__((ext_vector_type(8))) short short8;   // 8 x bf16
typedef __attribute__((ext_vector_type(4))) float f32x4;    // MFMA accumulator

#if defined(__has_builtin)
#if __has_builtin(__builtin_amdgcn_global_load_lds)
#define HAS_ASYNC 1
#endif
#endif
#ifndef HAS_ASYNC
#define HAS_ASYNC 0
#endif

__device__ __forceinline__ float b2f(unsigned short u) {
    return __uint_as_float(((uint32_t)u) << 16);
}
__device__ __forceinline__ unsigned short f2b(float f) {
    uint32_t u = __float_as_uint(f);
    u += 0x7fffu + ((u >> 16) & 1u);   // RNE
    return (unsigned short)(u >> 16);
}

// LDS bank swizzle: involution on byte bits [6:4] keyed by bits [9:7]
// (row = byte>>6 at 64B row stride; mask = (row>>1)&7). Post-swizzle bank
// group = (4*(row&1)+qg) ^ ((row>>1)&7) -> 2 lanes/group = conflict-free.
__device__ __forceinline__ int swzb(int b) {
    return b ^ (((b >> 7) & 7) << 4);
}

// ---------------------------------------------------------------------------
// Canonicalize mask to int32 (auto-detect uint8 / int32 / int64) — r7-green.
// ---------------------------------------------------------------------------
__global__ __launch_bounds__(256) void mask_canon(
    const unsigned char* __restrict__ raw, int* __restrict__ canon)
{
    __shared__ int enc_byte, enc_odd;
    int tid = threadIdx.x;
    if (tid == 0) { enc_byte = 0; enc_odd = 0; }
    __syncthreads();
    if (tid < 255 && raw[tid * 4 + 1]) atomicOr(&enc_byte, 1);
    if (tid < 128 && ((const int*)raw)[tid * 2 + 1]) atomicOr(&enc_odd, 1);
    __syncthreads();
    int i = blockIdx.x * 256 + tid;
    int v;
    if (enc_byte)      v = (raw[i] != 0);
    else if (enc_odd)  v = (((const int*)raw)[i] != 0);
    else               v = ((((const int*)raw)[i * 2] | ((const int*)raw)[i * 2 + 1]) != 0);
    canon[i] = v;
}

// ---------------------------------------------------------------------------
// addpe3: Q/K/V + pe -> bf16, one dispatch (seg = blk>>12).
// ---------------------------------------------------------------------------
__global__ __launch_bounds__(256) void addpe3(
    const float* __restrict__ Q, const float* __restrict__ K,
    const float* __restrict__ V, const float* __restrict__ pe,
    unsigned short* __restrict__ Qp, unsigned short* __restrict__ Kp,
    unsigned short* __restrict__ Vp)
{
    int blk = blockIdx.x;                  // 0..12287
    int seg = blk >> 12;
    const float* X = (seg == 0) ? Q : (seg == 1) ? K : V;
    unsigned short* O = (seg == 0) ? Qp : (seg == 1) ? Kp : Vp;
    long i = (long)((blk & 4095) * 256 + threadIdx.x) * 4;
    float4 x = *reinterpret_cast<const float4*>(X + i);
    float4 p = *reinterpret_cast<const float4*>(pe + (i & PE_MASK));
    ushort4 o;
    o.x = f2b(x.x + p.x); o.y = f2b(x.y + p.y);
    o.z = f2b(x.z + p.z); o.w = f2b(x.w + p.w);
    *reinterpret_cast<ushort4*>(O + i) = o;
}

// ---------------------------------------------------------------------------
// conv2: w1,w2 fp32 -> bf16, one dispatch (128 blocks, seg = blk>>6).
// ---------------------------------------------------------------------------
__global__ __launch_bounds__(256) void conv2(
    const float* __restrict__ w1, const float* __restrict__ w2,
    unsigned short* __restrict__ o1, unsigned short* __restrict__ o2)
{
    int blk = blockIdx.x;
    const float* in = (blk < 64) ? w1 : w2;
    unsigned short* out = (blk < 64) ? o1 : o2;
    long i = (long)((blk & 63) * 256 + threadIdx.x) * 4;
    float4 x = *reinterpret_cast<const float4*>(in + i);
    ushort4 o;
    o.x = f2b(x.x); o.y = f2b(x.y); o.z = f2b(x.z); o.w = f2b(x.w);
    *reinterpret_cast<ushort4*>(out + i) = o;
}

// ---------------------------------------------------------------------------
// Transpose fp32 -> bf16: out[c][r] = bf16(in[r][c]); 32x32 tiles.
// z selects among 3 same-shape inputs (Wq/Wk/Wv), out spaced by outStride.
// ---------------------------------------------------------------------------
__global__ __launch_bounds__(256) void transpose_f2b3(
    const float* __restrict__ in0, const float* __restrict__ in1,
    const float* __restrict__ in2, unsigned short* __restrict__ out,
    int ldin, int ldout, long outStride)
{
    int z = blockIdx.z;
    const float* in = (z == 0) ? in0 : (z == 1) ? in1 : in2;
    unsigned short* op = out + z * outStride;
    __shared__ unsigned short tile[32][33];
    int r0 = blockIdx.y * 32, c0 = blockIdx.x * 32;
    int i = threadIdx.x >> 3;
    int j = (threadIdx.x & 7) * 4;
    float4 v = *reinterpret_cast<const float4*>(in + (long)(r0 + i) * ldin + c0 + j);
    tile[i][j + 0] = f2b(v.x); tile[i][j + 1] = f2b(v.y);
    tile[i][j + 2] = f2b(v.z); tile[i][j + 3] = f2b(v.w);
    __syncthreads();
    ushort4 w;
    w.x = tile[j + 0][i]; w.y = tile[j + 1][i]; w.z = tile[j + 2][i]; w.w = tile[j + 3][i];
    *reinterpret_cast<ushort4*>(op + (long)(c0 + i) * ldout + r0 + j) = w;
}

__global__ __launch_bounds__(256) void transpose_f2b(
    const float* __restrict__ in, unsigned short* __restrict__ out,
    int ldin, int ldout)
{
    __shared__ unsigned short tile[32][33];
    int r0 = blockIdx.y * 32, c0 = blockIdx.x * 32;
    int i = threadIdx.x >> 3;
    int j = (threadIdx.x & 7) * 4;
    float4 v = *reinterpret_cast<const float4*>(in + (long)(r0 + i) * ldin + c0 + j);
    tile[i][j + 0] = f2b(v.x); tile[i][j + 1] = f2b(v.y);
    tile[i][j + 2] = f2b(v.z); tile[i][j + 3] = f2b(v.w);
    __syncthreads();
    ushort4 w;
    w.x = tile[j + 0][i]; w.y = tile[j + 1][i]; w.z = tile[j + 2][i]; w.w = tile[j + 3][i];
    *reinterpret_cast<ushort4*>(out + (long)(c0 + i) * ldout + r0 + j) = w;
}

// ---------------------------------------------------------------------------
// Batched bf16 transpose (per-head V): out[c][r] = in[r][c]
// ---------------------------------------------------------------------------
__global__ __launch_bounds__(256) void transpose_bf16(
    const unsigned short* __restrict__ in, unsigned short* __restrict__ out,
    int ldin, int ldout, long sInB, long sInH, long sOutB, long sOutH, int Hdiv)
{
    int z = blockIdx.z; int b = z / Hdiv; int h = z % Hdiv;
    const unsigned short* ip = in + b * sInB + h * sInH;
    unsigned short* op = out + b * sOutB + h * sOutH;
    __shared__ unsigned short tile[32][33];
    int r0 = blockIdx.y * 32, c0 = blockIdx.x * 32;
    int i = threadIdx.x >> 3;
    int j = (threadIdx.x & 7) * 4;
    ushort4 v = *reinterpret_cast<const ushort4*>(ip + (long)(r0 + i) * ldin + c0 + j);
    tile[i][j + 0] = v.x; tile[i][j + 1] = v.y; tile[i][j + 2] = v.z; tile[i][j + 3] = v.w;
    __syncthreads();
    ushort4 w;
    w.x = tile[j + 0][i]; w.y = tile[j + 1][i]; w.z = tile[j + 2][i]; w.w = tile[j + 3][i];
    *reinterpret_cast<ushort4*>(op + (long)(c0 + i) * ldout + r0 + j) = w;
}

// ---------------------------------------------------------------------------
// vmean_part: partial column sums of Vh over l. part[(bl*8+seg)][c] =
//   sum_{l in [seg*64, seg*64+64)} Vh[bl][l][c]   (fp32)
// ---------------------------------------------------------------------------
__global__ __launch_bounds__(256) void vmean_part(
    const unsigned short* __restrict__ Vh, float* __restrict__ part)
{
    int bl = blockIdx.x, seg = blockIdx.y;
    const unsigned short* p = Vh + (long)bl * SEQ * HD + (long)seg * 64 * HD;
    int c = threadIdx.x * 4;
    float s0 = 0.f, s1 = 0.f, s2 = 0.f, s3 = 0.f;
    for (int l = 0; l < 64; ++l) {
        ushort4 v = *reinterpret_cast<const ushort4*>(p + (long)l * HD + c);
        s0 += b2f(v.x); s1 += b2f(v.y); s2 += b2f(v.z); s3 += b2f(v.w);
    }
    float4 o = {s0, s1, s2, s3};
    *reinterpret_cast<float4*>(part + (long)(bl * 8 + seg) * HD + c) = o;
}

// ---------------------------------------------------------------------------
// vmean_reduce: Vm[bl][c] = bf16( (1/SEQ) * sum_seg part[bl*8+seg][c] )
// ---------------------------------------------------------------------------
__global__ __launch_bounds__(256) void vmean_reduce(
    const float* __restrict__ part, unsigned short* __restrict__ Vm)
{
    int bl = blockIdx.x;
    int c = threadIdx.x * 4;
    const float* p = part + (long)bl * 8 * HD + c;
    float s0 = 0.f, s1 = 0.f, s2 = 0.f, s3 = 0.f;
#pragma unroll
    for (int seg = 0; seg < 8; ++seg) {
        float4 v = *reinterpret_cast<const float4*>(p + (long)seg * HD);
        s0 += v.x; s1 += v.y; s2 += v.z; s3 += v.w;
    }
    const float inv = 1.0f / SEQ;
    ushort4 o;
    o.x = f2b(s0 * inv); o.y = f2b(s1 * inv);
    o.z = f2b(s2 * inv); o.w = f2b(s3 * inv);
    *reinterpret_cast<ushort4*>(Vm + (long)bl * HD + c) = o;
}

// ---------------------------------------------------------------------------
// fix_mask: for padding-masked query rows, Vatt row := Vm row (uniform
// attention over ALL keys, per reference semantics).
// ---------------------------------------------------------------------------
__global__ __launch_bounds__(256) void fix_mask(
    const unsigned short* __restrict__ Vm, unsigned short* __restrict__ Vatt,
    const int* __restrict__ maskc, int b0)
{
    int row = blockIdx.x;              // bl*SEQ + l
    int bl = row >> 9, l = row & (SEQ - 1);
    if (maskc[(long)(b0 + bl) * SEQ + l] == 0) return;
    int c = threadIdx.x * 4;
    ushort4 v = *reinterpret_cast<const ushort4*>(Vm + (long)bl * HD + c);
    *reinterpret_cast<ushort4*>(Vatt + (long)row * HD + c) = v;
}

// ---------------------------------------------------------------------------
// Pure-bf16 MFMA GEMM (r9-green): C = scale*A.Bt (+bias, relu), 128x128 tile,
// global_load_lds width-16 staging. Batched via blockIdx.z.
// ---------------------------------------------------------------------------
template<bool BIAS, bool RELU, bool OUTBF16>
__global__ __launch_bounds__(256) void gemm_bt(
    const unsigned short* __restrict__ A, int lda,
    const unsigned short* __restrict__ B, int ldb,
    void* __restrict__ Cv, int ldc,
    const float* __restrict__ bias, float scale, int K, int Hdiv,
    long sAb, long sAh, long sAz,
    long sBb, long sBh, long sBz,
    long sCb, long sCh, long sCz)
{
    const int m0 = blockIdx.y * 128;
    const int n0 = blockIdx.x * 128;
    int z  = blockIdx.z;
    int bb = z / Hdiv, hh = z % Hdiv;
    const unsigned short* Ab = A + bb * sAb + hh * sAh + (long)z * sAz;
    const unsigned short* Bb = B + bb * sBb + hh * sBh + (long)z * sBz;
    long coff = bb * sCb + hh * sCh + (long)z * sCz;

    __shared__ unsigned short As[128 * 32];
    __shared__ unsigned short Bs[128 * 32];

    const int tid  = threadIdx.x;
    const int lane = tid & 63;
    const int wave = tid >> 6;
    const int wm   = (wave >> 1) * 64;
    const int wn   = (wave & 1) * 64;
    const int lm   = lane & 15;
    const int kq   = (lane >> 4) * 8;

    f32x4 acc[4][4] = {};

    for (int k0 = 0; k0 < K; k0 += 32) {
#pragma unroll
        for (int it = 0; it < 2; ++it) {
            int id = tid + it * 256;
            int r  = id >> 2;
            int c8 = (id & 3) * 8;
            const unsigned short* gA = Ab + (long)(m0 + r) * lda + k0 + c8;
            const unsigned short* gB = Bb + (long)(n0 + r) * ldb + k0 + c8;
#if HAS_ASYNC
            unsigned short* lA = &As[(size_t)(it * 256 + wave * 64) * 8];
            unsigned short* lB = &Bs[(size_t)(it * 256 + wave * 64) * 8];
            __builtin_amdgcn_global_load_lds(
                (const __attribute__((address_space(1))) void*)gA,
                (__attribute__((address_space(3))) void*)lA, 16, 0, 0);
            __builtin_amdgcn_global_load_lds(
                (const __attribute__((address_space(1))) void*)gB,
                (__attribute__((address_space(3))) void*)lB, 16, 0, 0);
#else
            *reinterpret_cast<uint4*>(&As[(size_t)id * 8]) =
                *reinterpret_cast<const uint4*>(gA);
            *reinterpret_cast<uint4*>(&Bs[(size_t)id * 8]) =
                *reinterpret_cast<const uint4*>(gB);
#endif
        }
        __syncthreads();

        short8 af[4], bfr[4];
#pragma unroll
        for (int i = 0; i < 4; ++i)
            af[i] = *reinterpret_cast<const short8*>(&As[(wm + i * 16 + lm) * 32 + kq]);
#pragma unroll
        for (int j = 0; j < 4; ++j)
            bfr[j] = *reinterpret_cast<const short8*>(&Bs[(wn + j * 16 + lm) * 32 + kq]);
#pragma unroll
        for (int i = 0; i < 4; ++i)
#pragma unroll
            for (int j = 0; j < 4; ++j)
                acc[i][j] = __builtin_amdgcn_mfma_f32_16x16x32_bf16(af[i], bfr[j], acc[i][j], 0, 0, 0);
        __syncthreads();
    }

#pragma unroll
    for (int j = 0; j < 4; ++j) {
        int col  = n0 + wn + j * 16 + lm;
        float bv = 0.f;
        if (BIAS) bv = bias[col];
#pragma unroll
        for (int i = 0; i < 4; ++i) {
#pragma unroll
            for (int r = 0; r < 4; ++r) {
                int row = m0 + wm + i * 16 + (lane >> 4) * 4 + r;
                float v = acc[i][j][r] * scale + bv;
                if (RELU) v = fmaxf(v, 0.f);
                long idx = coff + (long)row * ldc + col;
                if (OUTBF16) reinterpret_cast<unsigned short*>(Cv)[idx] = f2b(v);
                else         reinterpret_cast<float*>(Cv)[idx] = v;
            }
        }
    }
}

// ---------------------------------------------------------------------------
// flash_attn staging helpers: linear LDS dest (gload_lds requirement) +
// pre-swizzled global source; fallback path stores to swizzled LDS address.
// Fixed trip counts (8 / 4) so the compiler can statically count vmcnt.
// ---------------------------------------------------------------------------
__device__ __forceinline__ void stage_k32(
    unsigned short* __restrict__ buf, const unsigned short* __restrict__ Ak,
    int kc, int tid, int wave)
{
#pragma unroll
    for (int it = 0; it < 8; ++it) {
        int id = tid + it * 256;
#if HAS_ASYNC
        int U = swzb(id * 16);
        const unsigned short* g = Ak + (long)(U >> 6) * HD + kc * 32 + ((U >> 4) & 3) * 8;
        unsigned short* l = buf + (size_t)(it * 256 + wave * 64) * 8;
        __builtin_amdgcn_global_load_lds(
            (const __attribute__((address_space(1))) void*)g,
            (__attribute__((address_space(3))) void*)l, 16, 0, 0);
#else
        const unsigned short* g = Ak + (long)(id >> 2) * HD + kc * 32 + (id & 3) * 8;
        *reinterpret_cast<uint4*>((char*)buf + swzb(id * 16)) =
            *reinterpret_cast<const uint4*>(g);
#endif
    }
}

__device__ __forceinline__ void stage_v32(
    unsigned short* __restrict__ buf, const unsigned short* __restrict__ Av,
    int chunk, int tid, int wave)
{
#pragma unroll
    for (int it = 0; it < 4; ++it) {
        int id = tid + it * 256;
#if HAS_ASYNC
        int U = swzb(id * 16);
        const unsigned short* g = Av + (long)(U >> 6) * SEQ + chunk * 32 + ((U >> 4) & 3) * 8;
        unsigned short* l = buf + (size_t)(it * 256 + wave * 64) * 8;
        __builtin_amdgcn_global_load_lds(
            (const __attribute__((address_space(1))) void*)g,
            (__attribute__((address_space(3))) void*)l, 16, 0, 0);
#else
        const unsigned short* g = Av + (long)(id >> 2) * SEQ + chunk * 32 + (id & 3) * 8;
        *reinterpret_cast<uint4*>((char*)buf + swzb(id * 16)) =
            *reinterpret_cast<const uint4*>(g);
#endif
    }
}

// ---------------------------------------------------------------------------
// Fused flash attention. Grid 8*nbh blocks; balanced XCD-affinity swizzle:
//   x=L&7, m=L>>3, qt=m&7, z=x+8*(m>>3)  (nbh%8==0)
// Phase 1: double-buffered stage-ahead (stage kc+1 || compute kc, one
//   barrier/iter); full 512-row staging (fixed vmcnt count); causal MFMA
//   bound NT. Ks reads XOR-swizzled (conflict-free).
// Softmax: causal-only masking; deferred normalization; P packed to bf16
//   regs right after exp so S[32] dies before O[16] goes live.
// Phase 2: CAUSAL bound KC = 2*(qt+1) chunks of 32 keys, V double-buffered
//   in the low 32KB of Ks (stage-ahead, 1 barrier/iter), swizzled reads.
// Epilogue: store only unmasked rows (masked rows owned by fix_mask).
// ---------------------------------------------------------------------------
__global__ __launch_bounds__(256, 2) void flash_attn(
    const unsigned short* __restrict__ Qh,
    const unsigned short* __restrict__ Kh,
    const unsigned short* __restrict__ VhT,
    unsigned short* __restrict__ Vatt,
    const int* __restrict__ maskc, int bh0, float scale, int nbh)
{
    const int tid  = threadIdx.x;
    const int lane = tid & 63;
    const int wave = tid >> 6;
    const int lm   = lane & 15;
    const int qg   = lane >> 4;
    const int kq   = qg * 8;

    const int L = blockIdx.x;
    int z, qt;
    if ((nbh & 7) == 0) {
        int x = L & 7, m = L >> 3;
        qt = m & 7;
        z  = x + 8 * (m >> 3);
    } else {
        z = L % nbh; qt = L / nbh;
    }
    const int b_l = z >> 2, h = z & 3;
    const int m0  = qt * 64;
    const int wq0 = m0 + wave * 16;
    const long qkbase = (long)b_l * SEQ * HD + (long)h * DM;
    const unsigned short* Aq = Qh + qkbase;
    const unsigned short* Ak = Kh + qkbase;
    const unsigned short* Av = VhT + (long)b_l * SEQ * HD + (long)h * SEQ * DM;
    unsigned short* Ov = Vatt + qkbase;
    const int bglob = (bh0 + z) >> 2;

    __shared__ unsigned short Ks[2 * SEQ * 32];             // 64 KiB dbuf
    __shared__ __align__(16) unsigned short Pw[4][16][40];  // 5 KiB

    f32x4 S[32] = {};
    const int NT = (m0 >> 4) + wave + 1;     // causal tile bound (wave-uniform)

    // ---- Phase 1: S = Q.K^T over 8 d-chunks of 32, stage-ahead dbuf ----
    stage_k32(Ks, Ak, 0, tid, wave);         // prologue: chunk 0 -> buf0
    __syncthreads();
    for (int kc = 0; kc < 8; ++kc) {
        unsigned short* cur = (kc & 1) ? (Ks + SEQ * 32) : Ks;
        unsigned short* nxt = (kc & 1) ? Ks : (Ks + SEQ * 32);
        short8 qf = *reinterpret_cast<const short8*>(
            Aq + (long)(wq0 + lm) * HD + kc * 32 + kq);
        if (kc < 7) {
            stage_k32(nxt, Ak, kc + 1, tid, wave);   // flies under compute
        } else {
            // last iter: prefetch V chunk 0 into buf0's low half instead
            stage_v32(Ks, Av, 0, tid, wave);         // covered by compute+softmax
        }
#pragma unroll
        for (int nt = 0; nt < 32; ++nt) {
            if (nt < NT) {
                int row = nt * 16 + lm;
                short8 bf = *reinterpret_cast<const short8*>(
                    (const char*)cur + swzb(row * 64 + qg * 16));
                S[nt] = __builtin_amdgcn_mfma_f32_16x16x32_bf16(qf, bf, S[nt], 0, 0, 0);
            }
        }
        __syncthreads();   // drains this iter's stage (covered by the MFMAs)
    }

    // ---- Softmax in registers (V chunk-0 prefetch still in flight) ----
    // Causal masking only: padding-masked rows compute a normal (discarded)
    // causal softmax. Deferred normalization: e = exp(s - m) unnormalized;
    // O scaled by 1/sum in the epilogue.
    int   qrow[4];
    bool  rowm[4];
    float mx[4], sm[4];
#pragma unroll
    for (int r = 0; r < 4; ++r) {
        int q = wq0 + qg * 4 + r;
        qrow[r] = q;
        rowm[r] = maskc[bglob * SEQ + q] != 0;
        mx[r] = -3.4e38f;
    }
#pragma unroll
    for (int nt = 0; nt < 32; ++nt) {
        int k = nt * 16 + lm;
#pragma unroll
        for (int r = 0; r < 4; ++r) {
            float v = S[nt][r] * scale;
            if (k > qrow[r]) v = NEGV;
            S[nt][r] = v;
            mx[r] = fmaxf(mx[r], v);
        }
    }
#pragma unroll
    for (int r = 0; r < 4; ++r) {
#pragma unroll
        for (int off = 8; off >= 1; off >>= 1)
            mx[r] = fmaxf(mx[r], __shfl_xor(mx[r], off));
        sm[r] = 0.f;
    }
    uint32_t pk[32][2];   // bf16x2-packed unnormalized P (64 VGPRs)
#pragma unroll
    for (int nt = 0; nt < 32; ++nt) {
        float e0 = __expf(S[nt][0] - mx[0]);
        float e1 = __expf(S[nt][1] - mx[1]);
        float e2 = __expf(S[nt][2] - mx[2]);
        float e3 = __expf(S[nt][3] - mx[3]);
        sm[0] += e0; sm[1] += e1; sm[2] += e2; sm[3] += e3;
        pk[nt][0] = (uint32_t)f2b(e0) | ((uint32_t)f2b(e1) << 16);
        pk[nt][1] = (uint32_t)f2b(e2) | ((uint32_t)f2b(e3) << 16);
    }
#pragma unroll
    for (int r = 0; r < 4; ++r) {
#pragma unroll
        for (int off = 8; off >= 1; off >>= 1)
            sm[r] += __shfl_xor(sm[r], off);
        sm[r] = 1.0f / sm[r];    // applied to O in the epilogue
    }

    // ---- Phase 2: O = P.V, causal KC chunks of 32 keys, double-buffered V --
    // Keys >= (qt+1)*64 have e == 0.0f exactly (exp underflow) -> skip.
    // KC is block-uniform (qt uniform), so guarded __syncthreads is safe.
    unsigned short* Vb0 = Ks;            // 16 KiB (low half of buf0)
    unsigned short* Vb1 = Ks + 8192;     // 16 KiB
    const int KC = 2 * (qt + 1);
    f32x4 O[16] = {};
#pragma unroll
    for (int kc2 = 0; kc2 < 16; ++kc2) {
        if (kc2 < KC) {
            unsigned short* Vcur = (kc2 & 1) ? Vb1 : Vb0;
            __syncthreads();     // drains staging of chunk kc2 (+ prior reads)
            if (kc2 + 1 < KC) {  // prefetch chunk kc2+1 into the other buffer
                unsigned short* Vnext = (kc2 & 1) ? Vb0 : Vb1;
                stage_v32(Vnext, Av, kc2 + 1, tid, wave);
            }
            // P chunk (32 keys): packed regs -> wave-private LDS (A-layout src)
#pragma unroll
            for (int t = 0; t < 2; ++t) {
                int nt = kc2 * 2 + t;
#pragma unroll
                for (int r = 0; r < 4; ++r)
                    Pw[wave][qg * 4 + r][t * 16 + lm] =
                        (unsigned short)(pk[nt][r >> 1] >> ((r & 1) * 16));
            }
            short8 pf = *reinterpret_cast<const short8*>(&Pw[wave][lm][kq]);
#pragma unroll
            for (int nt2 = 0; nt2 < 16; ++nt2) {
                int row = nt2 * 16 + lm;
                short8 vf = *reinterpret_cast<const short8*>(
                    (const char*)Vcur + swzb(row * 64 + qg * 16));
                O[nt2] = __builtin_amdgcn_mfma_f32_16x16x32_bf16(pf, vf, O[nt2], 0, 0, 0);
            }
        }
    }

    // ---- epilogue (apply deferred 1/sum; skip masked rows: fix_mask owns) --
#pragma unroll
    for (int nt2 = 0; nt2 < 16; ++nt2) {
#pragma unroll
        for (int r = 0; r < 4; ++r) {
            if (!rowm[r]) {
                int l = wq0 + qg * 4 + r;
                Ov[(long)l * HD + nt2 * 16 + lm] = f2b(O[nt2][r] * sm[r]);
            }
        }
    }
}

// ---------------------------------------------------------------------------
// LN1: x = bf16 AttO + fp32 Q + fp32 pe  ->  fp32 Xf AND bf16 Xb
// ---------------------------------------------------------------------------
__global__ __launch_bounds__(256) void ln1_kernel(
    const unsigned short* __restrict__ AttO, const float* __restrict__ Q,
    const float* __restrict__ pe,
    const float* __restrict__ gamma, const float* __restrict__ beta,
    float* __restrict__ outf, unsigned short* __restrict__ outb)
{
    int row  = blockIdx.x * 4 + (threadIdx.x >> 6);
    int lane = threadIdx.x & 63;
    long base = (long)row * DM + lane * 4;
    ushort4 a = *reinterpret_cast<const ushort4*>(AttO + base);
    float4 qv = *reinterpret_cast<const float4*>(Q + base);
    float4 pv = *reinterpret_cast<const float4*>(pe + (base & PE_MASK));
    float x[4] = {b2f(a.x) + qv.x + pv.x, b2f(a.y) + qv.y + pv.y,
                  b2f(a.z) + qv.z + pv.z, b2f(a.w) + qv.w + pv.w};
    float s = x[0] + x[1] + x[2] + x[3];
#pragma unroll
    for (int off = 32; off > 0; off >>= 1) s += __shfl_xor(s, off);
    float mu = s * (1.0f / DM);
    float vs = 0.f;
#pragma unroll
    for (int t = 0; t < 4; ++t) { float d = x[t] - mu; vs += d * d; }
#pragma unroll
    for (int off = 32; off > 0; off >>= 1) vs += __shfl_xor(vs, off);
    float inv = rsqrtf(vs * (1.0f / DM) + 1e-5f);
    int d0 = lane * 4;
    float4 g = *reinterpret_cast<const float4*>(gamma + d0);
    float4 bt = *reinterpret_cast<const float4*>(beta + d0);
    float4 o;
    o.x = (x[0] - mu) * inv * g.x + bt.x;
    o.y = (x[1] - mu) * inv * g.y + bt.y;
    o.z = (x[2] - mu) * inv * g.z + bt.z;
    o.w = (x[3] - mu) * inv * g.w + bt.w;
    *reinterpret_cast<float4*>(outf + base) = o;
    ushort4 ob;
    ob.x = f2b(o.x); ob.y = f2b(o.y); ob.z = f2b(o.z); ob.w = f2b(o.w);
    *reinterpret_cast<ushort4*>(outb + base) = ob;
}

// ---------------------------------------------------------------------------
// LN2: x = fp32 F + fp32 X  ->  FP32 out
// ---------------------------------------------------------------------------
__global__ __launch_bounds__(256) void ln2_kernel(
    const float* __restrict__ F, const float* __restrict__ X,
    const float* __restrict__ gamma, const float* __restrict__ beta,
    float* __restrict__ out)
{
    int row  = blockIdx.x * 4 + (threadIdx.x >> 6);
    int lane = threadIdx.x & 63;
    long base = (long)row * DM + lane * 4;
    float4 a = *reinterpret_cast<const float4*>(F + base);
    float4 c = *reinterpret_cast<const float4*>(X + base);
    float x[4] = {a.x + c.x, a.y + c.y, a.z + c.z, a.w + c.w};
    float s = x[0] + x[1] + x[2] + x[3];
#pragma unroll
    for (int off = 32; off > 0; off >>= 1) s += __shfl_xor(s, off);
    float mu = s * (1.0f / DM);
    float vs = 0.f;
#pragma unroll
    for (int t = 0; t < 4; ++t) { float d = x[t] - mu; vs += d * d; }
#pragma unroll
    for (int off = 32; off > 0; off >>= 1) vs += __shfl_xor(vs, off);
    float inv = rsqrtf(vs * (1.0f / DM) + 1e-5f);
    int d0 = lane * 4;
    float4 g = *reinterpret_cast<const float4*>(gamma + d0);
    float4 bt = *reinterpret_cast<const float4*>(beta + d0);
    float4 o;
    o.x = (x[0] - mu) * inv * g.x + bt.x;
    o.y = (x[1] - mu) * inv * g.y + bt.y;
    o.z = (x[2] - mu) * inv * g.z + bt.z;
    o.w = (x[3] - mu) * inv * g.w + bt.w;
    *reinterpret_cast<float4*>(out + base) = o;
}

// ---------------------------------------------------------------------------
extern "C" void kernel_launch(void* const* d_in, const int* in_sizes, int n_in,
                              void* d_out, int out_size, void* d_ws, size_t ws_size,
                              hipStream_t stream)
{
    const float* Q  = (const float*)d_in[0];
    const float* Ki = (const float*)d_in[1];
    const float* Vi = (const float*)d_in[2];
    const unsigned char* mask_raw = (const unsigned char*)d_in[3];
    const float* pe = (const float*)d_in[4];
    const float* Wq = (const float*)d_in[5];
    const float* Wk = (const float*)d_in[6];
    const float* Wv = (const float*)d_in[7];
    const float* Wo = (const float*)d_in[8];
    const float* w1 = (const float*)d_in[9];
    const float* b1 = (const float*)d_in[10];
    const float* w2 = (const float*)d_in[11];
    const float* b2 = (const float*)d_in[12];
    const float* gamma = (const float*)d_in[13];
    const float* beta  = (const float*)d_in[14];
    float* out = (float*)d_out;

    const size_t MiB = 1048576;
    char* ws = (char*)d_ws;

    // ---- adaptive chunk size: footprint = 59 + max(5*CB + 34KB*CB, 24) MiB --
    int CB = 1;
    for (int cb = 32; cb >= 1; cb >>= 1) {
        size_t scr_sz = (size_t)(5 * cb) * MiB + (size_t)cb * 34816;
        if (scr_sz < 24 * MiB) scr_sz = 24 * MiB;
        if ((59 * MiB + scr_sz) <= ws_size) { CB = cb; break; }
    }
    const int NCH = NB / CB;

    // ---- fixed low regions ----
    unsigned short* WqT  = (unsigned short*)(ws);                 // 512 KiB each
    unsigned short* WkT  = WqT + 262144;
    unsigned short* WvT  = WkT + 262144;
    unsigned short* WoT  = WvT + 262144;
    unsigned short* w1b  = (unsigned short*)(ws + 2 * MiB);       // 128 KiB
    unsigned short* w2b  = w1b + 65536;                           // 128 KiB
    int*            maskc = (int*)(ws + 2 * MiB + 262144);        // 64 KiB
    unsigned short* Qp   = (unsigned short*)(ws + 3 * MiB);       // 8 MiB bf16
    unsigned short* Kp   = (unsigned short*)(ws + 11 * MiB);      // 8 MiB
    unsigned short* Vp   = (unsigned short*)(ws + 19 * MiB);      // 8 MiB
    unsigned short* AttO = (unsigned short*)(ws + 27 * MiB);      // 8 MiB
    unsigned short* Xb   = (unsigned short*)(ws + 35 * MiB);      // 8 MiB
    float*          Xf   = (float*)(ws + 43 * MiB);               // 16 MiB
    char*           scr  = ws + 59 * MiB;
    // chunk scratch (CB MiB each)
    unsigned short* Qh   = (unsigned short*)(scr);
    unsigned short* Kh   = (unsigned short*)(scr + (size_t)CB * MiB);
    unsigned short* Vh   = (unsigned short*)(scr + (size_t)2 * CB * MiB);
    unsigned short* VhT  = (unsigned short*)(scr + (size_t)3 * CB * MiB);
    unsigned short* Vatt = (unsigned short*)(scr + (size_t)4 * CB * MiB);
    // vmean scratch (per chunk; dead at tail-alias time)
    float*          part = (float*)(scr + (size_t)5 * CB * MiB);            // CB*32 KiB
    unsigned short* Vm   = (unsigned short*)(scr + (size_t)5 * CB * MiB
                                             + (size_t)CB * 8 * HD * 4);    // CB*2 KiB
    // tail aliases over scratch (chunk buffers dead by then)
    unsigned short* H1   = (unsigned short*)(scr);                // 8 MiB bf16
    float*          Ff   = (float*)(scr + 8 * MiB);               // 16 MiB fp32

    const float scale = (float)(1.0 / (16.0 + 1e-6));
    const long CROWS = (long)CB * SEQ;
    const long CBELT = (long)CB * MiB / 2;     // chunk-buffer stride, elements

    // 0. prep (merged): mask, weight transposes/conversions, fused PE-add
    mask_canon<<<64, 256, 0, stream>>>(mask_raw, maskc);
    transpose_f2b3<<<dim3(32, 8, 3), 256, 0, stream>>>(Wq, Wk, Wv, WqT, HD, DM, 262144);
    transpose_f2b<<<dim3(8, 32, 1), 256, 0, stream>>>(Wo, WoT, DM, HD);
    conv2<<<128, 256, 0, stream>>>(w1, w2, w1b, w2b);
    addpe3<<<12288, 256, 0, stream>>>(Q, Ki, Vi, pe, Qp, Kp, Vp);

    // 1. attention in NCH chunks of CB batches
    for (int c = 0; c < NCH; ++c) {
        const long r0   = (long)c * CROWS;
        const int  bh0  = c * CB * NH;
        const int  gy   = (int)(CROWS / 128);
        const int  nbh  = CB * NH;

        // all 3 projections in ONE dispatch (z=0:Q, 1:K, 2:V)
        gemm_bt<false, false, true><<<dim3(8, gy, 3), 256, 0, stream>>>(
            Qp + r0 * DM, DM, WqT, DM, Qh, HD, nullptr, 1.f, DM,
            1, 4194304, 0, 0, 262144, 0, 0, CBELT, 0, 0);

        // per-head V transpose: VhT[bl][h][d][l] = Vh[bl][l][h*256+d]
        transpose_bf16<<<dim3(8, 16, CB * NH), 256, 0, stream>>>(
            Vh, VhT, HD, SEQ, (long)SEQ * HD, DM, (long)SEQ * HD, (long)SEQ * DM, NH);

        // per-batch V column means (for padding-masked rows)
        vmean_part<<<dim3(CB, 8), 256, 0, stream>>>(Vh, part);
        vmean_reduce<<<CB, 256, 0, stream>>>(part, Vm);

        // fused attention (balanced XCD swizzle + dbuf stage-ahead + T2 swz)
        flash_attn<<<dim3(8 * nbh, 1, 1), 256, 0, stream>>>(
            Qh, Kh, VhT, Vatt, maskc, bh0, scale, nbh);

        // masked rows: Vatt row := Vm row (uniform attention over all keys)
        fix_mask<<<(int)CROWS, 256, 0, stream>>>(Vm, Vatt, maskc, c * CB);

        // output projection for this chunk -> AttO rows [r0, r0+CROWS)
        gemm_bt<false, false, true><<<dim3(2, gy, 1), 256, 0, stream>>>(
            Vatt, HD, WoT, HD, AttO + r0 * DM, DM, nullptr, 1.f, HD,
            1, 0,0,0, 0,0,0, 0,0,0);
    }

    // 2. LN1: X = LN(Q + pe + AttO) -> fp32 Xf + bf16 Xb
    ln1_kernel<<<4096, 256, 0, stream>>>(AttO, Q, pe, gamma, beta, Xf, Xb);

    // 3. FFN1: H1 = relu(Xb @ w1^T + b1) -> bf16
    gemm_bt<true, true, true><<<dim3(2, 128, 1), 256, 0, stream>>>(
        Xb, DM, w1b, DM, H1, DM, b1, 1.f, DM, 1, 0,0,0, 0,0,0, 0,0,0);
    // 4. FFN2: F = H1 @ w2^T + b2 -> fp32
    gemm_bt<true, false, false><<<dim3(2, 128, 1), 256, 0, stream>>>(
        H1, DM, w2b, DM, Ff, DM, b2, 1.f, DM, 1, 0,0,0, 0,0,0, 0,0,0);

    // 5. LN2: out = LN(F + X) -> FP32
    ln2_kernel<<<4096, 256, 0, stream>>>(Ff, Xf, gamma, beta, out);
}

// Round 5
// 345.886 us; speedup vs baseline: 1.1252x; 1.0064x over previous
//
#include <hip/hip_runtime.h>
#include <stdint.h>

// ---------------------------------------------------------------------------
// TransformerBlock: B=32, L=512, D=256, H=4.
// Inputs fp32 (dict order); OUTPUT fp32.
// bf16 MFMA GEMMs + fused flash attention:
//   - XCD-affinity swizzle; r14: complementary qt pairing (consecutive
//     same-XCD blocks get qt and 7-qt -> equal work, decorrelated phases)
//   - LDS XOR-swizzle swzb (works at both 64B and 128B row strides)
//   - phase-1: causal dbuf stage-ahead (it<=qt); phase-2: 64-key V tiles
//     (32KB dbuf halves of Ks) -> barriers avg 9 -> 4.5
//   - r14: softmax scale folded into Q-projection (gemm scale applies to
//     blockIdx.z==0 only) with log2e premul -> raw v_exp_f32 (trans pipe),
//     removing 256 VALU muls/lane from flash
//   - T5 s_setprio around MFMA clusters
//   - masked rows via vmean/fix_mask (uniform attention = V column mean)
//   - deferred softmax normalization + early bf16 P-packing
//   - __launch_bounds__(256,2): ~240-reg peak, no spill, 2 blocks/CU.
// ws = 59 + 5*CB MiB + CB*34KB (CB=32 -> single chunk at ws=256MiB).
// ---------------------------------------------------------------------------
#define SEQ   512
#define DM    256
#define NB    32
#define NH    4
#define HD    (NH * DM)           // 1024
#define PE_MASK (SEQ * DM - 1)    // 131071
#define NEGV  (-4294967295.0f)

typedef __attribute__((ext_vector_type(8))) short short8;   // 8 x bf16
typedef __attribute__((ext_vector_type(4))) float f32x4;    // MFMA accumulator

#if defined(__has_builtin)
#if __has_builtin(__builtin_amdgcn_global_load_lds)
#define HAS_ASYNC 1
#endif
#endif
#ifndef HAS_ASYNC
#define HAS_ASYNC 0
#endif

__device__ __forceinline__ float b2f(unsigned short u) {
    return __uint_as_float(((uint32_t)u) << 16);
}
__device__ __forceinline__ unsigned short f2b(float f) {
    uint32_t u = __float_as_uint(f);
    u += 0x7fffu + ((u >> 16) & 1u);   // RNE
    return (unsigned short)(u >> 16);
}
// raw v_exp_f32: 2^x on the transcendental pipe (input pre-scaled by log2e)
__device__ __forceinline__ float fast_exp2(float x) {
    float r;
    asm("v_exp_f32 %0, %1" : "=v"(r) : "v"(x));
    return r;
}

// LDS bank swizzle: involution XORing byte bits [6:4] with bits [9:7].
// 64B-row tiles (K): row=b>>6, group=(4*(row&1)+qg)^((row>>1)&7) -> 2/group.
// 128B-row tiles (V): row=b>>7, group=(t*4+qg)^(row&7)           -> 2/group.
__device__ __forceinline__ int swzb(int b) {
    return b ^ (((b >> 7) & 7) << 4);
}

// ---------------------------------------------------------------------------
// Canonicalize mask to int32 (auto-detect uint8 / int32 / int64) — r7-green.
// ---------------------------------------------------------------------------
__global__ __launch_bounds__(256) void mask_canon(
    const unsigned char* __restrict__ raw, int* __restrict__ canon)
{
    __shared__ int enc_byte, enc_odd;
    int tid = threadIdx.x;
    if (tid == 0) { enc_byte = 0; enc_odd = 0; }
    __syncthreads();
    if (tid < 255 && raw[tid * 4 + 1]) atomicOr(&enc_byte, 1);
    if (tid < 128 && ((const int*)raw)[tid * 2 + 1]) atomicOr(&enc_odd, 1);
    __syncthreads();
    int i = blockIdx.x * 256 + tid;
    int v;
    if (enc_byte)      v = (raw[i] != 0);
    else if (enc_odd)  v = (((const int*)raw)[i] != 0);
    else               v = ((((const int*)raw)[i * 2] | ((const int*)raw)[i * 2 + 1]) != 0);
    canon[i] = v;
}

// ---------------------------------------------------------------------------
// addpe3: Q/K/V + pe -> bf16, one dispatch (seg = blk>>12).
// ---------------------------------------------------------------------------
__global__ __launch_bounds__(256) void addpe3(
    const float* __restrict__ Q, const float* __restrict__ K,
    const float* __restrict__ V, const float* __restrict__ pe,
    unsigned short* __restrict__ Qp, unsigned short* __restrict__ Kp,
    unsigned short* __restrict__ Vp)
{
    int blk = blockIdx.x;                  // 0..12287
    int seg = blk >> 12;
    const float* X = (seg == 0) ? Q : (seg == 1) ? K : V;
    unsigned short* O = (seg == 0) ? Qp : (seg == 1) ? Kp : Vp;
    long i = (long)((blk & 4095) * 256 + threadIdx.x) * 4;
    float4 x = *reinterpret_cast<const float4*>(X + i);
    float4 p = *reinterpret_cast<const float4*>(pe + (i & PE_MASK));
    ushort4 o;
    o.x = f2b(x.x + p.x); o.y = f2b(x.y + p.y);
    o.z = f2b(x.z + p.z); o.w = f2b(x.w + p.w);
    *reinterpret_cast<ushort4*>(O + i) = o;
}

// ---------------------------------------------------------------------------
// conv2: w1,w2 fp32 -> bf16, one dispatch (128 blocks, seg = blk>>6).
// ---------------------------------------------------------------------------
__global__ __launch_bounds__(256) void conv2(
    const float* __restrict__ w1, const float* __restrict__ w2,
    unsigned short* __restrict__ o1, unsigned short* __restrict__ o2)
{
    int blk = blockIdx.x;
    const float* in = (blk < 64) ? w1 : w2;
    unsigned short* out = (blk < 64) ? o1 : o2;
    long i = (long)((blk & 63) * 256 + threadIdx.x) * 4;
    float4 x = *reinterpret_cast<const float4*>(in + i);
    ushort4 o;
    o.x = f2b(x.x); o.y = f2b(x.y); o.z = f2b(x.z); o.w = f2b(x.w);
    *reinterpret_cast<ushort4*>(out + i) = o;
}

// ---------------------------------------------------------------------------
// Transpose fp32 -> bf16: out[c][r] = bf16(in[r][c]); 32x32 tiles.
// z selects among 3 same-shape inputs (Wq/Wk/Wv), out spaced by outStride.
// ---------------------------------------------------------------------------
__global__ __launch_bounds__(256) void transpose_f2b3(
    const float* __restrict__ in0, const float* __restrict__ in1,
    const float* __restrict__ in2, unsigned short* __restrict__ out,
    int ldin, int ldout, long outStride)
{
    int z = blockIdx.z;
    const float* in = (z == 0) ? in0 : (z == 1) ? in1 : in2;
    unsigned short* op = out + z * outStride;
    __shared__ unsigned short tile[32][33];
    int r0 = blockIdx.y * 32, c0 = blockIdx.x * 32;
    int i = threadIdx.x >> 3;
    int j = (threadIdx.x & 7) * 4;
    float4 v = *reinterpret_cast<const float4*>(in + (long)(r0 + i) * ldin + c0 + j);
    tile[i][j + 0] = f2b(v.x); tile[i][j + 1] = f2b(v.y);
    tile[i][j + 2] = f2b(v.z); tile[i][j + 3] = f2b(v.w);
    __syncthreads();
    ushort4 w;
    w.x = tile[j + 0][i]; w.y = tile[j + 1][i]; w.z = tile[j + 2][i]; w.w = tile[j + 3][i];
    *reinterpret_cast<ushort4*>(op + (long)(c0 + i) * ldout + r0 + j) = w;
}

__global__ __launch_bounds__(256) void transpose_f2b(
    const float* __restrict__ in, unsigned short* __restrict__ out,
    int ldin, int ldout)
{
    __shared__ unsigned short tile[32][33];
    int r0 = blockIdx.y * 32, c0 = blockIdx.x * 32;
    int i = threadIdx.x >> 3;
    int j = (threadIdx.x & 7) * 4;
    float4 v = *reinterpret_cast<const float4*>(in + (long)(r0 + i) * ldin + c0 + j);
    tile[i][j + 0] = f2b(v.x); tile[i][j + 1] = f2b(v.y);
    tile[i][j + 2] = f2b(v.z); tile[i][j + 3] = f2b(v.w);
    __syncthreads();
    ushort4 w;
    w.x = tile[j + 0][i]; w.y = tile[j + 1][i]; w.z = tile[j + 2][i]; w.w = tile[j + 3][i];
    *reinterpret_cast<ushort4*>(out + (long)(c0 + i) * ldout + r0 + j) = w;
}

// ---------------------------------------------------------------------------
// Batched bf16 transpose (per-head V): out[c][r] = in[r][c]
// ---------------------------------------------------------------------------
__global__ __launch_bounds__(256) void transpose_bf16(
    const unsigned short* __restrict__ in, unsigned short* __restrict__ out,
    int ldin, int ldout, long sInB, long sInH, long sOutB, long sOutH, int Hdiv)
{
    int z = blockIdx.z; int b = z / Hdiv; int h = z % Hdiv;
    const unsigned short* ip = in + b * sInB + h * sInH;
    unsigned short* op = out + b * sOutB + h * sOutH;
    __shared__ unsigned short tile[32][33];
    int r0 = blockIdx.y * 32, c0 = blockIdx.x * 32;
    int i = threadIdx.x >> 3;
    int j = (threadIdx.x & 7) * 4;
    ushort4 v = *reinterpret_cast<const ushort4*>(ip + (long)(r0 + i) * ldin + c0 + j);
    tile[i][j + 0] = v.x; tile[i][j + 1] = v.y; tile[i][j + 2] = v.z; tile[i][j + 3] = v.w;
    __syncthreads();
    ushort4 w;
    w.x = tile[j + 0][i]; w.y = tile[j + 1][i]; w.z = tile[j + 2][i]; w.w = tile[j + 3][i];
    *reinterpret_cast<ushort4*>(op + (long)(c0 + i) * ldout + r0 + j) = w;
}

// ---------------------------------------------------------------------------
// vmean_part: partial column sums of Vh over l. part[(bl*8+seg)][c] =
//   sum_{l in [seg*64, seg*64+64)} Vh[bl][l][c]   (fp32)
// ---------------------------------------------------------------------------
__global__ __launch_bounds__(256) void vmean_part(
    const unsigned short* __restrict__ Vh, float* __restrict__ part)
{
    int bl = blockIdx.x, seg = blockIdx.y;
    const unsigned short* p = Vh + (long)bl * SEQ * HD + (long)seg * 64 * HD;
    int c = threadIdx.x * 4;
    float s0 = 0.f, s1 = 0.f, s2 = 0.f, s3 = 0.f;
    for (int l = 0; l < 64; ++l) {
        ushort4 v = *reinterpret_cast<const ushort4*>(p + (long)l * HD + c);
        s0 += b2f(v.x); s1 += b2f(v.y); s2 += b2f(v.z); s3 += b2f(v.w);
    }
    float4 o = {s0, s1, s2, s3};
    *reinterpret_cast<float4*>(part + (long)(bl * 8 + seg) * HD + c) = o;
}

// ---------------------------------------------------------------------------
// vmean_reduce: Vm[bl][c] = bf16( (1/SEQ) * sum_seg part[bl*8+seg][c] )
// ---------------------------------------------------------------------------
__global__ __launch_bounds__(256) void vmean_reduce(
    const float* __restrict__ part, unsigned short* __restrict__ Vm)
{
    int bl = blockIdx.x;
    int c = threadIdx.x * 4;
    const float* p = part + (long)bl * 8 * HD + c;
    float s0 = 0.f, s1 = 0.f, s2 = 0.f, s3 = 0.f;
#pragma unroll
    for (int seg = 0; seg < 8; ++seg) {
        float4 v = *reinterpret_cast<const float4*>(p + (long)seg * HD);
        s0 += v.x; s1 += v.y; s2 += v.z; s3 += v.w;
    }
    const float inv = 1.0f / SEQ;
    ushort4 o;
    o.x = f2b(s0 * inv); o.y = f2b(s1 * inv);
    o.z = f2b(s2 * inv); o.w = f2b(s3 * inv);
    *reinterpret_cast<ushort4*>(Vm + (long)bl * HD + c) = o;
}

// ---------------------------------------------------------------------------
// fix_mask: for padding-masked query rows, Vatt row := Vm row (uniform
// attention over ALL keys). 4 rows/block, 16 shorts/lane.
// ---------------------------------------------------------------------------
__global__ __launch_bounds__(256) void fix_mask(
    const unsigned short* __restrict__ Vm, unsigned short* __restrict__ Vatt,
    const int* __restrict__ maskc, int b0)
{
    int row = blockIdx.x * 4 + (threadIdx.x >> 6);   // bl*SEQ + l
    int bl = row >> 9, l = row & (SEQ - 1);
    if (maskc[(long)(b0 + bl) * SEQ + l] == 0) return;   // wave-uniform
    int c = (threadIdx.x & 63) * 16;
    uint4 a = *reinterpret_cast<const uint4*>(Vm + (long)bl * HD + c);
    uint4 b = *reinterpret_cast<const uint4*>(Vm + (long)bl * HD + c + 8);
    *reinterpret_cast<uint4*>(Vatt + (long)row * HD + c) = a;
    *reinterpret_cast<uint4*>(Vatt + (long)row * HD + c + 8) = b;
}

// ---------------------------------------------------------------------------
// Pure-bf16 MFMA GEMM: C = scl*A.Bt (+bias, relu), 128x128 tile,
// global_load_lds width-16 staging. Batched via blockIdx.z.
// NOTE (r14): `scale` applies to blockIdx.z==0 slabs ONLY (others get 1.0)
// — used to fold softmax scale*log2e into the Q projection.
// ---------------------------------------------------------------------------
template<bool BIAS, bool RELU, bool OUTBF16>
__global__ __launch_bounds__(256) void gemm_bt(
    const unsigned short* __restrict__ A, int lda,
    const unsigned short* __restrict__ B, int ldb,
    void* __restrict__ Cv, int ldc,
    const float* __restrict__ bias, float scale, int K, int Hdiv,
    long sAb, long sAh, long sAz,
    long sBb, long sBh, long sBz,
    long sCb, long sCh, long sCz)
{
    const int m0 = blockIdx.y * 128;
    const int n0 = blockIdx.x * 128;
    int z  = blockIdx.z;
    int bb = z / Hdiv, hh = z % Hdiv;
    const unsigned short* Ab = A + bb * sAb + hh * sAh + (long)z * sAz;
    const unsigned short* Bb = B + bb * sBb + hh * sBh + (long)z * sBz;
    long coff = bb * sCb + hh * sCh + (long)z * sCz;
    const float scl = (z == 0) ? scale : 1.0f;

    __shared__ unsigned short As[128 * 32];
    __shared__ unsigned short Bs[128 * 32];

    const int tid  = threadIdx.x;
    const int lane = tid & 63;
    const int wave = tid >> 6;
    const int wm   = (wave >> 1) * 64;
    const int wn   = (wave & 1) * 64;
    const int lm   = lane & 15;
    const int kq   = (lane >> 4) * 8;

    f32x4 acc[4][4] = {};

    for (int k0 = 0; k0 < K; k0 += 32) {
#pragma unroll
        for (int it = 0; it < 2; ++it) {
            int id = tid + it * 256;
            int r  = id >> 2;
            int c8 = (id & 3) * 8;
            const unsigned short* gA = Ab + (long)(m0 + r) * lda + k0 + c8;
            const unsigned short* gB = Bb + (long)(n0 + r) * ldb + k0 + c8;
#if HAS_ASYNC
            unsigned short* lA = &As[(size_t)(it * 256 + wave * 64) * 8];
            unsigned short* lB = &Bs[(size_t)(it * 256 + wave * 64) * 8];
            __builtin_amdgcn_global_load_lds(
                (const __attribute__((address_space(1))) void*)gA,
                (__attribute__((address_space(3))) void*)lA, 16, 0, 0);
            __builtin_amdgcn_global_load_lds(
                (const __attribute__((address_space(1))) void*)gB,
                (__attribute__((address_space(3))) void*)lB, 16, 0, 0);
#else
            *reinterpret_cast<uint4*>(&As[(size_t)id * 8]) =
                *reinterpret_cast<const uint4*>(gA);
            *reinterpret_cast<uint4*>(&Bs[(size_t)id * 8]) =
                *reinterpret_cast<const uint4*>(gB);
#endif
        }
        __syncthreads();

        short8 af[4], bfr[4];
#pragma unroll
        for (int i = 0; i < 4; ++i)
            af[i] = *reinterpret_cast<const short8*>(&As[(wm + i * 16 + lm) * 32 + kq]);
#pragma unroll
        for (int j = 0; j < 4; ++j)
            bfr[j] = *reinterpret_cast<const short8*>(&Bs[(wn + j * 16 + lm) * 32 + kq]);
#pragma unroll
        for (int i = 0; i < 4; ++i)
#pragma unroll
            for (int j = 0; j < 4; ++j)
                acc[i][j] = __builtin_amdgcn_mfma_f32_16x16x32_bf16(af[i], bfr[j], acc[i][j], 0, 0, 0);
        __syncthreads();
    }

#pragma unroll
    for (int j = 0; j < 4; ++j) {
        int col  = n0 + wn + j * 16 + lm;
        float bv = 0.f;
        if (BIAS) bv = bias[col];
#pragma unroll
        for (int i = 0; i < 4; ++i) {
#pragma unroll
            for (int r = 0; r < 4; ++r) {
                int row = m0 + wm + i * 16 + (lane >> 4) * 4 + r;
                float v = acc[i][j][r] * scl + bv;
                if (RELU) v = fmaxf(v, 0.f);
                long idx = coff + (long)row * ldc + col;
                if (OUTBF16) reinterpret_cast<unsigned short*>(Cv)[idx] = f2b(v);
                else         reinterpret_cast<float*>(Cv)[idx] = v;
            }
        }
    }
}

// ---------------------------------------------------------------------------
// flash_attn staging: linear LDS dest (gload_lds requirement) + pre-swizzled
// GLOBAL source; fallback stores to swizzled LDS address (rule 21).
// ---------------------------------------------------------------------------
// K tile: 64B rows (32 d-cols), causal row bound (qt+1)*64.
__device__ __forceinline__ void stage_k32(
    unsigned short* __restrict__ buf, const unsigned short* __restrict__ Ak,
    int kc, int qt, int tid, int wave)
{
    for (int it = 0; it <= qt; ++it) {
        int id = tid + it * 256;
#if HAS_ASYNC
        int U = swzb(id * 16);
        const unsigned short* g = Ak + (long)(U >> 6) * HD + kc * 32 + ((U >> 4) & 3) * 8;
        unsigned short* l = buf + (size_t)(it * 256 + wave * 64) * 8;
        __builtin_amdgcn_global_load_lds(
            (const __attribute__((address_space(1))) void*)g,
            (__attribute__((address_space(3))) void*)l, 16, 0, 0);
#else
        const unsigned short* g = Ak + (long)(id >> 2) * HD + kc * 32 + (id & 3) * 8;
        *reinterpret_cast<uint4*>((char*)buf + swzb(id * 16)) =
            *reinterpret_cast<const uint4*>(g);
#endif
    }
}

// V tile: 128B rows (256 d-rows x 64 key-cols = 32KB per buffer).
__device__ __forceinline__ void stage_v64(
    unsigned short* __restrict__ buf, const unsigned short* __restrict__ Av,
    int c64, int tid, int wave)
{
#pragma unroll
    for (int it = 0; it < 8; ++it) {
        int id = tid + it * 256;
#if HAS_ASYNC
        int U = swzb(id * 16);
        const unsigned short* g = Av + (long)(U >> 7) * SEQ + c64 * 64 + ((U >> 4) & 7) * 8;
        unsigned short* l = buf + (size_t)(it * 256 + wave * 64) * 8;
        __builtin_amdgcn_global_load_lds(
            (const __attribute__((address_space(1))) void*)g,
            (__attribute__((address_space(3))) void*)l, 16, 0, 0);
#else
        const unsigned short* g = Av + (long)(id >> 3) * SEQ + c64 * 64 + (id & 7) * 8;
        *reinterpret_cast<uint4*>((char*)buf + swzb(id * 16)) =
            *reinterpret_cast<const uint4*>(g);
#endif
    }
}

// ---------------------------------------------------------------------------
// Fused flash attention. Grid 8*nbh blocks. XCD = L&7; within an XCD the
// dispatch order pairs complementary q-tiles (qt, 7-qt) so co-resident
// blocks have equal total work and decorrelated barrier phases.
// Phase 1: causal dbuf stage-ahead; Ks reads XOR-swizzled; setprio(1) MFMA.
// Softmax: Q pre-scaled by scale*log2e at projection -> raw v_exp_f32;
//   causal-only masking; deferred normalization; early bf16 P-packing.
// Phase 2: causal NC = qt+1 tiles of 64 keys, V double-buffered in the two
//   32KB halves of Ks (1 barrier/tile), swizzled reads at 128B row stride.
// Epilogue: store only unmasked rows (masked rows owned by fix_mask).
// ---------------------------------------------------------------------------
__global__ __launch_bounds__(256, 2) void flash_attn(
    const unsigned short* __restrict__ Qh,
    const unsigned short* __restrict__ Kh,
    const unsigned short* __restrict__ VhT,
    unsigned short* __restrict__ Vatt,
    const int* __restrict__ maskc, int bh0, int nbh)
{
    const int tid  = threadIdx.x;
    const int lane = tid & 63;
    const int wave = tid >> 6;
    const int lm   = lane & 15;
    const int qg   = lane >> 4;
    const int kq   = qg * 8;

    const int L = blockIdx.x;
    int z, qt;
    if ((nbh & 7) == 0) {
        int x = L & 7, m = L >> 3;
        int mq = m & 7;
        qt = (mq & 1) ? (7 - (mq >> 1)) : (mq >> 1);   // 0,7,1,6,2,5,3,4
        z  = x + 8 * (m >> 3);
    } else {
        z = L % nbh; qt = L / nbh;
    }
    const int b_l = z >> 2, h = z & 3;
    const int m0  = qt * 64;
    const int wq0 = m0 + wave * 16;
    const long qkbase = (long)b_l * SEQ * HD + (long)h * DM;
    const unsigned short* Aq = Qh + qkbase;
    const unsigned short* Ak = Kh + qkbase;
    const unsigned short* Av = VhT + (long)b_l * SEQ * HD + (long)h * SEQ * DM;
    unsigned short* Ov = Vatt + qkbase;
    const int bglob = (bh0 + z) >> 2;

    __shared__ unsigned short Ks[2 * SEQ * 32];             // 64 KiB dbuf
    __shared__ __align__(16) unsigned short Pw[4][16][40];  // 5 KiB

    f32x4 S[32] = {};
    const int NT = (m0 >> 4) + wave + 1;     // causal tile bound (wave-uniform)

    // ---- Phase 1: S = Q.K^T over 8 d-chunks of 32, causal dbuf stage-ahead --
    stage_k32(Ks, Ak, 0, qt, tid, wave);     // prologue: chunk 0 -> buf0
    __syncthreads();
    for (int kc = 0; kc < 8; ++kc) {
        unsigned short* cur = (kc & 1) ? (Ks + SEQ * 32) : Ks;
        unsigned short* nxt = (kc & 1) ? Ks : (Ks + SEQ * 32);
        short8 qf = *reinterpret_cast<const short8*>(
            Aq + (long)(wq0 + lm) * HD + kc * 32 + kq);
        if (kc < 7) {
            stage_k32(nxt, Ak, kc + 1, qt, tid, wave);   // flies under compute
        } else {
            // last iter: prefetch V tile 0 into buf0 (compute uses buf1)
            stage_v64(Ks, Av, 0, tid, wave);
        }
        __builtin_amdgcn_s_setprio(1);
#pragma unroll
        for (int nt = 0; nt < 32; ++nt) {
            if (nt < NT) {
                int row = nt * 16 + lm;
                short8 bf = *reinterpret_cast<const short8*>(
                    (const char*)cur + swzb(row * 64 + qg * 16));
                S[nt] = __builtin_amdgcn_mfma_f32_16x16x32_bf16(qf, bf, S[nt], 0, 0, 0);
            }
        }
        __builtin_amdgcn_s_setprio(0);
        __syncthreads();   // next-iter buffer ready; cur reads drained
    }

    // ---- Softmax in registers (V tile-0 prefetch still in flight) ----
    // S is pre-scaled by scale*log2e (folded into Q projection): P = 2^(S-mx)
    // via raw v_exp_f32. Deferred normalization (1/sum applied in epilogue).
    int   qrow[4];
    bool  rowm[4];
    float mx[4], sm[4];
#pragma unroll
    for (int r = 0; r < 4; ++r) {
        int q = wq0 + qg * 4 + r;
        qrow[r] = q;
        rowm[r] = maskc[bglob * SEQ + q] != 0;
        mx[r] = -3.4e38f;
    }
#pragma unroll
    for (int nt = 0; nt < 32; ++nt) {
        int k = nt * 16 + lm;
#pragma unroll
        for (int r = 0; r < 4; ++r) {
            float v = S[nt][r];
            if (k > qrow[r]) v = NEGV;
            S[nt][r] = v;
            mx[r] = fmaxf(mx[r], v);
        }
    }
#pragma unroll
    for (int r = 0; r < 4; ++r) {
#pragma unroll
        for (int off = 8; off >= 1; off >>= 1)
            mx[r] = fmaxf(mx[r], __shfl_xor(mx[r], off));
        sm[r] = 0.f;
    }
    uint32_t pk[32][2];   // bf16x2-packed unnormalized P (64 VGPRs)
#pragma unroll
    for (int nt = 0; nt < 32; ++nt) {
        float e0 = fast_exp2(S[nt][0] - mx[0]);
        float e1 = fast_exp2(S[nt][1] - mx[1]);
        float e2 = fast_exp2(S[nt][2] - mx[2]);
        float e3 = fast_exp2(S[nt][3] - mx[3]);
        sm[0] += e0; sm[1] += e1; sm[2] += e2; sm[3] += e3;
        pk[nt][0] = (uint32_t)f2b(e0) | ((uint32_t)f2b(e1) << 16);
        pk[nt][1] = (uint32_t)f2b(e2) | ((uint32_t)f2b(e3) << 16);
    }
#pragma unroll
    for (int r = 0; r < 4; ++r) {
#pragma unroll
        for (int off = 8; off >= 1; off >>= 1)
            sm[r] += __shfl_xor(sm[r], off);
        sm[r] = 1.0f / sm[r];    // applied to O in the epilogue
    }

    // ---- Phase 2: O = P.V, causal NC tiles of 64 keys, double-buffered V ----
    // Keys >= (qt+1)*64 have e == 0.0f exactly (exp underflow) -> skip.
    // NC block-uniform -> guarded __syncthreads safe; full unroll keeps pk[]
    // statically indexed.
    unsigned short* Vb0 = Ks;             // 32 KiB
    unsigned short* Vb1 = Ks + 16384;     // 32 KiB
    const int NC = qt + 1;
    f32x4 O[16] = {};
#pragma unroll
    for (int c64 = 0; c64 < 8; ++c64) {
        if (c64 < NC) {
            unsigned short* Vcur = (c64 & 1) ? Vb1 : Vb0;
            __syncthreads();     // drains staging of tile c64 (+ prior reads)
            if (c64 + 1 < NC) {  // prefetch tile c64+1 into the other buffer
                unsigned short* Vnext = (c64 & 1) ? Vb0 : Vb1;
                stage_v64(Vnext, Av, c64 + 1, tid, wave);
            }
#pragma unroll
            for (int t = 0; t < 2; ++t) {
                // P sub-chunk (32 keys): packed regs -> wave-private LDS
#pragma unroll
                for (int tt = 0; tt < 2; ++tt) {
                    int nt = c64 * 4 + t * 2 + tt;
#pragma unroll
                    for (int r = 0; r < 4; ++r)
                        Pw[wave][qg * 4 + r][tt * 16 + lm] =
                            (unsigned short)(pk[nt][r >> 1] >> ((r & 1) * 16));
                }
                short8 pf = *reinterpret_cast<const short8*>(&Pw[wave][lm][kq]);
                __builtin_amdgcn_s_setprio(1);
#pragma unroll
                for (int nt2 = 0; nt2 < 16; ++nt2) {
                    int row = nt2 * 16 + lm;
                    short8 vf = *reinterpret_cast<const short8*>(
                        (const char*)Vcur + swzb(row * 128 + t * 64 + qg * 16));
                    O[nt2] = __builtin_amdgcn_mfma_f32_16x16x32_bf16(pf, vf, O[nt2], 0, 0, 0);
                }
                __builtin_amdgcn_s_setprio(0);
            }
        }
    }

    // ---- epilogue (apply deferred 1/sum; skip masked rows: fix_mask owns) --
#pragma unroll
    for (int nt2 = 0; nt2 < 16; ++nt2) {
#pragma unroll
        for (int r = 0; r < 4; ++r) {
            if (!rowm[r]) {
                int l = wq0 + qg * 4 + r;
                Ov[(long)l * HD + nt2 * 16 + lm] = f2b(O[nt2][r] * sm[r]);
            }
        }
    }
}

// ---------------------------------------------------------------------------
// LN1: x = bf16 AttO + fp32 Q + fp32 pe  ->  fp32 Xf AND bf16 Xb
// ---------------------------------------------------------------------------
__global__ __launch_bounds__(256) void ln1_kernel(
    const unsigned short* __restrict__ AttO, const float* __restrict__ Q,
    const float* __restrict__ pe,
    const float* __restrict__ gamma, const float* __restrict__ beta,
    float* __restrict__ outf, unsigned short* __restrict__ outb)
{
    int row  = blockIdx.x * 4 + (threadIdx.x >> 6);
    int lane = threadIdx.x & 63;
    long base = (long)row * DM + lane * 4;
    ushort4 a = *reinterpret_cast<const ushort4*>(AttO + base);
    float4 qv = *reinterpret_cast<const float4*>(Q + base);
    float4 pv = *reinterpret_cast<const float4*>(pe + (base & PE_MASK));
    float x[4] = {b2f(a.x) + qv.x + pv.x, b2f(a.y) + qv.y + pv.y,
                  b2f(a.z) + qv.z + pv.z, b2f(a.w) + qv.w + pv.w};
    float s = x[0] + x[1] + x[2] + x[3];
#pragma unroll
    for (int off = 32; off > 0; off >>= 1) s += __shfl_xor(s, off);
    float mu = s * (1.0f / DM);
    float vs = 0.f;
#pragma unroll
    for (int t = 0; t < 4; ++t) { float d = x[t] - mu; vs += d * d; }
#pragma unroll
    for (int off = 32; off > 0; off >>= 1) vs += __shfl_xor(vs, off);
    float inv = rsqrtf(vs * (1.0f / DM) + 1e-5f);
    int d0 = lane * 4;
    float4 g = *reinterpret_cast<const float4*>(gamma + d0);
    float4 bt = *reinterpret_cast<const float4*>(beta + d0);
    float4 o;
    o.x = (x[0] - mu) * inv * g.x + bt.x;
    o.y = (x[1] - mu) * inv * g.y + bt.y;
    o.z = (x[2] - mu) * inv * g.z + bt.z;
    o.w = (x[3] - mu) * inv * g.w + bt.w;
    *reinterpret_cast<float4*>(outf + base) = o;
    ushort4 ob;
    ob.x = f2b(o.x); ob.y = f2b(o.y); ob.z = f2b(o.z); ob.w = f2b(o.w);
    *reinterpret_cast<ushort4*>(outb + base) = ob;
}

// ---------------------------------------------------------------------------
// LN2: x = fp32 F + fp32 X  ->  FP32 out
// ---------------------------------------------------------------------------
__global__ __launch_bounds__(256) void ln2_kernel(
    const float* __restrict__ F, const float* __restrict__ X,
    const float* __restrict__ gamma, const float* __restrict__ beta,
    float* __restrict__ out)
{
    int row  = blockIdx.x * 4 + (threadIdx.x >> 6);
    int lane = threadIdx.x & 63;
    long base = (long)row * DM + lane * 4;
    float4 a = *reinterpret_cast<const float4*>(F + base);
    float4 c = *reinterpret_cast<const float4*>(X + base);
    float x[4] = {a.x + c.x, a.y + c.y, a.z + c.z, a.w + c.w};
    float s = x[0] + x[1] + x[2] + x[3];
#pragma unroll
    for (int off = 32; off > 0; off >>= 1) s += __shfl_xor(s, off);
    float mu = s * (1.0f / DM);
    float vs = 0.f;
#pragma unroll
    for (int t = 0; t < 4; ++t) { float d = x[t] - mu; vs += d * d; }
#pragma unroll
    for (int off = 32; off > 0; off >>= 1) vs += __shfl_xor(vs, off);
    float inv = rsqrtf(vs * (1.0f / DM) + 1e-5f);
    int d0 = lane * 4;
    float4 g = *reinterpret_cast<const float4*>(gamma + d0);
    float4 bt = *reinterpret_cast<const float4*>(beta + d0);
    float4 o;
    o.x = (x[0] - mu) * inv * g.x + bt.x;
    o.y = (x[1] - mu) * inv * g.y + bt.y;
    o.z = (x[2] - mu) * inv * g.z + bt.z;
    o.w = (x[3] - mu) * inv * g.w + bt.w;
    *reinterpret_cast<float4*>(out + base) = o;
}

// ---------------------------------------------------------------------------
extern "C" void kernel_launch(void* const* d_in, const int* in_sizes, int n_in,
                              void* d_out, int out_size, void* d_ws, size_t ws_size,
                              hipStream_t stream)
{
    const float* Q  = (const float*)d_in[0];
    const float* Ki = (const float*)d_in[1];
    const float* Vi = (const float*)d_in[2];
    const unsigned char* mask_raw = (const unsigned char*)d_in[3];
    const float* pe = (const float*)d_in[4];
    const float* Wq = (const float*)d_in[5];
    const float* Wk = (const float*)d_in[6];
    const float* Wv = (const float*)d_in[7];
    const float* Wo = (const float*)d_in[8];
    const float* w1 = (const float*)d_in[9];
    const float* b1 = (const float*)d_in[10];
    const float* w2 = (const float*)d_in[11];
    const float* b2 = (const float*)d_in[12];
    const float* gamma = (const float*)d_in[13];
    const float* beta  = (const float*)d_in[14];
    float* out = (float*)d_out;

    const size_t MiB = 1048576;
    char* ws = (char*)d_ws;

    // ---- adaptive chunk size: footprint = 59 + max(5*CB + 34KB*CB, 24) MiB --
    int CB = 1;
    for (int cb = 32; cb >= 1; cb >>= 1) {
        size_t scr_sz = (size_t)(5 * cb) * MiB + (size_t)cb * 34816;
        if (scr_sz < 24 * MiB) scr_sz = 24 * MiB;
        if ((59 * MiB + scr_sz) <= ws_size) { CB = cb; break; }
    }
    const int NCH = NB / CB;

    // ---- fixed low regions ----
    unsigned short* WqT  = (unsigned short*)(ws);                 // 512 KiB each
    unsigned short* WkT  = WqT + 262144;
    unsigned short* WvT  = WkT + 262144;
    unsigned short* WoT  = WvT + 262144;
    unsigned short* w1b  = (unsigned short*)(ws + 2 * MiB);       // 128 KiB
    unsigned short* w2b  = w1b + 65536;                           // 128 KiB
    int*            maskc = (int*)(ws + 2 * MiB + 262144);        // 64 KiB
    unsigned short* Qp   = (unsigned short*)(ws + 3 * MiB);       // 8 MiB bf16
    unsigned short* Kp   = (unsigned short*)(ws + 11 * MiB);      // 8 MiB
    unsigned short* Vp   = (unsigned short*)(ws + 19 * MiB);      // 8 MiB
    unsigned short* AttO = (unsigned short*)(ws + 27 * MiB);      // 8 MiB
    unsigned short* Xb   = (unsigned short*)(ws + 35 * MiB);      // 8 MiB
    float*          Xf   = (float*)(ws + 43 * MiB);               // 16 MiB
    char*           scr  = ws + 59 * MiB;
    // chunk scratch (CB MiB each)
    unsigned short* Qh   = (unsigned short*)(scr);
    unsigned short* Kh   = (unsigned short*)(scr + (size_t)CB * MiB);
    unsigned short* Vh   = (unsigned short*)(scr + (size_t)2 * CB * MiB);
    unsigned short* VhT  = (unsigned short*)(scr + (size_t)3 * CB * MiB);
    unsigned short* Vatt = (unsigned short*)(scr + (size_t)4 * CB * MiB);
    // vmean scratch (per chunk; dead at tail-alias time)
    float*          part = (float*)(scr + (size_t)5 * CB * MiB);            // CB*32 KiB
    unsigned short* Vm   = (unsigned short*)(scr + (size_t)5 * CB * MiB
                                             + (size_t)CB * 8 * HD * 4);    // CB*2 KiB
    // tail aliases over scratch (chunk buffers dead by then)
    unsigned short* H1   = (unsigned short*)(scr);                // 8 MiB bf16
    float*          Ff   = (float*)(scr + 8 * MiB);               // 16 MiB fp32

    // softmax scale * log2(e), folded into the Q projection (z==0 slab)
    const float SCALE_Q = (float)((1.0 / (16.0 + 1e-6)) * 1.4426950408889634);
    const long CROWS = (long)CB * SEQ;
    const long CBELT = (long)CB * MiB / 2;     // chunk-buffer stride, elements

    // 0. prep (merged): mask, weight transposes/conversions, fused PE-add
    mask_canon<<<64, 256, 0, stream>>>(mask_raw, maskc);
    transpose_f2b3<<<dim3(32, 8, 3), 256, 0, stream>>>(Wq, Wk, Wv, WqT, HD, DM, 262144);
    transpose_f2b<<<dim3(8, 32, 1), 256, 0, stream>>>(Wo, WoT, DM, HD);
    conv2<<<128, 256, 0, stream>>>(w1, w2, w1b, w2b);
    addpe3<<<12288, 256, 0, stream>>>(Q, Ki, Vi, pe, Qp, Kp, Vp);

    // 1. attention in NCH chunks of CB batches
    for (int c = 0; c < NCH; ++c) {
        const long r0   = (long)c * CROWS;
        const int  bh0  = c * CB * NH;
        const int  gy   = (int)(CROWS / 128);
        const int  nbh  = CB * NH;

        // all 3 projections in ONE dispatch (z=0: Q scaled by SCALE_Q, 1:K, 2:V)
        gemm_bt<false, false, true><<<dim3(8, gy, 3), 256, 0, stream>>>(
            Qp + r0 * DM, DM, WqT, DM, Qh, HD, nullptr, SCALE_Q, DM,
            1, 4194304, 0, 0, 262144, 0, 0, CBELT, 0, 0);

        // per-head V transpose: VhT[bl][h][d][l] = Vh[bl][l][h*256+d]
        transpose_bf16<<<dim3(8, 16, CB * NH), 256, 0, stream>>>(
            Vh, VhT, HD, SEQ, (long)SEQ * HD, DM, (long)SEQ * HD, (long)SEQ * DM, NH);

        // per-batch V column means (for padding-masked rows)
        vmean_part<<<dim3(CB, 8), 256, 0, stream>>>(Vh, part);
        vmean_reduce<<<CB, 256, 0, stream>>>(part, Vm);

        // fused attention
        flash_attn<<<dim3(8 * nbh, 1, 1), 256, 0, stream>>>(
            Qh, Kh, VhT, Vatt, maskc, bh0, nbh);

        // masked rows: Vatt row := Vm row (uniform attention over all keys)
        fix_mask<<<(int)(CROWS / 4), 256, 0, stream>>>(Vm, Vatt, maskc, c * CB);

        // output projection for this chunk -> AttO rows [r0, r0+CROWS)
        gemm_bt<false, false, true><<<dim3(2, gy, 1), 256, 0, stream>>>(
            Vatt, HD, WoT, HD, AttO + r0 * DM, DM, nullptr, 1.f, HD,
            1, 0,0,0, 0,0,0, 0,0,0);
    }

    // 2. LN1: X = LN(Q + pe + AttO) -> fp32 Xf + bf16 Xb
    ln1_kernel<<<4096, 256, 0, stream>>>(AttO, Q, pe, gamma, beta, Xf, Xb);

    // 3. FFN1: H1 = relu(Xb @ w1^T + b1) -> bf16
    gemm_bt<true, true, true><<<dim3(2, 128, 1), 256, 0, stream>>>(
        Xb, DM, w1b, DM, H1, DM, b1, 1.f, DM, 1, 0,0,0, 0,0,0, 0,0,0);
    // 4. FFN2: F = H1 @ w2^T + b2 -> fp32
    gemm_bt<true, false, false><<<dim3(2, 128, 1), 256, 0, stream>>>(
        H1, DM, w2b, DM, Ff, DM, b2, 1.f, DM, 1, 0,0,0, 0,0,0, 0,0,0);

    // 5. LN2: out = LN(F + X) -> FP32
    ln2_kernel<<<4096, 256, 0, stream>>>(Ff, Xf, gamma, beta, out);
}

// Round 6
// 332.619 us; speedup vs baseline: 1.1700x; 1.0399x over previous
//
#include <hip/hip_runtime.h>
#include <stdint.h>

// ---------------------------------------------------------------------------
// TransformerBlock: B=32, L=512, D=256, H=4.
// Inputs fp32 (dict order); OUTPUT fp32.
// r15: dispatch-count reduction 16 -> 9 (launch-gap overhead was ~100us):
//   - prep_all: mask_canon + WqWkWv/Wo transposes + conv2 + addpe3 fused
//   - tv_kernel: per-head V transpose + vmean partial sums fused
//   - flash epilogue: vmean reduce + masked-row fix fused (reads `part`,
//     stores rowm ? colmean(V) : O*sm -- same f2b(sum/512) rounding as the
//     old Vm path). vmean_reduce/fix_mask kernels + Vm buffer deleted.
// flash internals = r14 (proven): XCD swizzle + complementary qt pairing,
//   LDS XOR-swizzle, causal dbuf stage-ahead, scale*log2e folded into Q
//   projection -> raw v_exp_f32, 64-key V tiles, setprio, deferred norm,
//   early bf16 P-packing, launch_bounds(256,2).
// ws = 59 + 5*CB MiB + CB*32KB (CB=32 -> single chunk at ws=256MiB).
// ---------------------------------------------------------------------------
#define SEQ   512
#define DM    256
#define NB    32
#define NH    4
#define HD    (NH * DM)           // 1024
#define PE_MASK (SEQ * DM - 1)    // 131071
#define NEGV  (-4294967295.0f)

typedef __attribute__((ext_vector_type(8))) short short8;   // 8 x bf16
typedef __attribute__((ext_vector_type(4))) float f32x4;    // MFMA accumulator

#if defined(__has_builtin)
#if __has_builtin(__builtin_amdgcn_global_load_lds)
#define HAS_ASYNC 1
#endif
#endif
#ifndef HAS_ASYNC
#define HAS_ASYNC 0
#endif

__device__ __forceinline__ float b2f(unsigned short u) {
    return __uint_as_float(((uint32_t)u) << 16);
}
__device__ __forceinline__ unsigned short f2b(float f) {
    uint32_t u = __float_as_uint(f);
    u += 0x7fffu + ((u >> 16) & 1u);   // RNE
    return (unsigned short)(u >> 16);
}
// raw v_exp_f32: 2^x on the transcendental pipe (input pre-scaled by log2e)
__device__ __forceinline__ float fast_exp2(float x) {
    float r;
    asm("v_exp_f32 %0, %1" : "=v"(r) : "v"(x));
    return r;
}

// LDS bank swizzle: involution XORing byte bits [6:4] with bits [9:7].
// 64B-row tiles (K): row=b>>6, group=(4*(row&1)+qg)^((row>>1)&7) -> 2/group.
// 128B-row tiles (V): row=b>>7, group=(t*4+qg)^(row&7)           -> 2/group.
__device__ __forceinline__ int swzb(int b) {
    return b ^ (((b >> 7) & 7) << 4);
}

// ---------------------------------------------------------------------------
// prep_all: fused preprocessing, one dispatch (13504 blocks):
//   [0,64)        mask_canon (auto-detect uint8/int32/int64 -> int32)
//   [64,832)      Wq/Wk/Wv fp32->bf16 transpose (32x8x3 tiles)
//   [832,1088)    Wo fp32->bf16 transpose (8x32 tiles)
//   [1088,1216)   w1,w2 fp32->bf16 convert
//   [1216,13504)  Q/K/V + pe -> bf16 (addpe)
// ---------------------------------------------------------------------------
__global__ __launch_bounds__(256) void prep_all(
    const unsigned char* __restrict__ mask_raw, int* __restrict__ maskc,
    const float* __restrict__ Wq, const float* __restrict__ Wk,
    const float* __restrict__ Wv, unsigned short* __restrict__ WqT,
    const float* __restrict__ Wo, unsigned short* __restrict__ WoT,
    const float* __restrict__ w1, const float* __restrict__ w2,
    unsigned short* __restrict__ o1, unsigned short* __restrict__ o2,
    const float* __restrict__ Q, const float* __restrict__ K,
    const float* __restrict__ V, const float* __restrict__ pe,
    unsigned short* __restrict__ Qp, unsigned short* __restrict__ Kp,
    unsigned short* __restrict__ Vp)
{
    __shared__ unsigned short tile[32][33];
    __shared__ int enc[2];
    const int blk = blockIdx.x;
    const int tid = threadIdx.x;

    if (blk < 64) {
        // ---- mask canonicalization ----
        if (tid == 0) { enc[0] = 0; enc[1] = 0; }
        __syncthreads();
        if (tid < 255 && mask_raw[tid * 4 + 1]) atomicOr(&enc[0], 1);
        if (tid < 128 && ((const int*)mask_raw)[tid * 2 + 1]) atomicOr(&enc[1], 1);
        __syncthreads();
        int i = blk * 256 + tid;
        int v;
        if (enc[0])      v = (mask_raw[i] != 0);
        else if (enc[1]) v = (((const int*)mask_raw)[i] != 0);
        else             v = ((((const int*)mask_raw)[i * 2] |
                              ((const int*)mask_raw)[i * 2 + 1]) != 0);
        maskc[i] = v;
    } else if (blk < 832) {
        // ---- Wq/Wk/Wv transpose fp32 -> bf16 (out[c][r]) ----
        int t = blk - 64;
        int x = t & 31, y = (t >> 5) & 7, zz = t >> 8;
        const float* in = (zz == 0) ? Wq : (zz == 1) ? Wk : Wv;
        unsigned short* op = WqT + (long)zz * 262144;
        int r0 = y * 32, c0 = x * 32;
        int i = tid >> 3, j = (tid & 7) * 4;
        float4 v = *reinterpret_cast<const float4*>(in + (long)(r0 + i) * HD + c0 + j);
        tile[i][j + 0] = f2b(v.x); tile[i][j + 1] = f2b(v.y);
        tile[i][j + 2] = f2b(v.z); tile[i][j + 3] = f2b(v.w);
        __syncthreads();
        ushort4 w;
        w.x = tile[j + 0][i]; w.y = tile[j + 1][i];
        w.z = tile[j + 2][i]; w.w = tile[j + 3][i];
        *reinterpret_cast<ushort4*>(op + (long)(c0 + i) * DM + r0 + j) = w;
    } else if (blk < 1088) {
        // ---- Wo transpose fp32 -> bf16 ----
        int t = blk - 832;
        int x = t & 7, y = t >> 3;
        int r0 = y * 32, c0 = x * 32;
        int i = tid >> 3, j = (tid & 7) * 4;
        float4 v = *reinterpret_cast<const float4*>(Wo + (long)(r0 + i) * DM + c0 + j);
        tile[i][j + 0] = f2b(v.x); tile[i][j + 1] = f2b(v.y);
        tile[i][j + 2] = f2b(v.z); tile[i][j + 3] = f2b(v.w);
        __syncthreads();
        ushort4 w;
        w.x = tile[j + 0][i]; w.y = tile[j + 1][i];
        w.z = tile[j + 2][i]; w.w = tile[j + 3][i];
        *reinterpret_cast<ushort4*>(WoT + (long)(c0 + i) * HD + r0 + j) = w;
    } else if (blk < 1216) {
        // ---- w1/w2 fp32 -> bf16 ----
        int t = blk - 1088;
        const float* in = (t < 64) ? w1 : w2;
        unsigned short* out = (t < 64) ? o1 : o2;
        long i = (long)((t & 63) * 256 + tid) * 4;
        float4 x = *reinterpret_cast<const float4*>(in + i);
        ushort4 o;
        o.x = f2b(x.x); o.y = f2b(x.y); o.z = f2b(x.z); o.w = f2b(x.w);
        *reinterpret_cast<ushort4*>(out + i) = o;
    } else {
        // ---- Q/K/V + pe -> bf16 ----
        int t = blk - 1216;
        int seg = t >> 12;
        const float* X = (seg == 0) ? Q : (seg == 1) ? K : V;
        unsigned short* O = (seg == 0) ? Qp : (seg == 1) ? Kp : Vp;
        long i = (long)((t & 4095) * 256 + tid) * 4;
        float4 x = *reinterpret_cast<const float4*>(X + i);
        float4 p = *reinterpret_cast<const float4*>(pe + (i & PE_MASK));
        ushort4 o;
        o.x = f2b(x.x + p.x); o.y = f2b(x.y + p.y);
        o.z = f2b(x.z + p.z); o.w = f2b(x.w + p.w);
        *reinterpret_cast<ushort4*>(O + i) = o;
    }
}

// ---------------------------------------------------------------------------
// tv_kernel: fused per-head V transpose + vmean partial sums (both read Vh):
//   [0, nbl*NH*128)        VhT[bl][h][d][l] = Vh[bl][l][h*256+d]
//   [nT, nT + nbl*8)       part[(bl*8+seg)][c] = sum_{l in seg*64..+64} Vh[bl][l][c]
// ---------------------------------------------------------------------------
__global__ __launch_bounds__(256) void tv_kernel(
    const unsigned short* __restrict__ Vh, unsigned short* __restrict__ VhT,
    float* __restrict__ part, int nbl)
{
    __shared__ unsigned short tile[32][33];
    const int blk = blockIdx.x;
    const int tid = threadIdx.x;
    const int nT = nbl * NH * 128;           // 8x16 tiles per (bl,h)

    if (blk < nT) {
        int x = blk & 7, y = (blk >> 3) & 15, zz = blk >> 7;
        int b = zz / NH, hh = zz % NH;
        const unsigned short* ip = Vh + (long)b * SEQ * HD + (long)hh * DM;
        unsigned short* op = VhT + (long)b * SEQ * HD + (long)hh * SEQ * DM;
        int r0 = y * 32, c0 = x * 32;
        int i = tid >> 3, j = (tid & 7) * 4;
        ushort4 v = *reinterpret_cast<const ushort4*>(ip + (long)(r0 + i) * HD + c0 + j);
        tile[i][j + 0] = v.x; tile[i][j + 1] = v.y;
        tile[i][j + 2] = v.z; tile[i][j + 3] = v.w;
        __syncthreads();
        ushort4 w;
        w.x = tile[j + 0][i]; w.y = tile[j + 1][i];
        w.z = tile[j + 2][i]; w.w = tile[j + 3][i];
        *reinterpret_cast<ushort4*>(op + (long)(c0 + i) * SEQ + r0 + j) = w;
    } else {
        int t = blk - nT;
        int bl = t >> 3, seg = t & 7;
        const unsigned short* p = Vh + (long)bl * SEQ * HD + (long)seg * 64 * HD;
        int c = tid * 4;
        float s0 = 0.f, s1 = 0.f, s2 = 0.f, s3 = 0.f;
        for (int l = 0; l < 64; ++l) {
            ushort4 v = *reinterpret_cast<const ushort4*>(p + (long)l * HD + c);
            s0 += b2f(v.x); s1 += b2f(v.y); s2 += b2f(v.z); s3 += b2f(v.w);
        }
        float4 o = {s0, s1, s2, s3};
        *reinterpret_cast<float4*>(part + (long)(bl * 8 + seg) * HD + c) = o;
    }
}

// ---------------------------------------------------------------------------
// Pure-bf16 MFMA GEMM: C = scl*A.Bt (+bias, relu), 128x128 tile,
// global_load_lds width-16 staging. Batched via blockIdx.z.
// `scale` applies to blockIdx.z==0 slabs ONLY (others get 1.0) — used to
// fold softmax scale*log2e into the Q projection.
// ---------------------------------------------------------------------------
template<bool BIAS, bool RELU, bool OUTBF16>
__global__ __launch_bounds__(256) void gemm_bt(
    const unsigned short* __restrict__ A, int lda,
    const unsigned short* __restrict__ B, int ldb,
    void* __restrict__ Cv, int ldc,
    const float* __restrict__ bias, float scale, int K, int Hdiv,
    long sAb, long sAh, long sAz,
    long sBb, long sBh, long sBz,
    long sCb, long sCh, long sCz)
{
    const int m0 = blockIdx.y * 128;
    const int n0 = blockIdx.x * 128;
    int z  = blockIdx.z;
    int bb = z / Hdiv, hh = z % Hdiv;
    const unsigned short* Ab = A + bb * sAb + hh * sAh + (long)z * sAz;
    const unsigned short* Bb = B + bb * sBb + hh * sBh + (long)z * sBz;
    long coff = bb * sCb + hh * sCh + (long)z * sCz;
    const float scl = (z == 0) ? scale : 1.0f;

    __shared__ unsigned short As[128 * 32];
    __shared__ unsigned short Bs[128 * 32];

    const int tid  = threadIdx.x;
    const int lane = tid & 63;
    const int wave = tid >> 6;
    const int wm   = (wave >> 1) * 64;
    const int wn   = (wave & 1) * 64;
    const int lm   = lane & 15;
    const int kq   = (lane >> 4) * 8;

    f32x4 acc[4][4] = {};

    for (int k0 = 0; k0 < K; k0 += 32) {
#pragma unroll
        for (int it = 0; it < 2; ++it) {
            int id = tid + it * 256;
            int r  = id >> 2;
            int c8 = (id & 3) * 8;
            const unsigned short* gA = Ab + (long)(m0 + r) * lda + k0 + c8;
            const unsigned short* gB = Bb + (long)(n0 + r) * ldb + k0 + c8;
#if HAS_ASYNC
            unsigned short* lA = &As[(size_t)(it * 256 + wave * 64) * 8];
            unsigned short* lB = &Bs[(size_t)(it * 256 + wave * 64) * 8];
            __builtin_amdgcn_global_load_lds(
                (const __attribute__((address_space(1))) void*)gA,
                (__attribute__((address_space(3))) void*)lA, 16, 0, 0);
            __builtin_amdgcn_global_load_lds(
                (const __attribute__((address_space(1))) void*)gB,
                (__attribute__((address_space(3))) void*)lB, 16, 0, 0);
#else
            *reinterpret_cast<uint4*>(&As[(size_t)id * 8]) =
                *reinterpret_cast<const uint4*>(gA);
            *reinterpret_cast<uint4*>(&Bs[(size_t)id * 8]) =
                *reinterpret_cast<const uint4*>(gB);
#endif
        }
        __syncthreads();

        short8 af[4], bfr[4];
#pragma unroll
        for (int i = 0; i < 4; ++i)
            af[i] = *reinterpret_cast<const short8*>(&As[(wm + i * 16 + lm) * 32 + kq]);
#pragma unroll
        for (int j = 0; j < 4; ++j)
            bfr[j] = *reinterpret_cast<const short8*>(&Bs[(wn + j * 16 + lm) * 32 + kq]);
#pragma unroll
        for (int i = 0; i < 4; ++i)
#pragma unroll
            for (int j = 0; j < 4; ++j)
                acc[i][j] = __builtin_amdgcn_mfma_f32_16x16x32_bf16(af[i], bfr[j], acc[i][j], 0, 0, 0);
        __syncthreads();
    }

#pragma unroll
    for (int j = 0; j < 4; ++j) {
        int col  = n0 + wn + j * 16 + lm;
        float bv = 0.f;
        if (BIAS) bv = bias[col];
#pragma unroll
        for (int i = 0; i < 4; ++i) {
#pragma unroll
            for (int r = 0; r < 4; ++r) {
                int row = m0 + wm + i * 16 + (lane >> 4) * 4 + r;
                float v = acc[i][j][r] * scl + bv;
                if (RELU) v = fmaxf(v, 0.f);
                long idx = coff + (long)row * ldc + col;
                if (OUTBF16) reinterpret_cast<unsigned short*>(Cv)[idx] = f2b(v);
                else         reinterpret_cast<float*>(Cv)[idx] = v;
            }
        }
    }
}

// ---------------------------------------------------------------------------
// flash_attn staging: linear LDS dest (gload_lds requirement) + pre-swizzled
// GLOBAL source; fallback stores to swizzled LDS address (rule 21).
// ---------------------------------------------------------------------------
// K tile: 64B rows (32 d-cols), causal row bound (qt+1)*64.
__device__ __forceinline__ void stage_k32(
    unsigned short* __restrict__ buf, const unsigned short* __restrict__ Ak,
    int kc, int qt, int tid, int wave)
{
    for (int it = 0; it <= qt; ++it) {
        int id = tid + it * 256;
#if HAS_ASYNC
        int U = swzb(id * 16);
        const unsigned short* g = Ak + (long)(U >> 6) * HD + kc * 32 + ((U >> 4) & 3) * 8;
        unsigned short* l = buf + (size_t)(it * 256 + wave * 64) * 8;
        __builtin_amdgcn_global_load_lds(
            (const __attribute__((address_space(1))) void*)g,
            (__attribute__((address_space(3))) void*)l, 16, 0, 0);
#else
        const unsigned short* g = Ak + (long)(id >> 2) * HD + kc * 32 + (id & 3) * 8;
        *reinterpret_cast<uint4*>((char*)buf + swzb(id * 16)) =
            *reinterpret_cast<const uint4*>(g);
#endif
    }
}

// V tile: 128B rows (256 d-rows x 64 key-cols = 32KB per buffer).
__device__ __forceinline__ void stage_v64(
    unsigned short* __restrict__ buf, const unsigned short* __restrict__ Av,
    int c64, int tid, int wave)
{
#pragma unroll
    for (int it = 0; it < 8; ++it) {
        int id = tid + it * 256;
#if HAS_ASYNC
        int U = swzb(id * 16);
        const unsigned short* g = Av + (long)(U >> 7) * SEQ + c64 * 64 + ((U >> 4) & 7) * 8;
        unsigned short* l = buf + (size_t)(it * 256 + wave * 64) * 8;
        __builtin_amdgcn_global_load_lds(
            (const __attribute__((address_space(1))) void*)g,
            (__attribute__((address_space(3))) void*)l, 16, 0, 0);
#else
        const unsigned short* g = Av + (long)(id >> 3) * SEQ + c64 * 64 + (id & 7) * 8;
        *reinterpret_cast<uint4*>((char*)buf + swzb(id * 16)) =
            *reinterpret_cast<const uint4*>(g);
#endif
    }
}

// ---------------------------------------------------------------------------
// Fused flash attention. Grid 8*nbh blocks. XCD = L&7; within an XCD the
// dispatch order pairs complementary q-tiles (qt, 7-qt).
// Phase 1: causal dbuf stage-ahead; Ks reads XOR-swizzled; setprio MFMA.
// Softmax: Q pre-scaled by scale*log2e at projection -> raw v_exp_f32;
//   causal-only masking; deferred normalization; early bf16 P-packing.
// Phase 2: causal NC = qt+1 tiles of 64 keys, V dbuf (1 barrier/tile).
// Epilogue (r15): masked rows get uniform-attention value = V column mean,
//   reduced in-register from `part` (8 partial-sum rows); rounding matches
//   the old vmean_reduce/fix_mask path exactly (f2b(sum/512)).
// ---------------------------------------------------------------------------
__global__ __launch_bounds__(256, 2) void flash_attn(
    const unsigned short* __restrict__ Qh,
    const unsigned short* __restrict__ Kh,
    const unsigned short* __restrict__ VhT,
    const float* __restrict__ part,
    unsigned short* __restrict__ Vatt,
    const int* __restrict__ maskc, int bh0, int nbh)
{
    const int tid  = threadIdx.x;
    const int lane = tid & 63;
    const int wave = tid >> 6;
    const int lm   = lane & 15;
    const int qg   = lane >> 4;
    const int kq   = qg * 8;

    const int L = blockIdx.x;
    int z, qt;
    if ((nbh & 7) == 0) {
        int x = L & 7, m = L >> 3;
        int mq = m & 7;
        qt = (mq & 1) ? (7 - (mq >> 1)) : (mq >> 1);   // 0,7,1,6,2,5,3,4
        z  = x + 8 * (m >> 3);
    } else {
        z = L % nbh; qt = L / nbh;
    }
    const int b_l = z >> 2, h = z & 3;
    const int m0  = qt * 64;
    const int wq0 = m0 + wave * 16;
    const long qkbase = (long)b_l * SEQ * HD + (long)h * DM;
    const unsigned short* Aq = Qh + qkbase;
    const unsigned short* Ak = Kh + qkbase;
    const unsigned short* Av = VhT + (long)b_l * SEQ * HD + (long)h * SEQ * DM;
    unsigned short* Ov = Vatt + qkbase;
    const int bglob = (bh0 + z) >> 2;

    __shared__ unsigned short Ks[2 * SEQ * 32];             // 64 KiB dbuf
    __shared__ __align__(16) unsigned short Pw[4][16][40];  // 5 KiB

    f32x4 S[32] = {};
    const int NT = (m0 >> 4) + wave + 1;     // causal tile bound (wave-uniform)

    // ---- Phase 1: S = Q.K^T over 8 d-chunks of 32, causal dbuf stage-ahead --
    stage_k32(Ks, Ak, 0, qt, tid, wave);     // prologue: chunk 0 -> buf0
    __syncthreads();
    for (int kc = 0; kc < 8; ++kc) {
        unsigned short* cur = (kc & 1) ? (Ks + SEQ * 32) : Ks;
        unsigned short* nxt = (kc & 1) ? Ks : (Ks + SEQ * 32);
        short8 qf = *reinterpret_cast<const short8*>(
            Aq + (long)(wq0 + lm) * HD + kc * 32 + kq);
        if (kc < 7) {
            stage_k32(nxt, Ak, kc + 1, qt, tid, wave);   // flies under compute
        } else {
            // last iter: prefetch V tile 0 into buf0 (compute uses buf1)
            stage_v64(Ks, Av, 0, tid, wave);
        }
        __builtin_amdgcn_s_setprio(1);
#pragma unroll
        for (int nt = 0; nt < 32; ++nt) {
            if (nt < NT) {
                int row = nt * 16 + lm;
                short8 bf = *reinterpret_cast<const short8*>(
                    (const char*)cur + swzb(row * 64 + qg * 16));
                S[nt] = __builtin_amdgcn_mfma_f32_16x16x32_bf16(qf, bf, S[nt], 0, 0, 0);
            }
        }
        __builtin_amdgcn_s_setprio(0);
        __syncthreads();   // next-iter buffer ready; cur reads drained
    }

    // ---- Softmax in registers (V tile-0 prefetch still in flight) ----
    // S is pre-scaled by scale*log2e (folded into Q projection): P = 2^(S-mx)
    // via raw v_exp_f32. Deferred normalization (1/sum applied in epilogue).
    int   qrow[4];
    bool  rowm[4];
    float mx[4], sm[4];
#pragma unroll
    for (int r = 0; r < 4; ++r) {
        int q = wq0 + qg * 4 + r;
        qrow[r] = q;
        rowm[r] = maskc[bglob * SEQ + q] != 0;
        mx[r] = -3.4e38f;
    }
#pragma unroll
    for (int nt = 0; nt < 32; ++nt) {
        int k = nt * 16 + lm;
#pragma unroll
        for (int r = 0; r < 4; ++r) {
            float v = S[nt][r];
            if (k > qrow[r]) v = NEGV;
            S[nt][r] = v;
            mx[r] = fmaxf(mx[r], v);
        }
    }
#pragma unroll
    for (int r = 0; r < 4; ++r) {
#pragma unroll
        for (int off = 8; off >= 1; off >>= 1)
            mx[r] = fmaxf(mx[r], __shfl_xor(mx[r], off));
        sm[r] = 0.f;
    }
    uint32_t pk[32][2];   // bf16x2-packed unnormalized P (64 VGPRs)
#pragma unroll
    for (int nt = 0; nt < 32; ++nt) {
        float e0 = fast_exp2(S[nt][0] - mx[0]);
        float e1 = fast_exp2(S[nt][1] - mx[1]);
        float e2 = fast_exp2(S[nt][2] - mx[2]);
        float e3 = fast_exp2(S[nt][3] - mx[3]);
        sm[0] += e0; sm[1] += e1; sm[2] += e2; sm[3] += e3;
        pk[nt][0] = (uint32_t)f2b(e0) | ((uint32_t)f2b(e1) << 16);
        pk[nt][1] = (uint32_t)f2b(e2) | ((uint32_t)f2b(e3) << 16);
    }
#pragma unroll
    for (int r = 0; r < 4; ++r) {
#pragma unroll
        for (int off = 8; off >= 1; off >>= 1)
            sm[r] += __shfl_xor(sm[r], off);
        sm[r] = 1.0f / sm[r];    // applied to O in the epilogue
    }

    // ---- Phase 2: O = P.V, causal NC tiles of 64 keys, double-buffered V ----
    unsigned short* Vb0 = Ks;             // 32 KiB
    unsigned short* Vb1 = Ks + 16384;     // 32 KiB
    const int NC = qt + 1;
    f32x4 O[16] = {};
#pragma unroll
    for (int c64 = 0; c64 < 8; ++c64) {
        if (c64 < NC) {
            unsigned short* Vcur = (c64 & 1) ? Vb1 : Vb0;
            __syncthreads();     // drains staging of tile c64 (+ prior reads)
            if (c64 + 1 < NC) {  // prefetch tile c64+1 into the other buffer
                unsigned short* Vnext = (c64 & 1) ? Vb0 : Vb1;
                stage_v64(Vnext, Av, c64 + 1, tid, wave);
            }
#pragma unroll
            for (int t = 0; t < 2; ++t) {
                // P sub-chunk (32 keys): packed regs -> wave-private LDS
#pragma unroll
                for (int tt = 0; tt < 2; ++tt) {
                    int nt = c64 * 4 + t * 2 + tt;
#pragma unroll
                    for (int r = 0; r < 4; ++r)
                        Pw[wave][qg * 4 + r][tt * 16 + lm] =
                            (unsigned short)(pk[nt][r >> 1] >> ((r & 1) * 16));
                }
                short8 pf = *reinterpret_cast<const short8*>(&Pw[wave][lm][kq]);
                __builtin_amdgcn_s_setprio(1);
#pragma unroll
                for (int nt2 = 0; nt2 < 16; ++nt2) {
                    int row = nt2 * 16 + lm;
                    short8 vf = *reinterpret_cast<const short8*>(
                        (const char*)Vcur + swzb(row * 128 + t * 64 + qg * 16));
                    O[nt2] = __builtin_amdgcn_mfma_f32_16x16x32_bf16(pf, vf, O[nt2], 0, 0, 0);
                }
                __builtin_amdgcn_s_setprio(0);
            }
        }
    }

    // ---- epilogue: masked rows <- V column mean (uniform attention over
    // ALL keys); live rows <- O * 1/sum. Mean reduced from `part` in fp32;
    // identical rounding to the old Vm path. ----
    const float* pb = part + (long)(b_l * 8) * HD + h * DM + lm;
    float vmf[16];
#pragma unroll
    for (int nt2 = 0; nt2 < 16; ++nt2) {
        float s = 0.f;
#pragma unroll
        for (int seg = 0; seg < 8; ++seg)
            s += pb[(long)seg * HD + nt2 * 16];
        vmf[nt2] = s * (1.0f / SEQ);
    }
#pragma unroll
    for (int nt2 = 0; nt2 < 16; ++nt2) {
#pragma unroll
        for (int r = 0; r < 4; ++r) {
            int l = wq0 + qg * 4 + r;
            float val = rowm[r] ? vmf[nt2] : O[nt2][r] * sm[r];
            Ov[(long)l * HD + nt2 * 16 + lm] = f2b(val);
        }
    }
}

// ---------------------------------------------------------------------------
// LN1: x = bf16 AttO + fp32 Q + fp32 pe  ->  fp32 Xf AND bf16 Xb
// ---------------------------------------------------------------------------
__global__ __launch_bounds__(256) void ln1_kernel(
    const unsigned short* __restrict__ AttO, const float* __restrict__ Q,
    const float* __restrict__ pe,
    const float* __restrict__ gamma, const float* __restrict__ beta,
    float* __restrict__ outf, unsigned short* __restrict__ outb)
{
    int row  = blockIdx.x * 4 + (threadIdx.x >> 6);
    int lane = threadIdx.x & 63;
    long base = (long)row * DM + lane * 4;
    ushort4 a = *reinterpret_cast<const ushort4*>(AttO + base);
    float4 qv = *reinterpret_cast<const float4*>(Q + base);
    float4 pv = *reinterpret_cast<const float4*>(pe + (base & PE_MASK));
    float x[4] = {b2f(a.x) + qv.x + pv.x, b2f(a.y) + qv.y + pv.y,
                  b2f(a.z) + qv.z + pv.z, b2f(a.w) + qv.w + pv.w};
    float s = x[0] + x[1] + x[2] + x[3];
#pragma unroll
    for (int off = 32; off > 0; off >>= 1) s += __shfl_xor(s, off);
    float mu = s * (1.0f / DM);
    float vs = 0.f;
#pragma unroll
    for (int t = 0; t < 4; ++t) { float d = x[t] - mu; vs += d * d; }
#pragma unroll
    for (int off = 32; off > 0; off >>= 1) vs += __shfl_xor(vs, off);
    float inv = rsqrtf(vs * (1.0f / DM) + 1e-5f);
    int d0 = lane * 4;
    float4 g = *reinterpret_cast<const float4*>(gamma + d0);
    float4 bt = *reinterpret_cast<const float4*>(beta + d0);
    float4 o;
    o.x = (x[0] - mu) * inv * g.x + bt.x;
    o.y = (x[1] - mu) * inv * g.y + bt.y;
    o.z = (x[2] - mu) * inv * g.z + bt.z;
    o.w = (x[3] - mu) * inv * g.w + bt.w;
    *reinterpret_cast<float4*>(outf + base) = o;
    ushort4 ob;
    ob.x = f2b(o.x); ob.y = f2b(o.y); ob.z = f2b(o.z); ob.w = f2b(o.w);
    *reinterpret_cast<ushort4*>(outb + base) = ob;
}

// ---------------------------------------------------------------------------
// LN2: x = fp32 F + fp32 X  ->  FP32 out
// ---------------------------------------------------------------------------
__global__ __launch_bounds__(256) void ln2_kernel(
    const float* __restrict__ F, const float* __restrict__ X,
    const float* __restrict__ gamma, const float* __restrict__ beta,
    float* __restrict__ out)
{
    int row  = blockIdx.x * 4 + (threadIdx.x >> 6);
    int lane = threadIdx.x & 63;
    long base = (long)row * DM + lane * 4;
    float4 a = *reinterpret_cast<const float4*>(F + base);
    float4 c = *reinterpret_cast<const float4*>(X + base);
    float x[4] = {a.x + c.x, a.y + c.y, a.z + c.z, a.w + c.w};
    float s = x[0] + x[1] + x[2] + x[3];
#pragma unroll
    for (int off = 32; off > 0; off >>= 1) s += __shfl_xor(s, off);
    float mu = s * (1.0f / DM);
    float vs = 0.f;
#pragma unroll
    for (int t = 0; t < 4; ++t) { float d = x[t] - mu; vs += d * d; }
#pragma unroll
    for (int off = 32; off > 0; off >>= 1) vs += __shfl_xor(vs, off);
    float inv = rsqrtf(vs * (1.0f / DM) + 1e-5f);
    int d0 = lane * 4;
    float4 g = *reinterpret_cast<const float4*>(gamma + d0);
    float4 bt = *reinterpret_cast<const float4*>(beta + d0);
    float4 o;
    o.x = (x[0] - mu) * inv * g.x + bt.x;
    o.y = (x[1] - mu) * inv * g.y + bt.y;
    o.z = (x[2] - mu) * inv * g.z + bt.z;
    o.w = (x[3] - mu) * inv * g.w + bt.w;
    *reinterpret_cast<float4*>(out + base) = o;
}

// ---------------------------------------------------------------------------
extern "C" void kernel_launch(void* const* d_in, const int* in_sizes, int n_in,
                              void* d_out, int out_size, void* d_ws, size_t ws_size,
                              hipStream_t stream)
{
    const float* Q  = (const float*)d_in[0];
    const float* Ki = (const float*)d_in[1];
    const float* Vi = (const float*)d_in[2];
    const unsigned char* mask_raw = (const unsigned char*)d_in[3];
    const float* pe = (const float*)d_in[4];
    const float* Wq = (const float*)d_in[5];
    const float* Wk = (const float*)d_in[6];
    const float* Wv = (const float*)d_in[7];
    const float* Wo = (const float*)d_in[8];
    const float* w1 = (const float*)d_in[9];
    const float* b1 = (const float*)d_in[10];
    const float* w2 = (const float*)d_in[11];
    const float* b2 = (const float*)d_in[12];
    const float* gamma = (const float*)d_in[13];
    const float* beta  = (const float*)d_in[14];
    float* out = (float*)d_out;

    const size_t MiB = 1048576;
    char* ws = (char*)d_ws;

    // ---- adaptive chunk size: footprint = 59 + max(5*CB + 32KB*CB, 24) MiB --
    int CB = 1;
    for (int cb = 32; cb >= 1; cb >>= 1) {
        size_t scr_sz = (size_t)(5 * cb) * MiB + (size_t)cb * 32768;
        if (scr_sz < 24 * MiB) scr_sz = 24 * MiB;
        if ((59 * MiB + scr_sz) <= ws_size) { CB = cb; break; }
    }
    const int NCH = NB / CB;

    // ---- fixed low regions ----
    unsigned short* WqT  = (unsigned short*)(ws);                 // 512 KiB each
    unsigned short* WkT  = WqT + 262144;
    unsigned short* WvT  = WkT + 262144;
    unsigned short* WoT  = WvT + 262144;
    unsigned short* w1b  = (unsigned short*)(ws + 2 * MiB);       // 128 KiB
    unsigned short* w2b  = w1b + 65536;                           // 128 KiB
    int*            maskc = (int*)(ws + 2 * MiB + 262144);        // 64 KiB
    unsigned short* Qp   = (unsigned short*)(ws + 3 * MiB);       // 8 MiB bf16
    unsigned short* Kp   = (unsigned short*)(ws + 11 * MiB);      // 8 MiB
    unsigned short* Vp   = (unsigned short*)(ws + 19 * MiB);      // 8 MiB
    unsigned short* AttO = (unsigned short*)(ws + 27 * MiB);      // 8 MiB
    unsigned short* Xb   = (unsigned short*)(ws + 35 * MiB);      // 8 MiB
    float*          Xf   = (float*)(ws + 43 * MiB);               // 16 MiB
    char*           scr  = ws + 59 * MiB;
    // chunk scratch (CB MiB each)
    unsigned short* Qh   = (unsigned short*)(scr);
    unsigned short* Kh   = (unsigned short*)(scr + (size_t)CB * MiB);
    unsigned short* Vh   = (unsigned short*)(scr + (size_t)2 * CB * MiB);
    unsigned short* VhT  = (unsigned short*)(scr + (size_t)3 * CB * MiB);
    unsigned short* Vatt = (unsigned short*)(scr + (size_t)4 * CB * MiB);
    // vmean partial sums (per chunk; dead at tail-alias time)
    float*          part = (float*)(scr + (size_t)5 * CB * MiB);  // CB*32 KiB
    // tail aliases over scratch (chunk buffers dead by then)
    unsigned short* H1   = (unsigned short*)(scr);                // 8 MiB bf16
    float*          Ff   = (float*)(scr + 8 * MiB);               // 16 MiB fp32

    // softmax scale * log2(e), folded into the Q projection (z==0 slab)
    const float SCALE_Q = (float)((1.0 / (16.0 + 1e-6)) * 1.4426950408889634);
    const long CROWS = (long)CB * SEQ;
    const long CBELT = (long)CB * MiB / 2;     // chunk-buffer stride, elements

    // 0. fused prep: mask + weight transposes/conversions + PE-add (1 dispatch)
    prep_all<<<13504, 256, 0, stream>>>(
        mask_raw, maskc, Wq, Wk, Wv, WqT, Wo, WoT,
        w1, w2, w1b, w2b, Q, Ki, Vi, pe, Qp, Kp, Vp);

    // 1. attention in NCH chunks of CB batches
    for (int c = 0; c < NCH; ++c) {
        const long r0   = (long)c * CROWS;
        const int  bh0  = c * CB * NH;
        const int  gy   = (int)(CROWS / 128);
        const int  nbh  = CB * NH;

        // all 3 projections in ONE dispatch (z=0: Q scaled by SCALE_Q, 1:K, 2:V)
        gemm_bt<false, false, true><<<dim3(8, gy, 3), 256, 0, stream>>>(
            Qp + r0 * DM, DM, WqT, DM, Qh, HD, nullptr, SCALE_Q, DM,
            1, 4194304, 0, 0, 262144, 0, 0, CBELT, 0, 0);

        // fused per-head V transpose + vmean partial sums (1 dispatch)
        tv_kernel<<<CB * NH * 128 + CB * 8, 256, 0, stream>>>(
            Vh, VhT, part, CB);

        // fused attention (+ masked-row mean + store, 1 dispatch)
        flash_attn<<<dim3(8 * nbh, 1, 1), 256, 0, stream>>>(
            Qh, Kh, VhT, part, Vatt, maskc, bh0, nbh);

        // output projection for this chunk -> AttO rows [r0, r0+CROWS)
        gemm_bt<false, false, true><<<dim3(2, gy, 1), 256, 0, stream>>>(
            Vatt, HD, WoT, HD, AttO + r0 * DM, DM, nullptr, 1.f, HD,
            1, 0,0,0, 0,0,0, 0,0,0);
    }

    // 2. LN1: X = LN(Q + pe + AttO) -> fp32 Xf + bf16 Xb
    ln1_kernel<<<4096, 256, 0, stream>>>(AttO, Q, pe, gamma, beta, Xf, Xb);

    // 3. FFN1: H1 = relu(Xb @ w1^T + b1) -> bf16
    gemm_bt<true, true, true><<<dim3(2, 128, 1), 256, 0, stream>>>(
        Xb, DM, w1b, DM, H1, DM, b1, 1.f, DM, 1, 0,0,0, 0,0,0, 0,0,0);
    // 4. FFN2: F = H1 @ w2^T + b2 -> fp32
    gemm_bt<true, false, false><<<dim3(2, 128, 1), 256, 0, stream>>>(
        H1, DM, w2b, DM, Ff, DM, b2, 1.f, DM, 1, 0,0,0, 0,0,0, 0,0,0);

    // 5. LN2: out = LN(F + X) -> FP32
    ln2_kernel<<<4096, 256, 0, stream>>>(Ff, Xf, gamma, beta, out);
}

// Round 7
// 324.711 us; speedup vs baseline: 1.1985x; 1.0244x over previous
//
#include <hip/hip_runtime.h>
#include <stdint.h>

// ---------------------------------------------------------------------------
// TransformerBlock: B=32, L=512, D=256, H=4.
// Inputs fp32 (dict order); OUTPUT fp32.
// r16: gemm_bt upgraded with the flash-proven trio:
//   - LDS XOR-swizzle (swzb) on As/Bs: kills the 8-way ds_read_b128 bank
//     conflict (64B row stride) — same involution HW-verified in flash
//     (4.67M -> 147K conflict-cycles).
//   - double-buffered stage-ahead K-loop (1 barrier/K-step, loads fly
//     under MFMA) replacing the 2-barrier m97 structure.
//   - no setprio in gemm (T5 null on 2-phase GEMM per regime gate).
// r15 (kept): 9 dispatches/iter (prep_all, tv_kernel, flash-fused epilogue).
// flash internals = r14 (proven): XCD swizzle + complementary qt pairing,
//   LDS XOR-swizzle, causal dbuf stage-ahead, scale*log2e folded into Q
//   projection -> raw v_exp_f32, 64-key V tiles, setprio, deferred norm,
//   early bf16 P-packing, launch_bounds(256,2).
// ws = 59 + 5*CB MiB + CB*32KB (CB=32 -> single chunk at ws=256MiB).
// ---------------------------------------------------------------------------
#define SEQ   512
#define DM    256
#define NB    32
#define NH    4
#define HD    (NH * DM)           // 1024
#define PE_MASK (SEQ * DM - 1)    // 131071
#define NEGV  (-4294967295.0f)

typedef __attribute__((ext_vector_type(8))) short short8;   // 8 x bf16
typedef __attribute__((ext_vector_type(4))) float f32x4;    // MFMA accumulator

#if defined(__has_builtin)
#if __has_builtin(__builtin_amdgcn_global_load_lds)
#define HAS_ASYNC 1
#endif
#endif
#ifndef HAS_ASYNC
#define HAS_ASYNC 0
#endif

__device__ __forceinline__ float b2f(unsigned short u) {
    return __uint_as_float(((uint32_t)u) << 16);
}
__device__ __forceinline__ unsigned short f2b(float f) {
    uint32_t u = __float_as_uint(f);
    u += 0x7fffu + ((u >> 16) & 1u);   // RNE
    return (unsigned short)(u >> 16);
}
// raw v_exp_f32: 2^x on the transcendental pipe (input pre-scaled by log2e)
__device__ __forceinline__ float fast_exp2(float x) {
    float r;
    asm("v_exp_f32 %0, %1" : "=v"(r) : "v"(x));
    return r;
}

// LDS bank swizzle: involution XORing byte bits [6:4] with bits [9:7].
// 64B-row tiles (K/A/B): row=b>>6, group=(4*(row&1)+qg)^((row>>1)&7) -> free.
// 128B-row tiles (V):    row=b>>7, group=(t*4+qg)^(row&7)           -> free.
__device__ __forceinline__ int swzb(int b) {
    return b ^ (((b >> 7) & 7) << 4);
}

// ---------------------------------------------------------------------------
// prep_all: fused preprocessing, one dispatch (13504 blocks):
//   [0,64)        mask_canon (auto-detect uint8/int32/int64 -> int32)
//   [64,832)      Wq/Wk/Wv fp32->bf16 transpose (32x8x3 tiles)
//   [832,1088)    Wo fp32->bf16 transpose (8x32 tiles)
//   [1088,1216)   w1,w2 fp32->bf16 convert
//   [1216,13504)  Q/K/V + pe -> bf16 (addpe)
// ---------------------------------------------------------------------------
__global__ __launch_bounds__(256) void prep_all(
    const unsigned char* __restrict__ mask_raw, int* __restrict__ maskc,
    const float* __restrict__ Wq, const float* __restrict__ Wk,
    const float* __restrict__ Wv, unsigned short* __restrict__ WqT,
    const float* __restrict__ Wo, unsigned short* __restrict__ WoT,
    const float* __restrict__ w1, const float* __restrict__ w2,
    unsigned short* __restrict__ o1, unsigned short* __restrict__ o2,
    const float* __restrict__ Q, const float* __restrict__ K,
    const float* __restrict__ V, const float* __restrict__ pe,
    unsigned short* __restrict__ Qp, unsigned short* __restrict__ Kp,
    unsigned short* __restrict__ Vp)
{
    __shared__ unsigned short tile[32][33];
    __shared__ int enc[2];
    const int blk = blockIdx.x;
    const int tid = threadIdx.x;

    if (blk < 64) {
        // ---- mask canonicalization ----
        if (tid == 0) { enc[0] = 0; enc[1] = 0; }
        __syncthreads();
        if (tid < 255 && mask_raw[tid * 4 + 1]) atomicOr(&enc[0], 1);
        if (tid < 128 && ((const int*)mask_raw)[tid * 2 + 1]) atomicOr(&enc[1], 1);
        __syncthreads();
        int i = blk * 256 + tid;
        int v;
        if (enc[0])      v = (mask_raw[i] != 0);
        else if (enc[1]) v = (((const int*)mask_raw)[i] != 0);
        else             v = ((((const int*)mask_raw)[i * 2] |
                              ((const int*)mask_raw)[i * 2 + 1]) != 0);
        maskc[i] = v;
    } else if (blk < 832) {
        // ---- Wq/Wk/Wv transpose fp32 -> bf16 (out[c][r]) ----
        int t = blk - 64;
        int x = t & 31, y = (t >> 5) & 7, zz = t >> 8;
        const float* in = (zz == 0) ? Wq : (zz == 1) ? Wk : Wv;
        unsigned short* op = WqT + (long)zz * 262144;
        int r0 = y * 32, c0 = x * 32;
        int i = tid >> 3, j = (tid & 7) * 4;
        float4 v = *reinterpret_cast<const float4*>(in + (long)(r0 + i) * HD + c0 + j);
        tile[i][j + 0] = f2b(v.x); tile[i][j + 1] = f2b(v.y);
        tile[i][j + 2] = f2b(v.z); tile[i][j + 3] = f2b(v.w);
        __syncthreads();
        ushort4 w;
        w.x = tile[j + 0][i]; w.y = tile[j + 1][i];
        w.z = tile[j + 2][i]; w.w = tile[j + 3][i];
        *reinterpret_cast<ushort4*>(op + (long)(c0 + i) * DM + r0 + j) = w;
    } else if (blk < 1088) {
        // ---- Wo transpose fp32 -> bf16 ----
        int t = blk - 832;
        int x = t & 7, y = t >> 3;
        int r0 = y * 32, c0 = x * 32;
        int i = tid >> 3, j = (tid & 7) * 4;
        float4 v = *reinterpret_cast<const float4*>(Wo + (long)(r0 + i) * DM + c0 + j);
        tile[i][j + 0] = f2b(v.x); tile[i][j + 1] = f2b(v.y);
        tile[i][j + 2] = f2b(v.z); tile[i][j + 3] = f2b(v.w);
        __syncthreads();
        ushort4 w;
        w.x = tile[j + 0][i]; w.y = tile[j + 1][i];
        w.z = tile[j + 2][i]; w.w = tile[j + 3][i];
        *reinterpret_cast<ushort4*>(WoT + (long)(c0 + i) * HD + r0 + j) = w;
    } else if (blk < 1216) {
        // ---- w1/w2 fp32 -> bf16 ----
        int t = blk - 1088;
        const float* in = (t < 64) ? w1 : w2;
        unsigned short* out = (t < 64) ? o1 : o2;
        long i = (long)((t & 63) * 256 + tid) * 4;
        float4 x = *reinterpret_cast<const float4*>(in + i);
        ushort4 o;
        o.x = f2b(x.x); o.y = f2b(x.y); o.z = f2b(x.z); o.w = f2b(x.w);
        *reinterpret_cast<ushort4*>(out + i) = o;
    } else {
        // ---- Q/K/V + pe -> bf16 ----
        int t = blk - 1216;
        int seg = t >> 12;
        const float* X = (seg == 0) ? Q : (seg == 1) ? K : V;
        unsigned short* O = (seg == 0) ? Qp : (seg == 1) ? Kp : Vp;
        long i = (long)((t & 4095) * 256 + tid) * 4;
        float4 x = *reinterpret_cast<const float4*>(X + i);
        float4 p = *reinterpret_cast<const float4*>(pe + (i & PE_MASK));
        ushort4 o;
        o.x = f2b(x.x + p.x); o.y = f2b(x.y + p.y);
        o.z = f2b(x.z + p.z); o.w = f2b(x.w + p.w);
        *reinterpret_cast<ushort4*>(O + i) = o;
    }
}

// ---------------------------------------------------------------------------
// tv_kernel: fused per-head V transpose + vmean partial sums (both read Vh):
//   [0, nbl*NH*128)        VhT[bl][h][d][l] = Vh[bl][l][h*256+d]
//   [nT, nT + nbl*8)       part[(bl*8+seg)][c] = sum_{l in seg*64..+64} Vh[bl][l][c]
// ---------------------------------------------------------------------------
__global__ __launch_bounds__(256) void tv_kernel(
    const unsigned short* __restrict__ Vh, unsigned short* __restrict__ VhT,
    float* __restrict__ part, int nbl)
{
    __shared__ unsigned short tile[32][33];
    const int blk = blockIdx.x;
    const int tid = threadIdx.x;
    const int nT = nbl * NH * 128;           // 8x16 tiles per (bl,h)

    if (blk < nT) {
        int x = blk & 7, y = (blk >> 3) & 15, zz = blk >> 7;
        int b = zz / NH, hh = zz % NH;
        const unsigned short* ip = Vh + (long)b * SEQ * HD + (long)hh * DM;
        unsigned short* op = VhT + (long)b * SEQ * HD + (long)hh * SEQ * DM;
        int r0 = y * 32, c0 = x * 32;
        int i = tid >> 3, j = (tid & 7) * 4;
        ushort4 v = *reinterpret_cast<const ushort4*>(ip + (long)(r0 + i) * HD + c0 + j);
        tile[i][j + 0] = v.x; tile[i][j + 1] = v.y;
        tile[i][j + 2] = v.z; tile[i][j + 3] = v.w;
        __syncthreads();
        ushort4 w;
        w.x = tile[j + 0][i]; w.y = tile[j + 1][i];
        w.z = tile[j + 2][i]; w.w = tile[j + 3][i];
        *reinterpret_cast<ushort4*>(op + (long)(c0 + i) * SEQ + r0 + j) = w;
    } else {
        int t = blk - nT;
        int bl = t >> 3, seg = t & 7;
        const unsigned short* p = Vh + (long)bl * SEQ * HD + (long)seg * 64 * HD;
        int c = tid * 4;
        float s0 = 0.f, s1 = 0.f, s2 = 0.f, s3 = 0.f;
        for (int l = 0; l < 64; ++l) {
            ushort4 v = *reinterpret_cast<const ushort4*>(p + (long)l * HD + c);
            s0 += b2f(v.x); s1 += b2f(v.y); s2 += b2f(v.z); s3 += b2f(v.w);
        }
        float4 o = {s0, s1, s2, s3};
        *reinterpret_cast<float4*>(part + (long)(bl * 8 + seg) * HD + c) = o;
    }
}

// ---------------------------------------------------------------------------
// Pure-bf16 MFMA GEMM: C = scl*A.Bt (+bias, relu), 128x128 tile.
// r16: XOR-swizzled As/Bs (pre-swizzled global source via global_load_lds,
// swizzled ds_read — rule 21) + double-buffered stage-ahead K-loop
// (1 barrier/K-step). MFMA order per K-step unchanged -> bit-identical.
// `scale` applies to blockIdx.z==0 slabs ONLY (others get 1.0) — used to
// fold softmax scale*log2e into the Q projection.
// ---------------------------------------------------------------------------
template<bool BIAS, bool RELU, bool OUTBF16>
__global__ __launch_bounds__(256) void gemm_bt(
    const unsigned short* __restrict__ A, int lda,
    const unsigned short* __restrict__ B, int ldb,
    void* __restrict__ Cv, int ldc,
    const float* __restrict__ bias, float scale, int K, int Hdiv,
    long sAb, long sAh, long sAz,
    long sBb, long sBh, long sBz,
    long sCb, long sCh, long sCz)
{
    const int m0 = blockIdx.y * 128;
    const int n0 = blockIdx.x * 128;
    int z  = blockIdx.z;
    int bb = z / Hdiv, hh = z % Hdiv;
    const unsigned short* Ab = A + bb * sAb + hh * sAh + (long)z * sAz;
    const unsigned short* Bb = B + bb * sBb + hh * sBh + (long)z * sBz;
    long coff = bb * sCb + hh * sCh + (long)z * sCz;
    const float scl = (z == 0) ? scale : 1.0f;

    __shared__ unsigned short As[2][128 * 32];   // 2 x 8 KiB, swizzled layout
    __shared__ unsigned short Bs[2][128 * 32];

    const int tid  = threadIdx.x;
    const int lane = tid & 63;
    const int wave = tid >> 6;
    const int wm   = (wave >> 1) * 64;
    const int wn   = (wave & 1) * 64;
    const int lm   = lane & 15;
    const int kq   = (lane >> 4) * 8;

    f32x4 acc[4][4] = {};

    // stage K-step starting at column k0 into buffer b (pre-swizzled source)
    auto stage = [&](int b, int k0) {
#pragma unroll
        for (int it = 0; it < 2; ++it) {
            int id = tid + it * 256;
#if HAS_ASYNC
            int U  = swzb(id * 16);
            int r  = U >> 6;
            int c8 = ((U >> 4) & 3) * 8;
            const unsigned short* gA = Ab + (long)(m0 + r) * lda + k0 + c8;
            const unsigned short* gB = Bb + (long)(n0 + r) * ldb + k0 + c8;
            unsigned short* lA = &As[b][(size_t)(it * 256 + wave * 64) * 8];
            unsigned short* lB = &Bs[b][(size_t)(it * 256 + wave * 64) * 8];
            __builtin_amdgcn_global_load_lds(
                (const __attribute__((address_space(1))) void*)gA,
                (__attribute__((address_space(3))) void*)lA, 16, 0, 0);
            __builtin_amdgcn_global_load_lds(
                (const __attribute__((address_space(1))) void*)gB,
                (__attribute__((address_space(3))) void*)lB, 16, 0, 0);
#else
            int r  = id >> 2;
            int c8 = (id & 3) * 8;
            const unsigned short* gA = Ab + (long)(m0 + r) * lda + k0 + c8;
            const unsigned short* gB = Bb + (long)(n0 + r) * ldb + k0 + c8;
            *reinterpret_cast<uint4*>((char*)As[b] + swzb(id * 16)) =
                *reinterpret_cast<const uint4*>(gA);
            *reinterpret_cast<uint4*>((char*)Bs[b] + swzb(id * 16)) =
                *reinterpret_cast<const uint4*>(gB);
#endif
        }
    };

    stage(0, 0);                 // prologue: K-step 0 -> buf0
    __syncthreads();
    const int nk = K >> 5;
    for (int kk = 0; kk < nk; ++kk) {
        const int cur = kk & 1;
        if (kk + 1 < nk)
            stage(cur ^ 1, (kk + 1) * 32);   // flies under this step's MFMAs

        short8 af[4], bfr[4];
#pragma unroll
        for (int i = 0; i < 4; ++i)
            af[i] = *reinterpret_cast<const short8*>(
                (const char*)As[cur] + swzb((wm + i * 16 + lm) * 64 + kq * 2));
#pragma unroll
        for (int j = 0; j < 4; ++j)
            bfr[j] = *reinterpret_cast<const short8*>(
                (const char*)Bs[cur] + swzb((wn + j * 16 + lm) * 64 + kq * 2));
#pragma unroll
        for (int i = 0; i < 4; ++i)
#pragma unroll
            for (int j = 0; j < 4; ++j)
                acc[i][j] = __builtin_amdgcn_mfma_f32_16x16x32_bf16(af[i], bfr[j], acc[i][j], 0, 0, 0);
        __syncthreads();   // cur reads drained before kk+1 overwrites; nxt ready
    }

#pragma unroll
    for (int j = 0; j < 4; ++j) {
        int col  = n0 + wn + j * 16 + lm;
        float bv = 0.f;
        if (BIAS) bv = bias[col];
#pragma unroll
        for (int i = 0; i < 4; ++i) {
#pragma unroll
            for (int r = 0; r < 4; ++r) {
                int row = m0 + wm + i * 16 + (lane >> 4) * 4 + r;
                float v = acc[i][j][r] * scl + bv;
                if (RELU) v = fmaxf(v, 0.f);
                long idx = coff + (long)row * ldc + col;
                if (OUTBF16) reinterpret_cast<unsigned short*>(Cv)[idx] = f2b(v);
                else         reinterpret_cast<float*>(Cv)[idx] = v;
            }
        }
    }
}

// ---------------------------------------------------------------------------
// flash_attn staging: linear LDS dest (gload_lds requirement) + pre-swizzled
// GLOBAL source; fallback stores to swizzled LDS address (rule 21).
// ---------------------------------------------------------------------------
// K tile: 64B rows (32 d-cols), causal row bound (qt+1)*64.
__device__ __forceinline__ void stage_k32(
    unsigned short* __restrict__ buf, const unsigned short* __restrict__ Ak,
    int kc, int qt, int tid, int wave)
{
    for (int it = 0; it <= qt; ++it) {
        int id = tid + it * 256;
#if HAS_ASYNC
        int U = swzb(id * 16);
        const unsigned short* g = Ak + (long)(U >> 6) * HD + kc * 32 + ((U >> 4) & 3) * 8;
        unsigned short* l = buf + (size_t)(it * 256 + wave * 64) * 8;
        __builtin_amdgcn_global_load_lds(
            (const __attribute__((address_space(1))) void*)g,
            (__attribute__((address_space(3))) void*)l, 16, 0, 0);
#else
        const unsigned short* g = Ak + (long)(id >> 2) * HD + kc * 32 + (id & 3) * 8;
        *reinterpret_cast<uint4*>((char*)buf + swzb(id * 16)) =
            *reinterpret_cast<const uint4*>(g);
#endif
    }
}

// V tile: 128B rows (256 d-rows x 64 key-cols = 32KB per buffer).
__device__ __forceinline__ void stage_v64(
    unsigned short* __restrict__ buf, const unsigned short* __restrict__ Av,
    int c64, int tid, int wave)
{
#pragma unroll
    for (int it = 0; it < 8; ++it) {
        int id = tid + it * 256;
#if HAS_ASYNC
        int U = swzb(id * 16);
        const unsigned short* g = Av + (long)(U >> 7) * SEQ + c64 * 64 + ((U >> 4) & 7) * 8;
        unsigned short* l = buf + (size_t)(it * 256 + wave * 64) * 8;
        __builtin_amdgcn_global_load_lds(
            (const __attribute__((address_space(1))) void*)g,
            (__attribute__((address_space(3))) void*)l, 16, 0, 0);
#else
        const unsigned short* g = Av + (long)(id >> 3) * SEQ + c64 * 64 + (id & 7) * 8;
        *reinterpret_cast<uint4*>((char*)buf + swzb(id * 16)) =
            *reinterpret_cast<const uint4*>(g);
#endif
    }
}

// ---------------------------------------------------------------------------
// Fused flash attention. Grid 8*nbh blocks. XCD = L&7; within an XCD the
// dispatch order pairs complementary q-tiles (qt, 7-qt).
// Phase 1: causal dbuf stage-ahead; Ks reads XOR-swizzled; setprio MFMA.
// Softmax: Q pre-scaled by scale*log2e at projection -> raw v_exp_f32;
//   causal-only masking; deferred normalization; early bf16 P-packing.
// Phase 2: causal NC = qt+1 tiles of 64 keys, V dbuf (1 barrier/tile).
// Epilogue: masked rows get uniform-attention value = V column mean,
//   reduced in-register from `part` (8 partial-sum rows); rounding matches
//   the old vmean_reduce/fix_mask path exactly (f2b(sum/512)).
// ---------------------------------------------------------------------------
__global__ __launch_bounds__(256, 2) void flash_attn(
    const unsigned short* __restrict__ Qh,
    const unsigned short* __restrict__ Kh,
    const unsigned short* __restrict__ VhT,
    const float* __restrict__ part,
    unsigned short* __restrict__ Vatt,
    const int* __restrict__ maskc, int bh0, int nbh)
{
    const int tid  = threadIdx.x;
    const int lane = tid & 63;
    const int wave = tid >> 6;
    const int lm   = lane & 15;
    const int qg   = lane >> 4;
    const int kq   = qg * 8;

    const int L = blockIdx.x;
    int z, qt;
    if ((nbh & 7) == 0) {
        int x = L & 7, m = L >> 3;
        int mq = m & 7;
        qt = (mq & 1) ? (7 - (mq >> 1)) : (mq >> 1);   // 0,7,1,6,2,5,3,4
        z  = x + 8 * (m >> 3);
    } else {
        z = L % nbh; qt = L / nbh;
    }
    const int b_l = z >> 2, h = z & 3;
    const int m0  = qt * 64;
    const int wq0 = m0 + wave * 16;
    const long qkbase = (long)b_l * SEQ * HD + (long)h * DM;
    const unsigned short* Aq = Qh + qkbase;
    const unsigned short* Ak = Kh + qkbase;
    const unsigned short* Av = VhT + (long)b_l * SEQ * HD + (long)h * SEQ * DM;
    unsigned short* Ov = Vatt + qkbase;
    const int bglob = (bh0 + z) >> 2;

    __shared__ unsigned short Ks[2 * SEQ * 32];             // 64 KiB dbuf
    __shared__ __align__(16) unsigned short Pw[4][16][40];  // 5 KiB

    f32x4 S[32] = {};
    const int NT = (m0 >> 4) + wave + 1;     // causal tile bound (wave-uniform)

    // ---- Phase 1: S = Q.K^T over 8 d-chunks of 32, causal dbuf stage-ahead --
    stage_k32(Ks, Ak, 0, qt, tid, wave);     // prologue: chunk 0 -> buf0
    __syncthreads();
    for (int kc = 0; kc < 8; ++kc) {
        unsigned short* cur = (kc & 1) ? (Ks + SEQ * 32) : Ks;
        unsigned short* nxt = (kc & 1) ? Ks : (Ks + SEQ * 32);
        short8 qf = *reinterpret_cast<const short8*>(
            Aq + (long)(wq0 + lm) * HD + kc * 32 + kq);
        if (kc < 7) {
            stage_k32(nxt, Ak, kc + 1, qt, tid, wave);   // flies under compute
        } else {
            // last iter: prefetch V tile 0 into buf0 (compute uses buf1)
            stage_v64(Ks, Av, 0, tid, wave);
        }
        __builtin_amdgcn_s_setprio(1);
#pragma unroll
        for (int nt = 0; nt < 32; ++nt) {
            if (nt < NT) {
                int row = nt * 16 + lm;
                short8 bf = *reinterpret_cast<const short8*>(
                    (const char*)cur + swzb(row * 64 + qg * 16));
                S[nt] = __builtin_amdgcn_mfma_f32_16x16x32_bf16(qf, bf, S[nt], 0, 0, 0);
            }
        }
        __builtin_amdgcn_s_setprio(0);
        __syncthreads();   // next-iter buffer ready; cur reads drained
    }

    // ---- Softmax in registers (V tile-0 prefetch still in flight) ----
    // S is pre-scaled by scale*log2e (folded into Q projection): P = 2^(S-mx)
    // via raw v_exp_f32. Deferred normalization (1/sum applied in epilogue).
    int   qrow[4];
    bool  rowm[4];
    float mx[4], sm[4];
#pragma unroll
    for (int r = 0; r < 4; ++r) {
        int q = wq0 + qg * 4 + r;
        qrow[r] = q;
        rowm[r] = maskc[bglob * SEQ + q] != 0;
        mx[r] = -3.4e38f;
    }
#pragma unroll
    for (int nt = 0; nt < 32; ++nt) {
        int k = nt * 16 + lm;
#pragma unroll
        for (int r = 0; r < 4; ++r) {
            float v = S[nt][r];
            if (k > qrow[r]) v = NEGV;
            S[nt][r] = v;
            mx[r] = fmaxf(mx[r], v);
        }
    }
#pragma unroll
    for (int r = 0; r < 4; ++r) {
#pragma unroll
        for (int off = 8; off >= 1; off >>= 1)
            mx[r] = fmaxf(mx[r], __shfl_xor(mx[r], off));
        sm[r] = 0.f;
    }
    uint32_t pk[32][2];   // bf16x2-packed unnormalized P (64 VGPRs)
#pragma unroll
    for (int nt = 0; nt < 32; ++nt) {
        float e0 = fast_exp2(S[nt][0] - mx[0]);
        float e1 = fast_exp2(S[nt][1] - mx[1]);
        float e2 = fast_exp2(S[nt][2] - mx[2]);
        float e3 = fast_exp2(S[nt][3] - mx[3]);
        sm[0] += e0; sm[1] += e1; sm[2] += e2; sm[3] += e3;
        pk[nt][0] = (uint32_t)f2b(e0) | ((uint32_t)f2b(e1) << 16);
        pk[nt][1] = (uint32_t)f2b(e2) | ((uint32_t)f2b(e3) << 16);
    }
#pragma unroll
    for (int r = 0; r < 4; ++r) {
#pragma unroll
        for (int off = 8; off >= 1; off >>= 1)
            sm[r] += __shfl_xor(sm[r], off);
        sm[r] = 1.0f / sm[r];    // applied to O in the epilogue
    }

    // ---- Phase 2: O = P.V, causal NC tiles of 64 keys, double-buffered V ----
    unsigned short* Vb0 = Ks;             // 32 KiB
    unsigned short* Vb1 = Ks + 16384;     // 32 KiB
    const int NC = qt + 1;
    f32x4 O[16] = {};
#pragma unroll
    for (int c64 = 0; c64 < 8; ++c64) {
        if (c64 < NC) {
            unsigned short* Vcur = (c64 & 1) ? Vb1 : Vb0;
            __syncthreads();     // drains staging of tile c64 (+ prior reads)
            if (c64 + 1 < NC) {  // prefetch tile c64+1 into the other buffer
                unsigned short* Vnext = (c64 & 1) ? Vb0 : Vb1;
                stage_v64(Vnext, Av, c64 + 1, tid, wave);
            }
#pragma unroll
            for (int t = 0; t < 2; ++t) {
                // P sub-chunk (32 keys): packed regs -> wave-private LDS
#pragma unroll
                for (int tt = 0; tt < 2; ++tt) {
                    int nt = c64 * 4 + t * 2 + tt;
#pragma unroll
                    for (int r = 0; r < 4; ++r)
                        Pw[wave][qg * 4 + r][tt * 16 + lm] =
                            (unsigned short)(pk[nt][r >> 1] >> ((r & 1) * 16));
                }
                short8 pf = *reinterpret_cast<const short8*>(&Pw[wave][lm][kq]);
                __builtin_amdgcn_s_setprio(1);
#pragma unroll
                for (int nt2 = 0; nt2 < 16; ++nt2) {
                    int row = nt2 * 16 + lm;
                    short8 vf = *reinterpret_cast<const short8*>(
                        (const char*)Vcur + swzb(row * 128 + t * 64 + qg * 16));
                    O[nt2] = __builtin_amdgcn_mfma_f32_16x16x32_bf16(pf, vf, O[nt2], 0, 0, 0);
                }
                __builtin_amdgcn_s_setprio(0);
            }
        }
    }

    // ---- epilogue: masked rows <- V column mean (uniform attention over
    // ALL keys); live rows <- O * 1/sum. Mean reduced from `part` in fp32;
    // identical rounding to the old Vm path. ----
    const float* pb = part + (long)(b_l * 8) * HD + h * DM + lm;
    float vmf[16];
#pragma unroll
    for (int nt2 = 0; nt2 < 16; ++nt2) {
        float s = 0.f;
#pragma unroll
        for (int seg = 0; seg < 8; ++seg)
            s += pb[(long)seg * HD + nt2 * 16];
        vmf[nt2] = s * (1.0f / SEQ);
    }
#pragma unroll
    for (int nt2 = 0; nt2 < 16; ++nt2) {
#pragma unroll
        for (int r = 0; r < 4; ++r) {
            int l = wq0 + qg * 4 + r;
            float val = rowm[r] ? vmf[nt2] : O[nt2][r] * sm[r];
            Ov[(long)l * HD + nt2 * 16 + lm] = f2b(val);
        }
    }
}

// ---------------------------------------------------------------------------
// LN1: x = bf16 AttO + fp32 Q + fp32 pe  ->  fp32 Xf AND bf16 Xb
// ---------------------------------------------------------------------------
__global__ __launch_bounds__(256) void ln1_kernel(
    const unsigned short* __restrict__ AttO, const float* __restrict__ Q,
    const float* __restrict__ pe,
    const float* __restrict__ gamma, const float* __restrict__ beta,
    float* __restrict__ outf, unsigned short* __restrict__ outb)
{
    int row  = blockIdx.x * 4 + (threadIdx.x >> 6);
    int lane = threadIdx.x & 63;
    long base = (long)row * DM + lane * 4;
    ushort4 a = *reinterpret_cast<const ushort4*>(AttO + base);
    float4 qv = *reinterpret_cast<const float4*>(Q + base);
    float4 pv = *reinterpret_cast<const float4*>(pe + (base & PE_MASK));
    float x[4] = {b2f(a.x) + qv.x + pv.x, b2f(a.y) + qv.y + pv.y,
                  b2f(a.z) + qv.z + pv.z, b2f(a.w) + qv.w + pv.w};
    float s = x[0] + x[1] + x[2] + x[3];
#pragma unroll
    for (int off = 32; off > 0; off >>= 1) s += __shfl_xor(s, off);
    float mu = s * (1.0f / DM);
    float vs = 0.f;
#pragma unroll
    for (int t = 0; t < 4; ++t) { float d = x[t] - mu; vs += d * d; }
#pragma unroll
    for (int off = 32; off > 0; off >>= 1) vs += __shfl_xor(vs, off);
    float inv = rsqrtf(vs * (1.0f / DM) + 1e-5f);
    int d0 = lane * 4;
    float4 g = *reinterpret_cast<const float4*>(gamma + d0);
    float4 bt = *reinterpret_cast<const float4*>(beta + d0);
    float4 o;
    o.x = (x[0] - mu) * inv * g.x + bt.x;
    o.y = (x[1] - mu) * inv * g.y + bt.y;
    o.z = (x[2] - mu) * inv * g.z + bt.z;
    o.w = (x[3] - mu) * inv * g.w + bt.w;
    *reinterpret_cast<float4*>(outf + base) = o;
    ushort4 ob;
    ob.x = f2b(o.x); ob.y = f2b(o.y); ob.z = f2b(o.z); ob.w = f2b(o.w);
    *reinterpret_cast<ushort4*>(outb + base) = ob;
}

// ---------------------------------------------------------------------------
// LN2: x = fp32 F + fp32 X  ->  FP32 out
// ---------------------------------------------------------------------------
__global__ __launch_bounds__(256) void ln2_kernel(
    const float* __restrict__ F, const float* __restrict__ X,
    const float* __restrict__ gamma, const float* __restrict__ beta,
    float* __restrict__ out)
{
    int row  = blockIdx.x * 4 + (threadIdx.x >> 6);
    int lane = threadIdx.x & 63;
    long base = (long)row * DM + lane * 4;
    float4 a = *reinterpret_cast<const float4*>(F + base);
    float4 c = *reinterpret_cast<const float4*>(X + base);
    float x[4] = {a.x + c.x, a.y + c.y, a.z + c.z, a.w + c.w};
    float s = x[0] + x[1] + x[2] + x[3];
#pragma unroll
    for (int off = 32; off > 0; off >>= 1) s += __shfl_xor(s, off);
    float mu = s * (1.0f / DM);
    float vs = 0.f;
#pragma unroll
    for (int t = 0; t < 4; ++t) { float d = x[t] - mu; vs += d * d; }
#pragma unroll
    for (int off = 32; off > 0; off >>= 1) vs += __shfl_xor(vs, off);
    float inv = rsqrtf(vs * (1.0f / DM) + 1e-5f);
    int d0 = lane * 4;
    float4 g = *reinterpret_cast<const float4*>(gamma + d0);
    float4 bt = *reinterpret_cast<const float4*>(beta + d0);
    float4 o;
    o.x = (x[0] - mu) * inv * g.x + bt.x;
    o.y = (x[1] - mu) * inv * g.y + bt.y;
    o.z = (x[2] - mu) * inv * g.z + bt.z;
    o.w = (x[3] - mu) * inv * g.w + bt.w;
    *reinterpret_cast<float4*>(out + base) = o;
}

// ---------------------------------------------------------------------------
extern "C" void kernel_launch(void* const* d_in, const int* in_sizes, int n_in,
                              void* d_out, int out_size, void* d_ws, size_t ws_size,
                              hipStream_t stream)
{
    const float* Q  = (const float*)d_in[0];
    const float* Ki = (const float*)d_in[1];
    const float* Vi = (const float*)d_in[2];
    const unsigned char* mask_raw = (const unsigned char*)d_in[3];
    const float* pe = (const float*)d_in[4];
    const float* Wq = (const float*)d_in[5];
    const float* Wk = (const float*)d_in[6];
    const float* Wv = (const float*)d_in[7];
    const float* Wo = (const float*)d_in[8];
    const float* w1 = (const float*)d_in[9];
    const float* b1 = (const float*)d_in[10];
    const float* w2 = (const float*)d_in[11];
    const float* b2 = (const float*)d_in[12];
    const float* gamma = (const float*)d_in[13];
    const float* beta  = (const float*)d_in[14];
    float* out = (float*)d_out;

    const size_t MiB = 1048576;
    char* ws = (char*)d_ws;

    // ---- adaptive chunk size: footprint = 59 + max(5*CB + 32KB*CB, 24) MiB --
    int CB = 1;
    for (int cb = 32; cb >= 1; cb >>= 1) {
        size_t scr_sz = (size_t)(5 * cb) * MiB + (size_t)cb * 32768;
        if (scr_sz < 24 * MiB) scr_sz = 24 * MiB;
        if ((59 * MiB + scr_sz) <= ws_size) { CB = cb; break; }
    }
    const int NCH = NB / CB;

    // ---- fixed low regions ----
    unsigned short* WqT  = (unsigned short*)(ws);                 // 512 KiB each
    unsigned short* WkT  = WqT + 262144;
    unsigned short* WvT  = WkT + 262144;
    unsigned short* WoT  = WvT + 262144;
    unsigned short* w1b  = (unsigned short*)(ws + 2 * MiB);       // 128 KiB
    unsigned short* w2b  = w1b + 65536;                           // 128 KiB
    int*            maskc = (int*)(ws + 2 * MiB + 262144);        // 64 KiB
    unsigned short* Qp   = (unsigned short*)(ws + 3 * MiB);       // 8 MiB bf16
    unsigned short* Kp   = (unsigned short*)(ws + 11 * MiB);      // 8 MiB
    unsigned short* Vp   = (unsigned short*)(ws + 19 * MiB);      // 8 MiB
    unsigned short* AttO = (unsigned short*)(ws + 27 * MiB);      // 8 MiB
    unsigned short* Xb   = (unsigned short*)(ws + 35 * MiB);      // 8 MiB
    float*          Xf   = (float*)(ws + 43 * MiB);               // 16 MiB
    char*           scr  = ws + 59 * MiB;
    // chunk scratch (CB MiB each)
    unsigned short* Qh   = (unsigned short*)(scr);
    unsigned short* Kh   = (unsigned short*)(scr + (size_t)CB * MiB);
    unsigned short* Vh   = (unsigned short*)(scr + (size_t)2 * CB * MiB);
    unsigned short* VhT  = (unsigned short*)(scr + (size_t)3 * CB * MiB);
    unsigned short* Vatt = (unsigned short*)(scr + (size_t)4 * CB * MiB);
    // vmean partial sums (per chunk; dead at tail-alias time)
    float*          part = (float*)(scr + (size_t)5 * CB * MiB);  // CB*32 KiB
    // tail aliases over scratch (chunk buffers dead by then)
    unsigned short* H1   = (unsigned short*)(scr);                // 8 MiB bf16
    float*          Ff   = (float*)(scr + 8 * MiB);               // 16 MiB fp32

    // softmax scale * log2(e), folded into the Q projection (z==0 slab)
    const float SCALE_Q = (float)((1.0 / (16.0 + 1e-6)) * 1.4426950408889634);
    const long CROWS = (long)CB * SEQ;
    const long CBELT = (long)CB * MiB / 2;     // chunk-buffer stride, elements

    // 0. fused prep: mask + weight transposes/conversions + PE-add (1 dispatch)
    prep_all<<<13504, 256, 0, stream>>>(
        mask_raw, maskc, Wq, Wk, Wv, WqT, Wo, WoT,
        w1, w2, w1b, w2b, Q, Ki, Vi, pe, Qp, Kp, Vp);

    // 1. attention in NCH chunks of CB batches
    for (int c = 0; c < NCH; ++c) {
        const long r0   = (long)c * CROWS;
        const int  bh0  = c * CB * NH;
        const int  gy   = (int)(CROWS / 128);
        const int  nbh  = CB * NH;

        // all 3 projections in ONE dispatch (z=0: Q scaled by SCALE_Q, 1:K, 2:V)
        gemm_bt<false, false, true><<<dim3(8, gy, 3), 256, 0, stream>>>(
            Qp + r0 * DM, DM, WqT, DM, Qh, HD, nullptr, SCALE_Q, DM,
            1, 4194304, 0, 0, 262144, 0, 0, CBELT, 0, 0);

        // fused per-head V transpose + vmean partial sums (1 dispatch)
        tv_kernel<<<CB * NH * 128 + CB * 8, 256, 0, stream>>>(
            Vh, VhT, part, CB);

        // fused attention (+ masked-row mean + store, 1 dispatch)
        flash_attn<<<dim3(8 * nbh, 1, 1), 256, 0, stream>>>(
            Qh, Kh, VhT, part, Vatt, maskc, bh0, nbh);

        // output projection for this chunk -> AttO rows [r0, r0+CROWS)
        gemm_bt<false, false, true><<<dim3(2, gy, 1), 256, 0, stream>>>(
            Vatt, HD, WoT, HD, AttO + r0 * DM, DM, nullptr, 1.f, HD,
            1, 0,0,0, 0,0,0, 0,0,0);
    }

    // 2. LN1: X = LN(Q + pe + AttO) -> fp32 Xf + bf16 Xb
    ln1_kernel<<<4096, 256, 0, stream>>>(AttO, Q, pe, gamma, beta, Xf, Xb);

    // 3. FFN1: H1 = relu(Xb @ w1^T + b1) -> bf16
    gemm_bt<true, true, true><<<dim3(2, 128, 1), 256, 0, stream>>>(
        Xb, DM, w1b, DM, H1, DM, b1, 1.f, DM, 1, 0,0,0, 0,0,0, 0,0,0);
    // 4. FFN2: F = H1 @ w2^T + b2 -> fp32
    gemm_bt<true, false, false><<<dim3(2, 128, 1), 256, 0, stream>>>(
        H1, DM, w2b, DM, Ff, DM, b2, 1.f, DM, 1, 0,0,0, 0,0,0, 0,0,0);

    // 5. LN2: out = LN(F + X) -> FP32
    ln2_kernel<<<4096, 256, 0, stream>>>(Ff, Xf, gamma, beta, out);
}